// Round 1
// baseline (1801.917 us; speedup 1.0000x reference)
//
#include <hip/hip_runtime.h>
#include <math.h>

// ---------------------------------------------------------------------------
// SplineCNN (kernel_size=4, dim=2, deg=2): CSR-by-dst build + 2 spline convs
// + BN/ELU + MLP. N=150k nodes, E=3M edges, S=16 kernel matrices.
// ---------------------------------------------------------------------------

#define WAVE 64

// Open quadratic B-spline, K=4, dim-separable basis binning.
// B[j] = sum_i b_i * [clip(floor(2u)+i,0,3) == j]
__device__ __forceinline__ void bspline4(float a, float B[4]) {
    a = fminf(fmaxf(a, 0.f), 1.f);
    float v  = a * 2.0f;          // K - DEG = 2
    float kv = floorf(v);
    float t  = v - kv;
    int   ik = (int)kv;           // 0..2
    float b0 = 0.5f * (1.f - t) * (1.f - t);
    float b1 = (t - t * t) + 0.5f;
    float b2 = 0.5f * t * t;
    int c0 = ik;
    int c1 = ik + 1;              // <= 3 always
    int c2 = ik + 2; if (c2 > 3) c2 = 3;
#pragma unroll
    for (int j = 0; j < 4; ++j)
        B[j] = (c0 == j ? b0 : 0.f) + (c1 == j ? b1 : 0.f) + (c2 == j ? b2 : 0.f);
}

__device__ __forceinline__ float eluf(float x) {
    return x > 0.f ? x : expm1f(x);
}

// ---------------- CSR build ----------------

__global__ void k_count(const int* __restrict__ dst, int E, int* __restrict__ deg) {
    int i = blockIdx.x * blockDim.x + threadIdx.x;
    int stride = gridDim.x * blockDim.x;
    for (; i < E; i += stride) atomicAdd(&deg[dst[i]], 1);
}

// tile = 1024 elements per block (256 thr x 4). Writes block-local exclusive
// prefix into rowptr, block totals into blockSums.
__global__ void k_scan1(const int* __restrict__ deg, int N,
                        int* __restrict__ rowptr, int* __restrict__ blockSums) {
    __shared__ int wsum[4];
    int tid  = threadIdx.x;
    int base = blockIdx.x * 1024 + tid * 4;
    int d0 = (base + 0) < N ? deg[base + 0] : 0;
    int d1 = (base + 1) < N ? deg[base + 1] : 0;
    int d2 = (base + 2) < N ? deg[base + 2] : 0;
    int d3 = (base + 3) < N ? deg[base + 3] : 0;
    int s4 = d0 + d1 + d2 + d3;
    int lane = tid & 63, wid = tid >> 6;
    int inc = s4;
#pragma unroll
    for (int off = 1; off < 64; off <<= 1) {
        int t = __shfl_up(inc, off);
        if (lane >= off) inc += t;
    }
    if (lane == 63) wsum[wid] = inc;
    __syncthreads();
    if (tid == 0) {
        int acc = 0;
#pragma unroll
        for (int w = 0; w < 4; ++w) { int t = wsum[w]; wsum[w] = acc; acc += t; }
    }
    __syncthreads();
    int ebase = wsum[wid] + inc - s4;   // exclusive-within-block
    if ((base + 0) < N) rowptr[base + 0] = ebase;
    if ((base + 1) < N) rowptr[base + 1] = ebase + d0;
    if ((base + 2) < N) rowptr[base + 2] = ebase + d0 + d1;
    if ((base + 3) < N) rowptr[base + 3] = ebase + d0 + d1 + d2;
    if (tid == 255) blockSums[blockIdx.x] = ebase + s4;  // block total
}

// single block scans <=256 block sums (147 for N=150k)
__global__ void k_scan2(const int* __restrict__ blockSums, int NB, int* __restrict__ blockOff) {
    __shared__ int sh[256];
    int tid = threadIdx.x;
    int own = (tid < NB) ? blockSums[tid] : 0;
    sh[tid] = own;
    __syncthreads();
    for (int off = 1; off < 256; off <<= 1) {
        int v = (tid >= off) ? sh[tid - off] : 0;
        __syncthreads();
        sh[tid] += v;
        __syncthreads();
    }
    if (tid < NB) blockOff[tid] = sh[tid] - own;  // exclusive
}

__global__ void k_scan3(int* __restrict__ rowptr, int* __restrict__ cursor,
                        const int* __restrict__ blockOff, int N, int E) {
    int i = blockIdx.x * blockDim.x + threadIdx.x;
    if (i < N) {
        int v = rowptr[i] + blockOff[i >> 10];
        rowptr[i] = v;
        cursor[i] = v;
    }
    if (i == 0) rowptr[N] = E;
}

__global__ void k_fill(const int* __restrict__ ei, const float* __restrict__ attr, int E,
                       int* __restrict__ cursor, int* __restrict__ csr_src,
                       float* __restrict__ csr_u, float* __restrict__ csr_v) {
    int i = blockIdx.x * blockDim.x + threadIdx.x;
    int stride = gridDim.x * blockDim.x;
    for (; i < E; i += stride) {
        int d = ei[E + i];
        int pos = atomicAdd(&cursor[d], 1);
        csr_src[pos] = ei[i];
        csr_u[pos]   = attr[2 * i + 0];
        csr_v[pos]   = attr[2 * i + 1];
    }
}

// ---------------- Layer 1 conv (in=1 -> out=32), thread per node ----------------

__global__ void k_conv1(const float* __restrict__ x, const int* __restrict__ rowptr,
                        const int* __restrict__ csr_src, const float* __restrict__ csr_u,
                        const float* __restrict__ csr_v,
                        const float* __restrict__ w1, const float* __restrict__ root1,
                        const float* __restrict__ b1, float* __restrict__ h1, int N) {
    __shared__ float w1s[16 * 32];
    __shared__ float r1s[32], b1s[32];
    int tid = threadIdx.x;
    for (int i = tid; i < 512; i += blockDim.x) w1s[i] = w1[i];
    if (tid < 32) { r1s[tid] = root1[tid]; b1s[tid] = b1[tid]; }
    __syncthreads();
    int n = blockIdx.x * blockDim.x + tid;
    if (n >= N) return;
    float agg[16] = {};
    int s = rowptr[n], e = rowptr[n + 1];
    for (int j = s; j < e; ++j) {
        float Bu[4], Bv[4];
        bspline4(csr_u[j], Bu);
        bspline4(csr_v[j], Bv);
        float xs = x[csr_src[j]];
#pragma unroll
        for (int k = 0; k < 16; ++k)
            agg[k] += (Bu[k & 3] * Bv[k >> 2]) * xs;
    }
    float xn = x[n];
#pragma unroll 4
    for (int o = 0; o < 32; ++o) {
        float acc = b1s[o] + xn * r1s[o];
#pragma unroll
        for (int k = 0; k < 16; ++k) acc += agg[k] * w1s[k * 32 + o];
        h1[n * 32 + o] = acc;
    }
}

// ---------------- BatchNorm ----------------

template <int C>
__global__ void k_bnstat(const float* __restrict__ h, int N, double* __restrict__ sums) {
    __shared__ float sh1[C], sh2[C];
    int tid  = blockIdx.x * blockDim.x + threadIdx.x;
    int c    = tid & (C - 1);
    int row  = tid / C;
    int rstr = (gridDim.x * blockDim.x) / C;
    float s1 = 0.f, s2 = 0.f;
    for (int r = row; r < N; r += rstr) {
        float v = h[(size_t)r * C + c];
        s1 += v; s2 += v * v;
    }
    if (threadIdx.x < C) { sh1[threadIdx.x] = 0.f; sh2[threadIdx.x] = 0.f; }
    __syncthreads();
    atomicAdd(&sh1[c], s1);
    atomicAdd(&sh2[c], s2);
    __syncthreads();
    if (threadIdx.x < C) {
        atomicAdd(&sums[threadIdx.x],     (double)sh1[threadIdx.x]);
        atomicAdd(&sums[C + threadIdx.x], (double)sh2[threadIdx.x]);
    }
}

__global__ void k_bnfinal(const double* __restrict__ sums, const float* __restrict__ gamma,
                          const float* __restrict__ beta, int C, int N, float* __restrict__ scsh) {
    int c = threadIdx.x;
    if (c < C) {
        double m   = sums[c] / (double)N;
        double var = sums[C + c] / (double)N - m * m;
        float vpe  = (float)var + 1e-5f;
        float sc   = gamma[c] / sqrtf(vpe);
        scsh[c]     = sc;
        scsh[C + c] = beta[c] - (float)m * sc;
    }
}

template <int C>
__global__ void k_bnelu(float* __restrict__ h, int N, const float* __restrict__ scsh) {
    int total = N * C / 4;
    int i = blockIdx.x * blockDim.x + threadIdx.x;
    int stride = gridDim.x * blockDim.x;
    float4* hp = (float4*)h;
    for (; i < total; i += stride) {
        float4 v = hp[i];
        int c0 = (i * 4) & (C - 1);
        v.x = eluf(v.x * scsh[c0 + 0] + scsh[C + c0 + 0]);
        v.y = eluf(v.y * scsh[c0 + 1] + scsh[C + c0 + 1]);
        v.z = eluf(v.z * scsh[c0 + 2] + scsh[C + c0 + 2]);
        v.w = eluf(v.w * scsh[c0 + 3] + scsh[C + c0 + 3]);
        hp[i] = v;
    }
}

// ---------------- Layer 2 conv (in=32 -> out=64), wave per node ----------------
// LDS: w2 (32768 f) + root2 (2048 f) + b2 (64 f) + per-wave agg scratch (8*512 f)

__global__ __launch_bounds__(512) void k_conv2(
    const float* __restrict__ h1, const int* __restrict__ rowptr,
    const int* __restrict__ csr_src, const float* __restrict__ csr_u,
    const float* __restrict__ csr_v,
    const float* __restrict__ w2, const float* __restrict__ root2,
    const float* __restrict__ b2, float* __restrict__ out2, int N) {
    extern __shared__ float lds[];
    float* w2s  = lds;                 // 32768
    float* r2s  = w2s + 32768;         // 2048
    float* b2s  = r2s + 2048;          // 64
    float* aggb = b2s + 64;            // 8 * 512
    int tid = threadIdx.x;
    for (int i = tid; i < 32768; i += 512) w2s[i] = w2[i];
    for (int i = tid; i < 2048;  i += 512) r2s[i] = root2[i];
    if (tid < 64) b2s[tid] = b2[tid];
    __syncthreads();

    int lane  = tid & 63;
    int w     = tid >> 6;
    int c     = lane & 31;
    int khalf = lane >> 5;
    float* myagg = aggb + w * 512;

    for (int n = blockIdx.x * 8 + w; n < N; n += gridDim.x * 8) {
        float agg[8] = {};
        int s = rowptr[n], e = rowptr[n + 1];
        for (int j = s; j < e; ++j) {
            float Bu[4], Bv[4];
            bspline4(csr_u[j], Bu);
            bspline4(csr_v[j], Bv);
            float hc  = h1[(size_t)csr_src[j] * 32 + c];
            float bvlo = khalf ? Bv[2] : Bv[0];
            float bvhi = khalf ? Bv[3] : Bv[1];
#pragma unroll
            for (int q = 0; q < 8; ++q) {
                float bv = (q < 4) ? bvlo : bvhi;
                agg[q] += (Bu[q & 3] * bv) * hc;   // k = khalf*8+q; ku=q&3, kv=khalf*2+(q>>2)
            }
        }
        // stash agg into per-wave LDS scratch: index k*32+c
#pragma unroll
        for (int q = 0; q < 8; ++q)
            myagg[(khalf * 8 + q) * 32 + c] = agg[q];
        // wave-internal LDS dependency; compiler inserts lgkmcnt waits

        float acc = b2s[lane];
#pragma unroll 8
        for (int cc = 0; cc < 32; ++cc)
            acc += h1[(size_t)n * 32 + cc] * r2s[cc * 64 + lane];

        const float4* av = (const float4*)myagg;
#pragma unroll 4
        for (int q4 = 0; q4 < 128; ++q4) {
            float4 a = av[q4];
            acc += a.x * w2s[(q4 * 4 + 0) * 64 + lane];
            acc += a.y * w2s[(q4 * 4 + 1) * 64 + lane];
            acc += a.z * w2s[(q4 * 4 + 2) * 64 + lane];
            acc += a.w * w2s[(q4 * 4 + 3) * 64 + lane];
        }
        out2[(size_t)n * 64 + lane] = acc;
    }
}

// ---------------- Final MLP: 64 -> 128 (ELU) -> 1, thread per node ----------------

__global__ void k_fc(const float* __restrict__ h2, const float* __restrict__ fc1w,
                     const float* __restrict__ fc1b, const float* __restrict__ fc2w,
                     const float* __restrict__ fc2b, float* __restrict__ out, int N) {
    __shared__ float w1s[64 * 128];
    __shared__ float b1s[128], w2s[128];
    int tid = threadIdx.x;
    for (int i = tid; i < 8192; i += blockDim.x) w1s[i] = fc1w[i];
    if (tid < 128) { b1s[tid] = fc1b[tid]; w2s[tid] = fc2w[tid]; }
    __syncthreads();
    int n = blockIdx.x * blockDim.x + tid;
    if (n >= N) return;
    float h[64];
    const float4* hp = (const float4*)(h2 + (size_t)n * 64);
#pragma unroll
    for (int i = 0; i < 16; ++i) {
        float4 v = hp[i];
        h[4 * i + 0] = v.x; h[4 * i + 1] = v.y; h[4 * i + 2] = v.z; h[4 * i + 3] = v.w;
    }
    float acc = fc2b[0];
    for (int o = 0; o < 128; ++o) {
        float p = b1s[o];
#pragma unroll
        for (int cd = 0; cd < 64; ++cd) p += h[cd] * w1s[cd * 128 + o];
        p = eluf(p);
        acc += p * w2s[o];
    }
    out[n] = acc;
}

// ---------------------------------------------------------------------------

extern "C" void kernel_launch(void* const* d_in, const int* in_sizes, int n_in,
                              void* d_out, int out_size, void* d_ws, size_t ws_size,
                              hipStream_t stream) {
    const float* x     = (const float*)d_in[0];
    const int*   ei    = (const int*)  d_in[1];
    const float* attr  = (const float*)d_in[2];
    const float* w1    = (const float*)d_in[3];
    const float* root1 = (const float*)d_in[4];
    const float* b1    = (const float*)d_in[5];
    const float* g1    = (const float*)d_in[6];
    const float* be1   = (const float*)d_in[7];
    const float* w2    = (const float*)d_in[8];
    const float* root2 = (const float*)d_in[9];
    const float* b2    = (const float*)d_in[10];
    const float* g2    = (const float*)d_in[11];
    const float* be2   = (const float*)d_in[12];
    const float* fc1w  = (const float*)d_in[13];
    const float* fc1b  = (const float*)d_in[14];
    const float* fc2w  = (const float*)d_in[15];
    const float* fc2b  = (const float*)d_in[16];
    float* out = (float*)d_out;

    int N = in_sizes[0];          // 150000
    int E = in_sizes[1] / 2;      // 3000000

    char* ws = (char*)d_ws;
    size_t off = 0;
    auto alloc = [&](size_t bytes) -> void* {
        void* p = ws + off;
        off = (off + bytes + 255) & ~(size_t)255;
        return p;
    };
    int*    rowptr    = (int*)   alloc((size_t)(N + 1) * 4);
    int*    deg       = (int*)   alloc((size_t)N * 4);
    int*    cursor    = (int*)   alloc((size_t)N * 4);
    int*    blockSums = (int*)   alloc(1024 * 4);
    int*    blockOff  = (int*)   alloc(1024 * 4);
    double* bnsum1    = (double*)alloc(128 * 8);
    double* bnsum2    = (double*)alloc(128 * 8);
    float*  scsh1     = (float*) alloc(64 * 4);
    float*  scsh2     = (float*) alloc(128 * 4);
    int*    csr_src   = (int*)   alloc((size_t)E * 4);
    float*  csr_u     = (float*) alloc((size_t)E * 4);
    float*  csr_v     = (float*) alloc((size_t)E * 4);
    float*  h1        = (float*) alloc((size_t)N * 32 * 4);
    float*  out2      = (float*) alloc((size_t)N * 64 * 4);
    (void)ws_size; (void)n_in; (void)out_size;

    hipMemsetAsync(deg, 0, (size_t)N * 4, stream);
    hipMemsetAsync(bnsum1, 0, 128 * 8, stream);
    hipMemsetAsync(bnsum2, 0, 128 * 8, stream);

    int gE = (E + 255) / 256; if (gE > 4096) gE = 4096;
    int NB = (N + 1023) / 1024;   // 147 <= 256

    k_count<<<gE, 256, 0, stream>>>(ei + E, E, deg);
    k_scan1<<<NB, 256, 0, stream>>>(deg, N, rowptr, blockSums);
    k_scan2<<<1, 256, 0, stream>>>(blockSums, NB, blockOff);
    k_scan3<<<(N + 255) / 256, 256, 0, stream>>>(rowptr, cursor, blockOff, N, E);
    k_fill<<<gE, 256, 0, stream>>>(ei, attr, E, cursor, csr_src, csr_u, csr_v);

    k_conv1<<<(N + 255) / 256, 256, 0, stream>>>(x, rowptr, csr_src, csr_u, csr_v,
                                                 w1, root1, b1, h1, N);
    k_bnstat<32><<<256, 256, 0, stream>>>(h1, N, bnsum1);
    k_bnfinal<<<1, 64, 0, stream>>>(bnsum1, g1, be1, 32, N, scsh1);
    k_bnelu<32><<<1024, 256, 0, stream>>>(h1, N, scsh1);

    size_t lds2 = (size_t)(32768 + 2048 + 64 + 8 * 512) * sizeof(float);  // 155904 B
    k_conv2<<<256, 512, lds2, stream>>>(h1, rowptr, csr_src, csr_u, csr_v,
                                        w2, root2, b2, out2, N);
    k_bnstat<64><<<256, 256, 0, stream>>>(out2, N, bnsum2);
    k_bnfinal<<<1, 64, 0, stream>>>(bnsum2, g2, be2, 64, N, scsh2);
    k_bnelu<64><<<2048, 256, 0, stream>>>(out2, N, scsh2);

    k_fc<<<(N + 255) / 256, 256, 0, stream>>>(out2, fc1w, fc1b, fc2w, fc2b, out, N);
}

// Round 2
// 1414.086 us; speedup vs baseline: 1.2743x; 1.2743x over previous
//
#include <hip/hip_runtime.h>
#include <math.h>

// ---------------------------------------------------------------------------
// SplineCNN (K=4, dim=2, deg=2). v2: precomputed dense basis per edge;
// conv2 split into aggregation (global agg, chunked) + register-tiled GEMM.
// ---------------------------------------------------------------------------

__device__ __forceinline__ void bspline4(float a, float B[4]) {
    a = fminf(fmaxf(a, 0.f), 1.f);
    float v  = a * 2.0f;          // K - DEG = 2
    float kv = floorf(v);
    float t  = v - kv;
    int   ik = (int)kv;           // 0..2
    float b0 = 0.5f * (1.f - t) * (1.f - t);
    float b1 = (t - t * t) + 0.5f;
    float b2 = 0.5f * t * t;
    int c0 = ik;
    int c1 = ik + 1;
    int c2 = ik + 2; if (c2 > 3) c2 = 3;
#pragma unroll
    for (int j = 0; j < 4; ++j)
        B[j] = (c0 == j ? b0 : 0.f) + (c1 == j ? b1 : 0.f) + (c2 == j ? b2 : 0.f);
}

__device__ __forceinline__ float eluf(float x) {
    return x > 0.f ? x : expm1f(x);
}

// ---------------- CSR build ----------------

__global__ void k_count(const int* __restrict__ dst, int E, int* __restrict__ deg) {
    int i = blockIdx.x * blockDim.x + threadIdx.x;
    int stride = gridDim.x * blockDim.x;
    for (; i < E; i += stride) atomicAdd(&deg[dst[i]], 1);
}

__global__ void k_scan1(const int* __restrict__ deg, int N,
                        int* __restrict__ rowptr, int* __restrict__ blockSums) {
    __shared__ int wsum[4];
    int tid  = threadIdx.x;
    int base = blockIdx.x * 1024 + tid * 4;
    int d0 = (base + 0) < N ? deg[base + 0] : 0;
    int d1 = (base + 1) < N ? deg[base + 1] : 0;
    int d2 = (base + 2) < N ? deg[base + 2] : 0;
    int d3 = (base + 3) < N ? deg[base + 3] : 0;
    int s4 = d0 + d1 + d2 + d3;
    int lane = tid & 63, wid = tid >> 6;
    int inc = s4;
#pragma unroll
    for (int off = 1; off < 64; off <<= 1) {
        int t = __shfl_up(inc, off);
        if (lane >= off) inc += t;
    }
    if (lane == 63) wsum[wid] = inc;
    __syncthreads();
    if (tid == 0) {
        int acc = 0;
#pragma unroll
        for (int w = 0; w < 4; ++w) { int t = wsum[w]; wsum[w] = acc; acc += t; }
    }
    __syncthreads();
    int ebase = wsum[wid] + inc - s4;
    if ((base + 0) < N) rowptr[base + 0] = ebase;
    if ((base + 1) < N) rowptr[base + 1] = ebase + d0;
    if ((base + 2) < N) rowptr[base + 2] = ebase + d0 + d1;
    if ((base + 3) < N) rowptr[base + 3] = ebase + d0 + d1 + d2;
    if (tid == 255) blockSums[blockIdx.x] = ebase + s4;
}

__global__ void k_scan2(const int* __restrict__ blockSums, int NB, int* __restrict__ blockOff) {
    __shared__ int sh[256];
    int tid = threadIdx.x;
    int own = (tid < NB) ? blockSums[tid] : 0;
    sh[tid] = own;
    __syncthreads();
    for (int off = 1; off < 256; off <<= 1) {
        int v = (tid >= off) ? sh[tid - off] : 0;
        __syncthreads();
        sh[tid] += v;
        __syncthreads();
    }
    if (tid < NB) blockOff[tid] = sh[tid] - own;
}

__global__ void k_scan3(int* __restrict__ rowptr, int* __restrict__ cursor,
                        const int* __restrict__ blockOff, int N, int E) {
    int i = blockIdx.x * blockDim.x + threadIdx.x;
    if (i < N) {
        int v = rowptr[i] + blockOff[i >> 10];
        rowptr[i] = v;
        cursor[i] = v;
    }
    if (i == 0) rowptr[N] = E;
}

// fill CSR; precompute dense 4-vector spline basis per dim (paid once here)
__global__ void k_fill(const int* __restrict__ ei, const float* __restrict__ attr, int E,
                       int* __restrict__ cursor, int* __restrict__ csr_src,
                       float4* __restrict__ csr_bu, float4* __restrict__ csr_bv) {
    int i = blockIdx.x * blockDim.x + threadIdx.x;
    int stride = gridDim.x * blockDim.x;
    for (; i < E; i += stride) {
        int d = ei[E + i];
        int pos = atomicAdd(&cursor[d], 1);
        csr_src[pos] = ei[i];
        float Bu[4], Bv[4];
        bspline4(attr[2 * i + 0], Bu);
        bspline4(attr[2 * i + 1], Bv);
        csr_bu[pos] = make_float4(Bu[0], Bu[1], Bu[2], Bu[3]);
        csr_bv[pos] = make_float4(Bv[0], Bv[1], Bv[2], Bv[3]);
    }
}

// ---------------- Layer 1 conv (in=1 -> out=32), thread per node ----------------

__global__ void k_conv1(const float* __restrict__ x, const int* __restrict__ rowptr,
                        const int* __restrict__ csr_src, const float4* __restrict__ csr_bu,
                        const float4* __restrict__ csr_bv,
                        const float* __restrict__ w1, const float* __restrict__ root1,
                        const float* __restrict__ b1, float* __restrict__ h1, int N) {
    __shared__ float w1s[16 * 32];
    __shared__ float r1s[32], b1s[32];
    int tid = threadIdx.x;
    for (int i = tid; i < 512; i += blockDim.x) w1s[i] = w1[i];
    if (tid < 32) { r1s[tid] = root1[tid]; b1s[tid] = b1[tid]; }
    __syncthreads();
    int n = blockIdx.x * blockDim.x + tid;
    if (n >= N) return;
    float agg[16] = {};
    int s = rowptr[n], e = rowptr[n + 1];
    for (int j = s; j < e; ++j) {
        float4 bu = csr_bu[j];
        float4 bv = csr_bv[j];
        float xs = x[csr_src[j]];
        float t0 = xs * bv.x, t1 = xs * bv.y, t2 = xs * bv.z, t3 = xs * bv.w;
        agg[0]  += bu.x * t0; agg[1]  += bu.y * t0; agg[2]  += bu.z * t0; agg[3]  += bu.w * t0;
        agg[4]  += bu.x * t1; agg[5]  += bu.y * t1; agg[6]  += bu.z * t1; agg[7]  += bu.w * t1;
        agg[8]  += bu.x * t2; agg[9]  += bu.y * t2; agg[10] += bu.z * t2; agg[11] += bu.w * t2;
        agg[12] += bu.x * t3; agg[13] += bu.y * t3; agg[14] += bu.z * t3; agg[15] += bu.w * t3;
    }
    float xn = x[n];
#pragma unroll 4
    for (int o = 0; o < 32; ++o) {
        float acc = b1s[o] + xn * r1s[o];
#pragma unroll
        for (int k = 0; k < 16; ++k) acc += agg[k] * w1s[k * 32 + o];
        h1[n * 32 + o] = acc;
    }
}

// ---------------- BatchNorm ----------------

template <int C>
__global__ void k_bnstat(const float* __restrict__ h, int N, double* __restrict__ sums) {
    __shared__ float sh1[C], sh2[C];
    int tid  = blockIdx.x * blockDim.x + threadIdx.x;
    int c    = tid & (C - 1);
    int row  = tid / C;
    int rstr = (gridDim.x * blockDim.x) / C;
    float s1 = 0.f, s2 = 0.f;
    for (int r = row; r < N; r += rstr) {
        float v = h[(size_t)r * C + c];
        s1 += v; s2 += v * v;
    }
    if (threadIdx.x < C) { sh1[threadIdx.x] = 0.f; sh2[threadIdx.x] = 0.f; }
    __syncthreads();
    atomicAdd(&sh1[c], s1);
    atomicAdd(&sh2[c], s2);
    __syncthreads();
    if (threadIdx.x < C) {
        atomicAdd(&sums[threadIdx.x],     (double)sh1[threadIdx.x]);
        atomicAdd(&sums[C + threadIdx.x], (double)sh2[threadIdx.x]);
    }
}

__global__ void k_bnfinal(const double* __restrict__ sums, const float* __restrict__ gamma,
                          const float* __restrict__ beta, int C, int N, float* __restrict__ scsh) {
    int c = threadIdx.x;
    if (c < C) {
        double m   = sums[c] / (double)N;
        double var = sums[C + c] / (double)N - m * m;
        float vpe  = (float)var + 1e-5f;
        float sc   = gamma[c] / sqrtf(vpe);
        scsh[c]     = sc;
        scsh[C + c] = beta[c] - (float)m * sc;
    }
}

template <int C>
__global__ void k_bnelu(float* __restrict__ h, int N, const float* __restrict__ scsh) {
    int total = N * C / 4;
    int i = blockIdx.x * blockDim.x + threadIdx.x;
    int stride = gridDim.x * blockDim.x;
    float4* hp = (float4*)h;
    for (; i < total; i += stride) {
        float4 v = hp[i];
        int c0 = (i * 4) & (C - 1);
        v.x = eluf(v.x * scsh[c0 + 0] + scsh[C + c0 + 0]);
        v.y = eluf(v.y * scsh[c0 + 1] + scsh[C + c0 + 1]);
        v.z = eluf(v.z * scsh[c0 + 2] + scsh[C + c0 + 2]);
        v.w = eluf(v.w * scsh[c0 + 3] + scsh[C + c0 + 3]);
        hp[i] = v;
    }
}

// ---------------- Layer 2: aggregation (wave per node) -> agg[nloc][512] ----------------

__global__ __launch_bounds__(512) void k_agg(
    const float* __restrict__ h1, const int* __restrict__ rowptr,
    const int* __restrict__ csr_src, const float4* __restrict__ csr_bu,
    const float4* __restrict__ csr_bv, float* __restrict__ agg,
    int n0, int n1) {
    int tid   = threadIdx.x;
    int lane  = tid & 63;
    int w     = tid >> 6;
    int c     = lane & 31;
    int khalf = lane >> 5;
    int n = n0 + blockIdx.x * 8 + w;
    if (n >= n1) return;
    float a[8] = {};
    int s = __builtin_amdgcn_readfirstlane(rowptr[n]);
    int e = __builtin_amdgcn_readfirstlane(rowptr[n + 1]);
    for (int j = s; j < e; ++j) {
        int src   = __builtin_amdgcn_readfirstlane(csr_src[j]);
        float4 bu = csr_bu[j];
        float4 bv = csr_bv[j];
        float hc  = h1[(size_t)src * 32 + c];
        float bvlo = khalf ? bv.z : bv.x;
        float bvhi = khalf ? bv.w : bv.y;
        float t0 = hc * bvlo, t1 = hc * bvhi;
        a[0] += bu.x * t0; a[1] += bu.y * t0; a[2] += bu.z * t0; a[3] += bu.w * t0;
        a[4] += bu.x * t1; a[5] += bu.y * t1; a[6] += bu.z * t1; a[7] += bu.w * t1;
    }
    float* ag = agg + (size_t)(n - n0) * 512 + khalf * 256 + c;
#pragma unroll
    for (int q = 0; q < 8; ++q) ag[q * 32] = a[q];
}

// ---------------- Layer 2: GEMM agg[cnt,512] @ w2[512,64] + h1 @ root2 + b2 ----------------

__global__ __launch_bounds__(256) void k_gemm(
    const float* __restrict__ agg, const float* __restrict__ h1,
    const float* __restrict__ w2, const float* __restrict__ root2,
    const float* __restrict__ b2, float* __restrict__ out2,
    int n0, int n1) {
    __shared__ float w2s[64 * 64];
    int tid   = threadIdx.x;
    int tc    = tid & 7;
    int tr    = tid >> 3;
    int obase = tc * 8;
    int cnt   = n1 - n0;
    int base  = blockIdx.x * 256 + tr * 8;

    float acc[8][8];
    float4 blo = *(const float4*)(b2 + obase);
    float4 bhi = *(const float4*)(b2 + obase + 4);
#pragma unroll
    for (int i = 0; i < 8; ++i) {
        acc[i][0] = blo.x; acc[i][1] = blo.y; acc[i][2] = blo.z; acc[i][3] = blo.w;
        acc[i][4] = bhi.x; acc[i][5] = bhi.y; acc[i][6] = bhi.z; acc[i][7] = bhi.w;
    }
    const float* arow[8];
    const float* hrow[8];
#pragma unroll
    for (int i = 0; i < 8; ++i) {
        int r = base + i; if (r > cnt - 1) r = cnt - 1;
        arow[i] = agg + (size_t)r * 512;
        hrow[i] = h1 + (size_t)(n0 + r) * 32;
    }

    for (int kc = 0; kc < 512; kc += 64) {
        __syncthreads();
        const float4* s4 = (const float4*)(w2 + kc * 64);
        float4* d4 = (float4*)w2s;
#pragma unroll
        for (int t = 0; t < 4; ++t) d4[tid + t * 256] = s4[tid + t * 256];
        __syncthreads();
#pragma unroll 2
        for (int k4 = 0; k4 < 64; k4 += 4) {
            float4 av[8];
#pragma unroll
            for (int i = 0; i < 8; ++i) av[i] = *(const float4*)(arow[i] + kc + k4);
#pragma unroll
            for (int kk = 0; kk < 4; ++kk) {
                const float* wp = w2s + (k4 + kk) * 64 + obase;
                float4 wlo = *(const float4*)(wp);
                float4 whi = *(const float4*)(wp + 4);
#pragma unroll
                for (int i = 0; i < 8; ++i) {
                    float a = (kk == 0) ? av[i].x : (kk == 1) ? av[i].y
                            : (kk == 2) ? av[i].z : av[i].w;
                    acc[i][0] += a * wlo.x; acc[i][1] += a * wlo.y;
                    acc[i][2] += a * wlo.z; acc[i][3] += a * wlo.w;
                    acc[i][4] += a * whi.x; acc[i][5] += a * whi.y;
                    acc[i][6] += a * whi.z; acc[i][7] += a * whi.w;
                }
            }
        }
    }
    __syncthreads();
    {
        const float4* s4 = (const float4*)root2;
        float4* d4 = (float4*)w2s;
#pragma unroll
        for (int t = 0; t < 2; ++t) d4[tid + t * 256] = s4[tid + t * 256];
    }
    __syncthreads();
#pragma unroll
    for (int k4 = 0; k4 < 32; k4 += 4) {
        float4 hv[8];
#pragma unroll
        for (int i = 0; i < 8; ++i) hv[i] = *(const float4*)(hrow[i] + k4);
#pragma unroll
        for (int kk = 0; kk < 4; ++kk) {
            const float* wp = w2s + (k4 + kk) * 64 + obase;
            float4 wlo = *(const float4*)(wp);
            float4 whi = *(const float4*)(wp + 4);
#pragma unroll
            for (int i = 0; i < 8; ++i) {
                float a = (kk == 0) ? hv[i].x : (kk == 1) ? hv[i].y
                        : (kk == 2) ? hv[i].z : hv[i].w;
                acc[i][0] += a * wlo.x; acc[i][1] += a * wlo.y;
                acc[i][2] += a * wlo.z; acc[i][3] += a * wlo.w;
                acc[i][4] += a * whi.x; acc[i][5] += a * whi.y;
                acc[i][6] += a * whi.z; acc[i][7] += a * whi.w;
            }
        }
    }
#pragma unroll
    for (int i = 0; i < 8; ++i) {
        int r = base + i;
        if (r < cnt) {
            float* op = out2 + (size_t)(n0 + r) * 64 + obase;
            *(float4*)op       = make_float4(acc[i][0], acc[i][1], acc[i][2], acc[i][3]);
            *(float4*)(op + 4) = make_float4(acc[i][4], acc[i][5], acc[i][6], acc[i][7]);
        }
    }
}

// ---------------- Final MLP: 64 -> 128 (ELU) -> 1, two nodes per thread ----------------

__global__ __launch_bounds__(256) void k_fc(
    const float* __restrict__ h2, const float* __restrict__ fc1w,
    const float* __restrict__ fc1b, const float* __restrict__ fc2w,
    const float* __restrict__ fc2b, float* __restrict__ out, int N) {
    __shared__ float w1t[128 * 64];  // transposed [o][cd]
    __shared__ float b1s[128], w2s[128];
    int tid = threadIdx.x;
    for (int i = tid; i < 8192; i += 256) {
        int o = i >> 6, cd = i & 63;
        w1t[o * 64 + cd] = fc1w[cd * 128 + o];
    }
    if (tid < 128) { b1s[tid] = fc1b[tid]; w2s[tid] = fc2w[tid]; }
    __syncthreads();
    int n0 = (blockIdx.x * 256 + tid) * 2;
    if (n0 >= N) return;
    int n1i = (n0 + 1 < N) ? n0 + 1 : n0;
    float h0[64], h1v[64];
    {
        const float4* p0 = (const float4*)(h2 + (size_t)n0 * 64);
        const float4* p1 = (const float4*)(h2 + (size_t)n1i * 64);
#pragma unroll
        for (int i = 0; i < 16; ++i) {
            float4 a = p0[i];
            h0[4 * i] = a.x; h0[4 * i + 1] = a.y; h0[4 * i + 2] = a.z; h0[4 * i + 3] = a.w;
            float4 b = p1[i];
            h1v[4 * i] = b.x; h1v[4 * i + 1] = b.y; h1v[4 * i + 2] = b.z; h1v[4 * i + 3] = b.w;
        }
    }
    float acc0 = fc2b[0], acc1 = acc0;
    for (int o = 0; o < 128; ++o) {
        float p0 = b1s[o], p1 = p0;
        const float4* wp = (const float4*)(w1t + o * 64);
#pragma unroll
        for (int q = 0; q < 16; ++q) {
            float4 wv = wp[q];
            p0 += h0[4 * q] * wv.x + h0[4 * q + 1] * wv.y + h0[4 * q + 2] * wv.z + h0[4 * q + 3] * wv.w;
            p1 += h1v[4 * q] * wv.x + h1v[4 * q + 1] * wv.y + h1v[4 * q + 2] * wv.z + h1v[4 * q + 3] * wv.w;
        }
        float w2v = w2s[o];
        acc0 += eluf(p0) * w2v;
        acc1 += eluf(p1) * w2v;
    }
    out[n0] = acc0;
    if (n0 + 1 < N) out[n0 + 1] = acc1;
}

// ---------------------------------------------------------------------------

extern "C" void kernel_launch(void* const* d_in, const int* in_sizes, int n_in,
                              void* d_out, int out_size, void* d_ws, size_t ws_size,
                              hipStream_t stream) {
    const float* x     = (const float*)d_in[0];
    const int*   ei    = (const int*)  d_in[1];
    const float* attr  = (const float*)d_in[2];
    const float* w1    = (const float*)d_in[3];
    const float* root1 = (const float*)d_in[4];
    const float* b1    = (const float*)d_in[5];
    const float* g1    = (const float*)d_in[6];
    const float* be1   = (const float*)d_in[7];
    const float* w2    = (const float*)d_in[8];
    const float* root2 = (const float*)d_in[9];
    const float* b2    = (const float*)d_in[10];
    const float* g2    = (const float*)d_in[11];
    const float* be2   = (const float*)d_in[12];
    const float* fc1w  = (const float*)d_in[13];
    const float* fc1b  = (const float*)d_in[14];
    const float* fc2w  = (const float*)d_in[15];
    const float* fc2b  = (const float*)d_in[16];
    float* out = (float*)d_out;

    int N = in_sizes[0];          // 150000
    int E = in_sizes[1] / 2;      // 3000000

    char* ws = (char*)d_ws;
    size_t off = 0;
    auto alloc = [&](size_t bytes) -> void* {
        void* p = ws + off;
        off = (off + bytes + 255) & ~(size_t)255;
        return p;
    };
    int*    rowptr    = (int*)   alloc((size_t)(N + 1) * 4);
    int*    deg       = (int*)   alloc((size_t)N * 4);
    int*    cursor    = (int*)   alloc((size_t)N * 4);
    int*    blockSums = (int*)   alloc(1024 * 4);
    int*    blockOff  = (int*)   alloc(1024 * 4);
    double* bnsum1    = (double*)alloc(128 * 8);
    double* bnsum2    = (double*)alloc(128 * 8);
    float*  scsh1     = (float*) alloc(64 * 4);
    float*  scsh2     = (float*) alloc(128 * 4);
    int*    csr_src   = (int*)   alloc((size_t)E * 4);
    float4* csr_bu    = (float4*)alloc((size_t)E * 16);
    float4* csr_bv    = (float4*)alloc((size_t)E * 16);
    float*  h1        = (float*) alloc((size_t)N * 32 * 4);
    float*  out2      = (float*) alloc((size_t)N * 64 * 4);
    const int NC = 30720;
    float*  aggbuf    = (float*) alloc((size_t)NC * 512 * 4);
    (void)ws_size; (void)n_in; (void)out_size;

    hipMemsetAsync(deg, 0, (size_t)N * 4, stream);
    hipMemsetAsync(bnsum1, 0, 128 * 8, stream);
    hipMemsetAsync(bnsum2, 0, 128 * 8, stream);

    int gE = (E + 255) / 256; if (gE > 4096) gE = 4096;
    int NB = (N + 1023) / 1024;

    k_count<<<gE, 256, 0, stream>>>(ei + E, E, deg);
    k_scan1<<<NB, 256, 0, stream>>>(deg, N, rowptr, blockSums);
    k_scan2<<<1, 256, 0, stream>>>(blockSums, NB, blockOff);
    k_scan3<<<(N + 255) / 256, 256, 0, stream>>>(rowptr, cursor, blockOff, N, E);
    k_fill<<<gE, 256, 0, stream>>>(ei, attr, E, cursor, csr_src, csr_bu, csr_bv);

    k_conv1<<<(N + 255) / 256, 256, 0, stream>>>(x, rowptr, csr_src, csr_bu, csr_bv,
                                                 w1, root1, b1, h1, N);
    k_bnstat<32><<<256, 256, 0, stream>>>(h1, N, bnsum1);
    k_bnfinal<<<1, 64, 0, stream>>>(bnsum1, g1, be1, 32, N, scsh1);
    k_bnelu<32><<<1024, 256, 0, stream>>>(h1, N, scsh1);

    for (int c0 = 0; c0 < N; c0 += NC) {
        int c1 = c0 + NC; if (c1 > N) c1 = N;
        int cnt = c1 - c0;
        k_agg<<<(cnt + 7) / 8, 512, 0, stream>>>(h1, rowptr, csr_src, csr_bu, csr_bv,
                                                 aggbuf, c0, c1);
        k_gemm<<<(cnt + 255) / 256, 256, 0, stream>>>(aggbuf, h1, w2, root2, b2,
                                                      out2, c0, c1);
    }

    k_bnstat<64><<<256, 256, 0, stream>>>(out2, N, bnsum2);
    k_bnfinal<<<1, 64, 0, stream>>>(bnsum2, g2, be2, 64, N, scsh2);
    k_bnelu<64><<<2048, 256, 0, stream>>>(out2, N, scsh2);

    int pairs = (N + 1) / 2;
    k_fc<<<(pairs + 255) / 256, 256, 0, stream>>>(out2, fc1w, fc1b, fc2w, fc2b, out, N);
}

// Round 3
// 1155.953 us; speedup vs baseline: 1.5588x; 1.2233x over previous
//
#include <hip/hip_runtime.h>
#include <hip/hip_fp16.h>
#include <math.h>

// ---------------------------------------------------------------------------
// SplineCNN (K=4, dim=2, deg=2). v3: 16B packed edge record (src + 6 fp16
// basis coeffs, 4th reconstructed from sum=1); fp16 agg buffer, single chunk.
// ---------------------------------------------------------------------------

__device__ __forceinline__ void bspline4(float a, float B[4]) {
    a = fminf(fmaxf(a, 0.f), 1.f);
    float v  = a * 2.0f;          // K - DEG = 2
    float kv = floorf(v);
    float t  = v - kv;
    int   ik = (int)kv;           // 0..2
    float b0 = 0.5f * (1.f - t) * (1.f - t);
    float b1 = (t - t * t) + 0.5f;
    float b2 = 0.5f * t * t;
    int c0 = ik;
    int c1 = ik + 1;
    int c2 = ik + 2; if (c2 > 3) c2 = 3;
#pragma unroll
    for (int j = 0; j < 4; ++j)
        B[j] = (c0 == j ? b0 : 0.f) + (c1 == j ? b1 : 0.f) + (c2 == j ? b2 : 0.f);
}

__device__ __forceinline__ float eluf(float x) {
    return x > 0.f ? x : expm1f(x);
}

// unpack 16B edge record -> src + bu[4] + bv[4]
__device__ __forceinline__ void unpack_edge(uint4 rec, int& src,
                                            float bu[4], float bv[4]) {
    src = (int)rec.x;
    float2 f01 = __half22float2(*(const __half2*)&rec.y);
    float2 f23 = __half22float2(*(const __half2*)&rec.z);
    float2 f45 = __half22float2(*(const __half2*)&rec.w);
    bu[0] = f01.x; bu[1] = f01.y; bu[2] = f23.x;
    bu[3] = 1.f - (bu[0] + bu[1] + bu[2]);
    bv[0] = f23.y; bv[1] = f45.x; bv[2] = f45.y;
    bv[3] = 1.f - (bv[0] + bv[1] + bv[2]);
}

// ---------------- CSR build ----------------

__global__ void k_count(const int* __restrict__ dst, int E, int* __restrict__ deg) {
    int i = blockIdx.x * blockDim.x + threadIdx.x;
    int stride = gridDim.x * blockDim.x;
    for (; i < E; i += stride) atomicAdd(&deg[dst[i]], 1);
}

__global__ void k_scan1(const int* __restrict__ deg, int N,
                        int* __restrict__ rowptr, int* __restrict__ blockSums) {
    __shared__ int wsum[4];
    int tid  = threadIdx.x;
    int base = blockIdx.x * 1024 + tid * 4;
    int d0 = (base + 0) < N ? deg[base + 0] : 0;
    int d1 = (base + 1) < N ? deg[base + 1] : 0;
    int d2 = (base + 2) < N ? deg[base + 2] : 0;
    int d3 = (base + 3) < N ? deg[base + 3] : 0;
    int s4 = d0 + d1 + d2 + d3;
    int lane = tid & 63, wid = tid >> 6;
    int inc = s4;
#pragma unroll
    for (int off = 1; off < 64; off <<= 1) {
        int t = __shfl_up(inc, off);
        if (lane >= off) inc += t;
    }
    if (lane == 63) wsum[wid] = inc;
    __syncthreads();
    if (tid == 0) {
        int acc = 0;
#pragma unroll
        for (int w = 0; w < 4; ++w) { int t = wsum[w]; wsum[w] = acc; acc += t; }
    }
    __syncthreads();
    int ebase = wsum[wid] + inc - s4;
    if ((base + 0) < N) rowptr[base + 0] = ebase;
    if ((base + 1) < N) rowptr[base + 1] = ebase + d0;
    if ((base + 2) < N) rowptr[base + 2] = ebase + d0 + d1;
    if ((base + 3) < N) rowptr[base + 3] = ebase + d0 + d1 + d2;
    if (tid == 255) blockSums[blockIdx.x] = ebase + s4;
}

__global__ void k_scan2(const int* __restrict__ blockSums, int NB, int* __restrict__ blockOff) {
    __shared__ int sh[256];
    int tid = threadIdx.x;
    int own = (tid < NB) ? blockSums[tid] : 0;
    sh[tid] = own;
    __syncthreads();
    for (int off = 1; off < 256; off <<= 1) {
        int v = (tid >= off) ? sh[tid - off] : 0;
        __syncthreads();
        sh[tid] += v;
        __syncthreads();
    }
    if (tid < NB) blockOff[tid] = sh[tid] - own;
}

__global__ void k_scan3(int* __restrict__ rowptr, int* __restrict__ cursor,
                        const int* __restrict__ blockOff, int N, int E) {
    int i = blockIdx.x * blockDim.x + threadIdx.x;
    if (i < N) {
        int v = rowptr[i] + blockOff[i >> 10];
        rowptr[i] = v;
        cursor[i] = v;
    }
    if (i == 0) rowptr[N] = E;
}

// fill CSR with packed 16B records
__global__ void k_fill(const int* __restrict__ ei, const float* __restrict__ attr, int E,
                       int* __restrict__ cursor, uint4* __restrict__ edges) {
    int i = blockIdx.x * blockDim.x + threadIdx.x;
    int stride = gridDim.x * blockDim.x;
    for (; i < E; i += stride) {
        int d = ei[E + i];
        int pos = atomicAdd(&cursor[d], 1);
        float Bu[4], Bv[4];
        bspline4(attr[2 * i + 0], Bu);
        bspline4(attr[2 * i + 1], Bv);
        __half2 p01 = __floats2half2_rn(Bu[0], Bu[1]);
        __half2 p23 = __floats2half2_rn(Bu[2], Bv[0]);
        __half2 p45 = __floats2half2_rn(Bv[1], Bv[2]);
        uint4 rec;
        rec.x = (unsigned)ei[i];
        rec.y = *(const unsigned*)&p01;
        rec.z = *(const unsigned*)&p23;
        rec.w = *(const unsigned*)&p45;
        edges[pos] = rec;
    }
}

// ---------------- Layer 1 conv (in=1 -> out=32), thread per node ----------------

__global__ void k_conv1(const float* __restrict__ x, const int* __restrict__ rowptr,
                        const uint4* __restrict__ edges,
                        const float* __restrict__ w1, const float* __restrict__ root1,
                        const float* __restrict__ b1, float* __restrict__ h1, int N) {
    __shared__ float w1s[16 * 32];
    __shared__ float r1s[32], b1s[32];
    int tid = threadIdx.x;
    for (int i = tid; i < 512; i += blockDim.x) w1s[i] = w1[i];
    if (tid < 32) { r1s[tid] = root1[tid]; b1s[tid] = b1[tid]; }
    __syncthreads();
    int n = blockIdx.x * blockDim.x + tid;
    if (n >= N) return;
    float agg[16] = {};
    int s = rowptr[n], e = rowptr[n + 1];
    for (int j = s; j < e; ++j) {
        uint4 rec = edges[j];
        int src; float bu[4], bv[4];
        unpack_edge(rec, src, bu, bv);
        float xs = x[src];
        float t0 = xs * bv[0], t1 = xs * bv[1], t2 = xs * bv[2], t3 = xs * bv[3];
        agg[0]  += bu[0] * t0; agg[1]  += bu[1] * t0; agg[2]  += bu[2] * t0; agg[3]  += bu[3] * t0;
        agg[4]  += bu[0] * t1; agg[5]  += bu[1] * t1; agg[6]  += bu[2] * t1; agg[7]  += bu[3] * t1;
        agg[8]  += bu[0] * t2; agg[9]  += bu[1] * t2; agg[10] += bu[2] * t2; agg[11] += bu[3] * t2;
        agg[12] += bu[0] * t3; agg[13] += bu[1] * t3; agg[14] += bu[2] * t3; agg[15] += bu[3] * t3;
    }
    float xn = x[n];
#pragma unroll 4
    for (int o = 0; o < 32; ++o) {
        float acc = b1s[o] + xn * r1s[o];
#pragma unroll
        for (int k = 0; k < 16; ++k) acc += agg[k] * w1s[k * 32 + o];
        h1[n * 32 + o] = acc;
    }
}

// ---------------- BatchNorm ----------------

template <int C>
__global__ void k_bnstat(const float* __restrict__ h, int N, double* __restrict__ sums) {
    __shared__ float sh1[C], sh2[C];
    int tid  = blockIdx.x * blockDim.x + threadIdx.x;
    int c    = tid & (C - 1);
    int row  = tid / C;
    int rstr = (gridDim.x * blockDim.x) / C;
    float s1 = 0.f, s2 = 0.f;
    for (int r = row; r < N; r += rstr) {
        float v = h[(size_t)r * C + c];
        s1 += v; s2 += v * v;
    }
    if (threadIdx.x < C) { sh1[threadIdx.x] = 0.f; sh2[threadIdx.x] = 0.f; }
    __syncthreads();
    atomicAdd(&sh1[c], s1);
    atomicAdd(&sh2[c], s2);
    __syncthreads();
    if (threadIdx.x < C) {
        atomicAdd(&sums[threadIdx.x],     (double)sh1[threadIdx.x]);
        atomicAdd(&sums[C + threadIdx.x], (double)sh2[threadIdx.x]);
    }
}

__global__ void k_bnfinal(const double* __restrict__ sums, const float* __restrict__ gamma,
                          const float* __restrict__ beta, int C, int N, float* __restrict__ scsh) {
    int c = threadIdx.x;
    if (c < C) {
        double m   = sums[c] / (double)N;
        double var = sums[C + c] / (double)N - m * m;
        float vpe  = (float)var + 1e-5f;
        float sc   = gamma[c] / sqrtf(vpe);
        scsh[c]     = sc;
        scsh[C + c] = beta[c] - (float)m * sc;
    }
}

template <int C>
__global__ void k_bnelu(float* __restrict__ h, int N, const float* __restrict__ scsh) {
    int total = N * C / 4;
    int i = blockIdx.x * blockDim.x + threadIdx.x;
    int stride = gridDim.x * blockDim.x;
    float4* hp = (float4*)h;
    for (; i < total; i += stride) {
        float4 v = hp[i];
        int c0 = (i * 4) & (C - 1);
        v.x = eluf(v.x * scsh[c0 + 0] + scsh[C + c0 + 0]);
        v.y = eluf(v.y * scsh[c0 + 1] + scsh[C + c0 + 1]);
        v.z = eluf(v.z * scsh[c0 + 2] + scsh[C + c0 + 2]);
        v.w = eluf(v.w * scsh[c0 + 3] + scsh[C + c0 + 3]);
        hp[i] = v;
    }
}

// ---------------- Layer 2: aggregation (wave per node) -> agg[nloc][512] fp16 ----------------

__global__ __launch_bounds__(512) void k_agg(
    const float* __restrict__ h1, const int* __restrict__ rowptr,
    const uint4* __restrict__ edges, __half* __restrict__ agg,
    int n0, int n1) {
    int tid   = threadIdx.x;
    int lane  = tid & 63;
    int w     = tid >> 6;
    int c     = lane & 31;
    int khalf = lane >> 5;
    int n = n0 + blockIdx.x * 8 + w;
    if (n >= n1) return;
    float a[8] = {};
    int s = __builtin_amdgcn_readfirstlane(rowptr[n]);
    int e = __builtin_amdgcn_readfirstlane(rowptr[n + 1]);
    for (int j = s; j < e; ++j) {
        uint4 rec = edges[j];
        int src; float bu[4], bv[4];
        unpack_edge(rec, src, bu, bv);
        float hc  = h1[(size_t)src * 32 + c];
        float bvlo = khalf ? bv[2] : bv[0];
        float bvhi = khalf ? bv[3] : bv[1];
        float t0 = hc * bvlo, t1 = hc * bvhi;
        a[0] += bu[0] * t0; a[1] += bu[1] * t0; a[2] += bu[2] * t0; a[3] += bu[3] * t0;
        a[4] += bu[0] * t1; a[5] += bu[1] * t1; a[6] += bu[2] * t1; a[7] += bu[3] * t1;
    }
    __half* ag = agg + (size_t)(n - n0) * 512 + khalf * 256 + c;
#pragma unroll
    for (int q = 0; q < 8; ++q) ag[q * 32] = __float2half(a[q]);
}

// ---------------- Layer 2: GEMM agg[cnt,512](fp16) @ w2[512,64] + h1 @ root2 + b2 ----------------

__global__ __launch_bounds__(256) void k_gemm(
    const __half* __restrict__ agg, const float* __restrict__ h1,
    const float* __restrict__ w2, const float* __restrict__ root2,
    const float* __restrict__ b2, float* __restrict__ out2,
    int n0, int n1) {
    __shared__ float w2s[64 * 64];
    int tid   = threadIdx.x;
    int tc    = tid & 7;
    int tr    = tid >> 3;
    int obase = tc * 8;
    int cnt   = n1 - n0;
    int base  = blockIdx.x * 256 + tr * 8;

    float acc[8][8];
    float4 blo = *(const float4*)(b2 + obase);
    float4 bhi = *(const float4*)(b2 + obase + 4);
#pragma unroll
    for (int i = 0; i < 8; ++i) {
        acc[i][0] = blo.x; acc[i][1] = blo.y; acc[i][2] = blo.z; acc[i][3] = blo.w;
        acc[i][4] = bhi.x; acc[i][5] = bhi.y; acc[i][6] = bhi.z; acc[i][7] = bhi.w;
    }
    const __half* arow[8];
    const float* hrow[8];
#pragma unroll
    for (int i = 0; i < 8; ++i) {
        int r = base + i; if (r > cnt - 1) r = cnt - 1;
        arow[i] = agg + (size_t)r * 512;
        hrow[i] = h1 + (size_t)(n0 + r) * 32;
    }

    for (int kc = 0; kc < 512; kc += 64) {
        __syncthreads();
        const float4* s4 = (const float4*)(w2 + kc * 64);
        float4* d4 = (float4*)w2s;
#pragma unroll
        for (int t = 0; t < 4; ++t) d4[tid + t * 256] = s4[tid + t * 256];
        __syncthreads();
#pragma unroll 2
        for (int k4 = 0; k4 < 64; k4 += 4) {
            float av[8][4];
#pragma unroll
            for (int i = 0; i < 8; ++i) {
                uint2 raw = *(const uint2*)(arow[i] + kc + k4);
                float2 f01 = __half22float2(*(const __half2*)&raw.x);
                float2 f23 = __half22float2(*(const __half2*)&raw.y);
                av[i][0] = f01.x; av[i][1] = f01.y; av[i][2] = f23.x; av[i][3] = f23.y;
            }
#pragma unroll
            for (int kk = 0; kk < 4; ++kk) {
                const float* wp = w2s + (k4 + kk) * 64 + obase;
                float4 wlo = *(const float4*)(wp);
                float4 whi = *(const float4*)(wp + 4);
#pragma unroll
                for (int i = 0; i < 8; ++i) {
                    float a = av[i][kk];
                    acc[i][0] += a * wlo.x; acc[i][1] += a * wlo.y;
                    acc[i][2] += a * wlo.z; acc[i][3] += a * wlo.w;
                    acc[i][4] += a * whi.x; acc[i][5] += a * whi.y;
                    acc[i][6] += a * whi.z; acc[i][7] += a * whi.w;
                }
            }
        }
    }
    __syncthreads();
    {
        const float4* s4 = (const float4*)root2;
        float4* d4 = (float4*)w2s;
#pragma unroll
        for (int t = 0; t < 2; ++t) d4[tid + t * 256] = s4[tid + t * 256];
    }
    __syncthreads();
#pragma unroll
    for (int k4 = 0; k4 < 32; k4 += 4) {
        float4 hv[8];
#pragma unroll
        for (int i = 0; i < 8; ++i) hv[i] = *(const float4*)(hrow[i] + k4);
#pragma unroll
        for (int kk = 0; kk < 4; ++kk) {
            const float* wp = w2s + (k4 + kk) * 64 + obase;
            float4 wlo = *(const float4*)(wp);
            float4 whi = *(const float4*)(wp + 4);
#pragma unroll
            for (int i = 0; i < 8; ++i) {
                float a = (kk == 0) ? hv[i].x : (kk == 1) ? hv[i].y
                        : (kk == 2) ? hv[i].z : hv[i].w;
                acc[i][0] += a * wlo.x; acc[i][1] += a * wlo.y;
                acc[i][2] += a * wlo.z; acc[i][3] += a * wlo.w;
                acc[i][4] += a * whi.x; acc[i][5] += a * whi.y;
                acc[i][6] += a * whi.z; acc[i][7] += a * whi.w;
            }
        }
    }
#pragma unroll
    for (int i = 0; i < 8; ++i) {
        int r = base + i;
        if (r < cnt) {
            float* op = out2 + (size_t)(n0 + r) * 64 + obase;
            *(float4*)op       = make_float4(acc[i][0], acc[i][1], acc[i][2], acc[i][3]);
            *(float4*)(op + 4) = make_float4(acc[i][4], acc[i][5], acc[i][6], acc[i][7]);
        }
    }
}

// ---------------- Final MLP: 64 -> 128 (ELU) -> 1, two nodes per thread ----------------

__global__ __launch_bounds__(256) void k_fc(
    const float* __restrict__ h2, const float* __restrict__ fc1w,
    const float* __restrict__ fc1b, const float* __restrict__ fc2w,
    const float* __restrict__ fc2b, float* __restrict__ out, int N) {
    __shared__ float w1t[128 * 64];  // transposed [o][cd]
    __shared__ float b1s[128], w2s[128];
    int tid = threadIdx.x;
    for (int i = tid; i < 8192; i += 256) {
        int o = i >> 6, cd = i & 63;
        w1t[o * 64 + cd] = fc1w[cd * 128 + o];
    }
    if (tid < 128) { b1s[tid] = fc1b[tid]; w2s[tid] = fc2w[tid]; }
    __syncthreads();
    int n0 = (blockIdx.x * 256 + tid) * 2;
    if (n0 >= N) return;
    int n1i = (n0 + 1 < N) ? n0 + 1 : n0;
    float h0[64], h1v[64];
    {
        const float4* p0 = (const float4*)(h2 + (size_t)n0 * 64);
        const float4* p1 = (const float4*)(h2 + (size_t)n1i * 64);
#pragma unroll
        for (int i = 0; i < 16; ++i) {
            float4 a = p0[i];
            h0[4 * i] = a.x; h0[4 * i + 1] = a.y; h0[4 * i + 2] = a.z; h0[4 * i + 3] = a.w;
            float4 b = p1[i];
            h1v[4 * i] = b.x; h1v[4 * i + 1] = b.y; h1v[4 * i + 2] = b.z; h1v[4 * i + 3] = b.w;
        }
    }
    float acc0 = fc2b[0], acc1 = acc0;
    for (int o = 0; o < 128; ++o) {
        float p0 = b1s[o], p1 = p0;
        const float4* wp = (const float4*)(w1t + o * 64);
#pragma unroll
        for (int q = 0; q < 16; ++q) {
            float4 wv = wp[q];
            p0 += h0[4 * q] * wv.x + h0[4 * q + 1] * wv.y + h0[4 * q + 2] * wv.z + h0[4 * q + 3] * wv.w;
            p1 += h1v[4 * q] * wv.x + h1v[4 * q + 1] * wv.y + h1v[4 * q + 2] * wv.z + h1v[4 * q + 3] * wv.w;
        }
        float w2v = w2s[o];
        acc0 += eluf(p0) * w2v;
        acc1 += eluf(p1) * w2v;
    }
    out[n0] = acc0;
    if (n0 + 1 < N) out[n0 + 1] = acc1;
}

// ---------------------------------------------------------------------------

extern "C" void kernel_launch(void* const* d_in, const int* in_sizes, int n_in,
                              void* d_out, int out_size, void* d_ws, size_t ws_size,
                              hipStream_t stream) {
    const float* x     = (const float*)d_in[0];
    const int*   ei    = (const int*)  d_in[1];
    const float* attr  = (const float*)d_in[2];
    const float* w1    = (const float*)d_in[3];
    const float* root1 = (const float*)d_in[4];
    const float* b1    = (const float*)d_in[5];
    const float* g1    = (const float*)d_in[6];
    const float* be1   = (const float*)d_in[7];
    const float* w2    = (const float*)d_in[8];
    const float* root2 = (const float*)d_in[9];
    const float* b2    = (const float*)d_in[10];
    const float* g2    = (const float*)d_in[11];
    const float* be2   = (const float*)d_in[12];
    const float* fc1w  = (const float*)d_in[13];
    const float* fc1b  = (const float*)d_in[14];
    const float* fc2w  = (const float*)d_in[15];
    const float* fc2b  = (const float*)d_in[16];
    float* out = (float*)d_out;

    int N = in_sizes[0];          // 150000
    int E = in_sizes[1] / 2;      // 3000000

    char* ws = (char*)d_ws;
    size_t off = 0;
    auto alloc = [&](size_t bytes) -> void* {
        void* p = ws + off;
        off = (off + bytes + 255) & ~(size_t)255;
        return p;
    };
    int*    rowptr    = (int*)   alloc((size_t)(N + 1) * 4);
    int*    deg       = (int*)   alloc((size_t)N * 4);
    int*    cursor    = (int*)   alloc((size_t)N * 4);
    int*    blockSums = (int*)   alloc(1024 * 4);
    int*    blockOff  = (int*)   alloc(1024 * 4);
    double* bnsum1    = (double*)alloc(128 * 8);
    double* bnsum2    = (double*)alloc(128 * 8);
    float*  scsh1     = (float*) alloc(64 * 4);
    float*  scsh2     = (float*) alloc(128 * 4);
    uint4*  edges     = (uint4*) alloc((size_t)E * 16);
    float*  h1        = (float*) alloc((size_t)N * 32 * 4);
    float*  out2      = (float*) alloc((size_t)N * 64 * 4);
    // agg buffer takes the remainder of the workspace (fp16, 512/node)
    size_t avail = (ws_size > off) ? (ws_size - off) : 0;
    int NC = (int)(avail / (512 * sizeof(__half)));
    if (NC > N) NC = N;
    NC &= ~255;
    if (NC < 256) NC = 256;
    __half* aggbuf = (__half*)alloc((size_t)NC * 512 * sizeof(__half));
    (void)n_in; (void)out_size;

    hipMemsetAsync(deg, 0, (size_t)N * 4, stream);
    hipMemsetAsync(bnsum1, 0, 128 * 8, stream);
    hipMemsetAsync(bnsum2, 0, 128 * 8, stream);

    int gE = (E + 255) / 256; if (gE > 4096) gE = 4096;
    int NB = (N + 1023) / 1024;

    k_count<<<gE, 256, 0, stream>>>(ei + E, E, deg);
    k_scan1<<<NB, 256, 0, stream>>>(deg, N, rowptr, blockSums);
    k_scan2<<<1, 256, 0, stream>>>(blockSums, NB, blockOff);
    k_scan3<<<(N + 255) / 256, 256, 0, stream>>>(rowptr, cursor, blockOff, N, E);
    k_fill<<<gE, 256, 0, stream>>>(ei, attr, E, cursor, edges);

    k_conv1<<<(N + 255) / 256, 256, 0, stream>>>(x, rowptr, edges, w1, root1, b1, h1, N);
    k_bnstat<32><<<256, 256, 0, stream>>>(h1, N, bnsum1);
    k_bnfinal<<<1, 64, 0, stream>>>(bnsum1, g1, be1, 32, N, scsh1);
    k_bnelu<32><<<1024, 256, 0, stream>>>(h1, N, scsh1);

    for (int c0 = 0; c0 < N; c0 += NC) {
        int c1 = c0 + NC; if (c1 > N) c1 = N;
        int cnt = c1 - c0;
        k_agg<<<(cnt + 7) / 8, 512, 0, stream>>>(h1, rowptr, edges, aggbuf, c0, c1);
        k_gemm<<<(cnt + 255) / 256, 256, 0, stream>>>(aggbuf, h1, w2, root2, b2,
                                                      out2, c0, c1);
    }

    k_bnstat<64><<<256, 256, 0, stream>>>(out2, N, bnsum2);
    k_bnfinal<<<1, 64, 0, stream>>>(bnsum2, g2, be2, 64, N, scsh2);
    k_bnelu<64><<<2048, 256, 0, stream>>>(out2, N, scsh2);

    int pairs = (N + 1) / 2;
    k_fc<<<(pairs + 255) / 256, 256, 0, stream>>>(out2, fc1w, fc1b, fc2w, fc2b, out, N);
}

// Round 4
// 822.745 us; speedup vs baseline: 2.1901x; 1.4050x over previous
//
#include <hip/hip_runtime.h>
#include <hip/hip_fp16.h>
#include <math.h>

// ---------------------------------------------------------------------------
// SplineCNN (K=4, dim=2, deg=2). v4: MFMA for the conv2 GEMM
// ([N,512]@[512,64] + root fold-in as K-step 16), fragment-ordered agg/w2.
// ---------------------------------------------------------------------------

typedef _Float16 half8 __attribute__((ext_vector_type(8)));
typedef float    f32x4 __attribute__((ext_vector_type(4)));

__device__ __forceinline__ void bspline4(float a, float B[4]) {
    a = fminf(fmaxf(a, 0.f), 1.f);
    float v  = a * 2.0f;          // K - DEG = 2
    float kv = floorf(v);
    float t  = v - kv;
    int   ik = (int)kv;           // 0..2
    float b0 = 0.5f * (1.f - t) * (1.f - t);
    float b1 = (t - t * t) + 0.5f;
    float b2 = 0.5f * t * t;
    int c0 = ik;
    int c1 = ik + 1;
    int c2 = ik + 2; if (c2 > 3) c2 = 3;
#pragma unroll
    for (int j = 0; j < 4; ++j)
        B[j] = (c0 == j ? b0 : 0.f) + (c1 == j ? b1 : 0.f) + (c2 == j ? b2 : 0.f);
}

__device__ __forceinline__ float eluf(float x) {
    return x > 0.f ? x : expm1f(x);
}

// unpack 16B edge record -> src + bu[4] + bv[4]
__device__ __forceinline__ void unpack_edge(uint4 rec, int& src,
                                            float bu[4], float bv[4]) {
    src = (int)rec.x;
    float2 f01 = __half22float2(*(const __half2*)&rec.y);
    float2 f23 = __half22float2(*(const __half2*)&rec.z);
    float2 f45 = __half22float2(*(const __half2*)&rec.w);
    bu[0] = f01.x; bu[1] = f01.y; bu[2] = f23.x;
    bu[3] = 1.f - (bu[0] + bu[1] + bu[2]);
    bv[0] = f23.y; bv[1] = f45.x; bv[2] = f45.y;
    bv[3] = 1.f - (bv[0] + bv[1] + bv[2]);
}

// ---------------- CSR build ----------------

__global__ void k_count(const int* __restrict__ dst, int E, int* __restrict__ deg) {
    int i = blockIdx.x * blockDim.x + threadIdx.x;
    int stride = gridDim.x * blockDim.x;
    for (; i < E; i += stride) atomicAdd(&deg[dst[i]], 1);
}

__global__ void k_scan1(const int* __restrict__ deg, int N,
                        int* __restrict__ rowptr, int* __restrict__ blockSums) {
    __shared__ int wsum[4];
    int tid  = threadIdx.x;
    int base = blockIdx.x * 1024 + tid * 4;
    int d0 = (base + 0) < N ? deg[base + 0] : 0;
    int d1 = (base + 1) < N ? deg[base + 1] : 0;
    int d2 = (base + 2) < N ? deg[base + 2] : 0;
    int d3 = (base + 3) < N ? deg[base + 3] : 0;
    int s4 = d0 + d1 + d2 + d3;
    int lane = tid & 63, wid = tid >> 6;
    int inc = s4;
#pragma unroll
    for (int off = 1; off < 64; off <<= 1) {
        int t = __shfl_up(inc, off);
        if (lane >= off) inc += t;
    }
    if (lane == 63) wsum[wid] = inc;
    __syncthreads();
    if (tid == 0) {
        int acc = 0;
#pragma unroll
        for (int w = 0; w < 4; ++w) { int t = wsum[w]; wsum[w] = acc; acc += t; }
    }
    __syncthreads();
    int ebase = wsum[wid] + inc - s4;
    if ((base + 0) < N) rowptr[base + 0] = ebase;
    if ((base + 1) < N) rowptr[base + 1] = ebase + d0;
    if ((base + 2) < N) rowptr[base + 2] = ebase + d0 + d1;
    if ((base + 3) < N) rowptr[base + 3] = ebase + d0 + d1 + d2;
    if (tid == 255) blockSums[blockIdx.x] = ebase + s4;
}

__global__ void k_scan2(const int* __restrict__ blockSums, int NB, int* __restrict__ blockOff) {
    __shared__ int sh[256];
    int tid = threadIdx.x;
    int own = (tid < NB) ? blockSums[tid] : 0;
    sh[tid] = own;
    __syncthreads();
    for (int off = 1; off < 256; off <<= 1) {
        int v = (tid >= off) ? sh[tid - off] : 0;
        __syncthreads();
        sh[tid] += v;
        __syncthreads();
    }
    if (tid < NB) blockOff[tid] = sh[tid] - own;
}

__global__ void k_scan3(int* __restrict__ rowptr, int* __restrict__ cursor,
                        const int* __restrict__ blockOff, int N, int E) {
    int i = blockIdx.x * blockDim.x + threadIdx.x;
    if (i < N) {
        int v = rowptr[i] + blockOff[i >> 10];
        rowptr[i] = v;
        cursor[i] = v;
    }
    if (i == 0) rowptr[N] = E;
}

// fill CSR with packed 16B records
__global__ void k_fill(const int* __restrict__ ei, const float* __restrict__ attr, int E,
                       int* __restrict__ cursor, uint4* __restrict__ edges) {
    int i = blockIdx.x * blockDim.x + threadIdx.x;
    int stride = gridDim.x * blockDim.x;
    for (; i < E; i += stride) {
        int d = ei[E + i];
        int pos = atomicAdd(&cursor[d], 1);
        float Bu[4], Bv[4];
        bspline4(attr[2 * i + 0], Bu);
        bspline4(attr[2 * i + 1], Bv);
        __half2 p01 = __floats2half2_rn(Bu[0], Bu[1]);
        __half2 p23 = __floats2half2_rn(Bu[2], Bv[0]);
        __half2 p45 = __floats2half2_rn(Bv[1], Bv[2]);
        uint4 rec;
        rec.x = (unsigned)ei[i];
        rec.y = *(const unsigned*)&p01;
        rec.z = *(const unsigned*)&p23;
        rec.w = *(const unsigned*)&p45;
        edges[pos] = rec;
    }
}

// ---------------- w2 + root2 pre-pack into B-fragment order (fp16) ----------------
// slot f = ((s*4 + t)*64 + lane)*8 + j ; s in [0,16] (s==16 -> root2 rows).
// For s<16: permuted k-position p = s*32 + (lane>>4)*8 + j; p decodes to the
// agg storage order (lane_a = p>>3 wrote kidx=(lane_a>>5)*8+(p&7), c=lane_a&31).

__global__ void k_w2pack(const float* __restrict__ w2, const float* __restrict__ root2,
                         _Float16* __restrict__ w2f) {
    int f = blockIdx.x * blockDim.x + threadIdx.x;
    int stride = gridDim.x * blockDim.x;
    for (; f < 34816; f += stride) {
        int j = f & 7, l = (f >> 3) & 63, t = (f >> 9) & 3;
        int o = t * 16 + (l & 15);
        float v;
        if (f < 32768) {
            int s = f >> 11;
            int p = s * 32 + ((l >> 4) << 3) + j;
            int lane_a = p >> 3, q = p & 7;
            int c = lane_a & 31, kidx = ((lane_a >> 5) << 3) + q;
            v = w2[(kidx * 32 + c) * 64 + o];
        } else {
            int c = ((l >> 4) << 3) + j;
            v = root2[c * 64 + o];
        }
        w2f[f] = (_Float16)v;
    }
}

// ---------------- Layer 1 conv (in=1 -> out=32), thread per node ----------------

__global__ void k_conv1(const float* __restrict__ x, const int* __restrict__ rowptr,
                        const uint4* __restrict__ edges,
                        const float* __restrict__ w1, const float* __restrict__ root1,
                        const float* __restrict__ b1, float* __restrict__ h1, int N) {
    __shared__ float w1s[16 * 32];
    __shared__ float r1s[32], b1s[32];
    int tid = threadIdx.x;
    for (int i = tid; i < 512; i += blockDim.x) w1s[i] = w1[i];
    if (tid < 32) { r1s[tid] = root1[tid]; b1s[tid] = b1[tid]; }
    __syncthreads();
    int n = blockIdx.x * blockDim.x + tid;
    if (n >= N) return;
    float agg[16] = {};
    int s = rowptr[n], e = rowptr[n + 1];
    for (int j = s; j < e; ++j) {
        uint4 rec = edges[j];
        int src; float bu[4], bv[4];
        unpack_edge(rec, src, bu, bv);
        float xs = x[src];
        float t0 = xs * bv[0], t1 = xs * bv[1], t2 = xs * bv[2], t3 = xs * bv[3];
        agg[0]  += bu[0] * t0; agg[1]  += bu[1] * t0; agg[2]  += bu[2] * t0; agg[3]  += bu[3] * t0;
        agg[4]  += bu[0] * t1; agg[5]  += bu[1] * t1; agg[6]  += bu[2] * t1; agg[7]  += bu[3] * t1;
        agg[8]  += bu[0] * t2; agg[9]  += bu[1] * t2; agg[10] += bu[2] * t2; agg[11] += bu[3] * t2;
        agg[12] += bu[0] * t3; agg[13] += bu[1] * t3; agg[14] += bu[2] * t3; agg[15] += bu[3] * t3;
    }
    float xn = x[n];
#pragma unroll 4
    for (int o = 0; o < 32; ++o) {
        float acc = b1s[o] + xn * r1s[o];
#pragma unroll
        for (int k = 0; k < 16; ++k) acc += agg[k] * w1s[k * 32 + o];
        h1[n * 32 + o] = acc;
    }
}

// ---------------- BatchNorm ----------------

template <int C>
__global__ void k_bnstat(const float* __restrict__ h, int N, double* __restrict__ sums) {
    __shared__ float sh1[C], sh2[C];
    int tid  = blockIdx.x * blockDim.x + threadIdx.x;
    int c    = tid & (C - 1);
    int row  = tid / C;
    int rstr = (gridDim.x * blockDim.x) / C;
    float s1 = 0.f, s2 = 0.f;
    for (int r = row; r < N; r += rstr) {
        float v = h[(size_t)r * C + c];
        s1 += v; s2 += v * v;
    }
    if (threadIdx.x < C) { sh1[threadIdx.x] = 0.f; sh2[threadIdx.x] = 0.f; }
    __syncthreads();
    atomicAdd(&sh1[c], s1);
    atomicAdd(&sh2[c], s2);
    __syncthreads();
    if (threadIdx.x < C) {
        atomicAdd(&sums[threadIdx.x],     (double)sh1[threadIdx.x]);
        atomicAdd(&sums[C + threadIdx.x], (double)sh2[threadIdx.x]);
    }
}

__global__ void k_bnfinal(const double* __restrict__ sums, const float* __restrict__ gamma,
                          const float* __restrict__ beta, int C, int N, float* __restrict__ scsh) {
    int c = threadIdx.x;
    if (c < C) {
        double m   = sums[c] / (double)N;
        double var = sums[C + c] / (double)N - m * m;
        float vpe  = (float)var + 1e-5f;
        float sc   = gamma[c] / sqrtf(vpe);
        scsh[c]     = sc;
        scsh[C + c] = beta[c] - (float)m * sc;
    }
}

// BN + ELU for h1 (C=32), output fp16 copy only (fp32 h1 dead afterwards)
__global__ void k_bnelu32h(const float* __restrict__ h, int N,
                           const float* __restrict__ scsh, _Float16* __restrict__ hh) {
    int total = N * 4;   // groups of 8 floats
    int i = blockIdx.x * blockDim.x + threadIdx.x;
    int stride = gridDim.x * blockDim.x;
    const float4* hp = (const float4*)h;
    for (; i < total; i += stride) {
        float4 v0 = hp[2 * i], v1 = hp[2 * i + 1];
        int c0 = (i * 8) & 31;
        half8 r;
        r[0] = (_Float16)eluf(v0.x * scsh[c0 + 0] + scsh[32 + c0 + 0]);
        r[1] = (_Float16)eluf(v0.y * scsh[c0 + 1] + scsh[32 + c0 + 1]);
        r[2] = (_Float16)eluf(v0.z * scsh[c0 + 2] + scsh[32 + c0 + 2]);
        r[3] = (_Float16)eluf(v0.w * scsh[c0 + 3] + scsh[32 + c0 + 3]);
        r[4] = (_Float16)eluf(v1.x * scsh[c0 + 4] + scsh[32 + c0 + 4]);
        r[5] = (_Float16)eluf(v1.y * scsh[c0 + 5] + scsh[32 + c0 + 5]);
        r[6] = (_Float16)eluf(v1.z * scsh[c0 + 6] + scsh[32 + c0 + 6]);
        r[7] = (_Float16)eluf(v1.w * scsh[c0 + 7] + scsh[32 + c0 + 7]);
        *(half8*)(hh + (size_t)i * 8) = r;
    }
}

template <int C>
__global__ void k_bnelu(float* __restrict__ h, int N, const float* __restrict__ scsh) {
    int total = N * C / 4;
    int i = blockIdx.x * blockDim.x + threadIdx.x;
    int stride = gridDim.x * blockDim.x;
    float4* hp = (float4*)h;
    for (; i < total; i += stride) {
        float4 v = hp[i];
        int c0 = (i * 4) & (C - 1);
        v.x = eluf(v.x * scsh[c0 + 0] + scsh[C + c0 + 0]);
        v.y = eluf(v.y * scsh[c0 + 1] + scsh[C + c0 + 1]);
        v.z = eluf(v.z * scsh[c0 + 2] + scsh[C + c0 + 2]);
        v.w = eluf(v.w * scsh[c0 + 3] + scsh[C + c0 + 3]);
        hp[i] = v;
    }
}

// ---------------- Layer 2: aggregation (wave per node), A-frag-order fp16 out ----------------

__global__ __launch_bounds__(512) void k_agg(
    const _Float16* __restrict__ h1h, const int* __restrict__ rowptr,
    const uint4* __restrict__ edges, _Float16* __restrict__ agg,
    int n0, int n1) {
    int tid   = threadIdx.x;
    int lane  = tid & 63;
    int w     = tid >> 6;
    int c     = lane & 31;
    int khalf = lane >> 5;
    int n = n0 + blockIdx.x * 8 + w;
    if (n >= n1) return;
    float a[8] = {};
    int s = __builtin_amdgcn_readfirstlane(rowptr[n]);
    int e = __builtin_amdgcn_readfirstlane(rowptr[n + 1]);
    for (int j = s; j < e; ++j) {
        uint4 rec = edges[j];
        int src; float bu[4], bv[4];
        unpack_edge(rec, src, bu, bv);
        float hc = (float)h1h[(size_t)src * 32 + c];
        float bvlo = khalf ? bv[2] : bv[0];
        float bvhi = khalf ? bv[3] : bv[1];
        float t0 = hc * bvlo, t1 = hc * bvhi;
        a[0] += bu[0] * t0; a[1] += bu[1] * t0; a[2] += bu[2] * t0; a[3] += bu[3] * t0;
        a[4] += bu[0] * t1; a[5] += bu[1] * t1; a[6] += bu[2] * t1; a[7] += bu[3] * t1;
    }
    half8 hv;
#pragma unroll
    for (int q = 0; q < 8; ++q) hv[q] = (_Float16)a[q];
    *(half8*)(agg + (size_t)(n - n0) * 512 + lane * 8) = hv;   // coalesced 16B/lane
}

// ---------------- Layer 2: MFMA GEMM  out2 = [agg|h1h] @ w2f + b2 ----------------
// wave handles 16 nodes x 64 outputs; K = 17 steps of 32 (step 16 = root term).

__global__ __launch_bounds__(256) void k_gemm2(
    const _Float16* __restrict__ agg, const _Float16* __restrict__ h1h,
    const _Float16* __restrict__ w2f, const float* __restrict__ b2,
    float* __restrict__ out2, int n0, int n1, int ntiles) {
    extern __shared__ _Float16 w2s[];
    int tid = threadIdx.x;
    {
        const uint4* s4 = (const uint4*)w2f;
        uint4* d4 = (uint4*)w2s;
        for (int i = tid; i < 4352; i += 256) d4[i] = s4[i];   // 69632 B
    }
    __syncthreads();
    const half8* bp = (const half8*)w2s;
    int l   = tid & 63, w = tid >> 6;
    int klo = (l >> 4) << 3;
    int m   = l & 15;
    float bv0 = b2[m], bv1 = b2[16 + m], bv2 = b2[32 + m], bv3 = b2[48 + m];
    for (int tile = blockIdx.x; tile < ntiles; tile += gridDim.x) {
        int wavebase = n0 + tile * 64 + w * 16;
        if (wavebase >= n1) continue;
        int arow = wavebase + m; if (arow > n1 - 1) arow = n1 - 1;
        const half8* ap = (const half8*)(agg + (size_t)(arow - n0) * 512 + klo);
        f32x4 acc0 = {0.f,0.f,0.f,0.f}, acc1 = acc0, acc2 = acc0, acc3 = acc0;
#pragma unroll
        for (int s = 0; s < 16; ++s) {
            half8 a = ap[s * 4];
            int bi = (s << 8) + l;
            acc0 = __builtin_amdgcn_mfma_f32_16x16x32_f16(a, bp[bi      ], acc0, 0, 0, 0);
            acc1 = __builtin_amdgcn_mfma_f32_16x16x32_f16(a, bp[bi +  64], acc1, 0, 0, 0);
            acc2 = __builtin_amdgcn_mfma_f32_16x16x32_f16(a, bp[bi + 128], acc2, 0, 0, 0);
            acc3 = __builtin_amdgcn_mfma_f32_16x16x32_f16(a, bp[bi + 192], acc3, 0, 0, 0);
        }
        {   // root term: K-step 16, A = h1h[arow][klo..klo+7]
            half8 a = *(const half8*)(h1h + (size_t)arow * 32 + klo);
            int bi = (16 << 8) + l;
            acc0 = __builtin_amdgcn_mfma_f32_16x16x32_f16(a, bp[bi      ], acc0, 0, 0, 0);
            acc1 = __builtin_amdgcn_mfma_f32_16x16x32_f16(a, bp[bi +  64], acc1, 0, 0, 0);
            acc2 = __builtin_amdgcn_mfma_f32_16x16x32_f16(a, bp[bi + 128], acc2, 0, 0, 0);
            acc3 = __builtin_amdgcn_mfma_f32_16x16x32_f16(a, bp[bi + 192], acc3, 0, 0, 0);
        }
        int rbase = wavebase + ((l >> 4) << 2);   // C/D: row=(lane>>4)*4+reg, col=lane&15
#pragma unroll
        for (int r = 0; r < 4; ++r) {
            int node = rbase + r;
            if (node < n1) {
                size_t o = (size_t)node * 64;
                out2[o + m]      = acc0[r] + bv0;
                out2[o + 16 + m] = acc1[r] + bv1;
                out2[o + 32 + m] = acc2[r] + bv2;
                out2[o + 48 + m] = acc3[r] + bv3;
            }
        }
    }
}

// ---------------- Final MLP: 64 -> 128 (ELU) -> 1, two nodes per thread ----------------

__global__ __launch_bounds__(256) void k_fc(
    const float* __restrict__ h2, const float* __restrict__ fc1w,
    const float* __restrict__ fc1b, const float* __restrict__ fc2w,
    const float* __restrict__ fc2b, float* __restrict__ out, int N) {
    __shared__ float w1t[128 * 64];  // transposed [o][cd]
    __shared__ float b1s[128], w2s[128];
    int tid = threadIdx.x;
    for (int i = tid; i < 8192; i += 256) {
        int o = i >> 6, cd = i & 63;
        w1t[o * 64 + cd] = fc1w[cd * 128 + o];
    }
    if (tid < 128) { b1s[tid] = fc1b[tid]; w2s[tid] = fc2w[tid]; }
    __syncthreads();
    int n0 = (blockIdx.x * 256 + tid) * 2;
    if (n0 >= N) return;
    int n1i = (n0 + 1 < N) ? n0 + 1 : n0;
    float h0[64], h1v[64];
    {
        const float4* p0 = (const float4*)(h2 + (size_t)n0 * 64);
        const float4* p1 = (const float4*)(h2 + (size_t)n1i * 64);
#pragma unroll
        for (int i = 0; i < 16; ++i) {
            float4 a = p0[i];
            h0[4 * i] = a.x; h0[4 * i + 1] = a.y; h0[4 * i + 2] = a.z; h0[4 * i + 3] = a.w;
            float4 b = p1[i];
            h1v[4 * i] = b.x; h1v[4 * i + 1] = b.y; h1v[4 * i + 2] = b.z; h1v[4 * i + 3] = b.w;
        }
    }
    float acc0 = fc2b[0], acc1 = acc0;
    for (int o = 0; o < 128; ++o) {
        float p0 = b1s[o], p1 = p0;
        const float4* wp = (const float4*)(w1t + o * 64);
#pragma unroll
        for (int q = 0; q < 16; ++q) {
            float4 wv = wp[q];
            p0 += h0[4 * q] * wv.x + h0[4 * q + 1] * wv.y + h0[4 * q + 2] * wv.z + h0[4 * q + 3] * wv.w;
            p1 += h1v[4 * q] * wv.x + h1v[4 * q + 1] * wv.y + h1v[4 * q + 2] * wv.z + h1v[4 * q + 3] * wv.w;
        }
        float w2v = w2s[o];
        acc0 += eluf(p0) * w2v;
        acc1 += eluf(p1) * w2v;
    }
    out[n0] = acc0;
    if (n0 + 1 < N) out[n0 + 1] = acc1;
}

// ---------------------------------------------------------------------------

extern "C" void kernel_launch(void* const* d_in, const int* in_sizes, int n_in,
                              void* d_out, int out_size, void* d_ws, size_t ws_size,
                              hipStream_t stream) {
    const float* x     = (const float*)d_in[0];
    const int*   ei    = (const int*)  d_in[1];
    const float* attr  = (const float*)d_in[2];
    const float* w1    = (const float*)d_in[3];
    const float* root1 = (const float*)d_in[4];
    const float* b1    = (const float*)d_in[5];
    const float* g1    = (const float*)d_in[6];
    const float* be1   = (const float*)d_in[7];
    const float* w2    = (const float*)d_in[8];
    const float* root2 = (const float*)d_in[9];
    const float* b2    = (const float*)d_in[10];
    const float* g2    = (const float*)d_in[11];
    const float* be2   = (const float*)d_in[12];
    const float* fc1w  = (const float*)d_in[13];
    const float* fc1b  = (const float*)d_in[14];
    const float* fc2w  = (const float*)d_in[15];
    const float* fc2b  = (const float*)d_in[16];
    float* out = (float*)d_out;

    int N = in_sizes[0];          // 150000
    int E = in_sizes[1] / 2;      // 3000000

    char* ws = (char*)d_ws;
    size_t off = 0;
    auto alloc = [&](size_t bytes) -> void* {
        void* p = ws + off;
        off = (off + bytes + 255) & ~(size_t)255;
        return p;
    };
    int*      rowptr    = (int*)     alloc((size_t)(N + 1) * 4);
    int*      deg       = (int*)     alloc((size_t)N * 4);
    int*      cursor    = (int*)     alloc((size_t)N * 4);
    int*      blockSums = (int*)     alloc(1024 * 4);
    int*      blockOff  = (int*)     alloc(1024 * 4);
    double*   bnsum1    = (double*)  alloc(128 * 8);
    double*   bnsum2    = (double*)  alloc(128 * 8);
    float*    scsh1     = (float*)   alloc(64 * 4);
    float*    scsh2     = (float*)   alloc(128 * 4);
    _Float16* w2f       = (_Float16*)alloc(34816 * 2);
    uint4*    edges     = (uint4*)   alloc((size_t)E * 16);
    float*    h1        = (float*)   alloc((size_t)N * 32 * 4);
    _Float16* h1h       = (_Float16*)alloc((size_t)N * 32 * 2);
    float*    out2      = (float*)   alloc((size_t)N * 64 * 4);
    // agg buffer takes the remainder of the workspace (512 fp16 = 1024 B/node)
    size_t avail = (ws_size > off) ? (ws_size - off) : 0;
    int NC = (int)(avail / 1024);
    if (NC > N) NC = N;
    NC &= ~255;
    if (NC < 256) NC = 256;
    _Float16* aggbuf = (_Float16*)alloc((size_t)NC * 1024);
    (void)n_in; (void)out_size;

    hipMemsetAsync(deg, 0, (size_t)N * 4, stream);
    hipMemsetAsync(bnsum1, 0, 128 * 8, stream);
    hipMemsetAsync(bnsum2, 0, 128 * 8, stream);

    int gE = (E + 255) / 256; if (gE > 4096) gE = 4096;
    int NB = (N + 1023) / 1024;

    k_w2pack<<<136, 256, 0, stream>>>(w2, root2, w2f);
    k_count<<<gE, 256, 0, stream>>>(ei + E, E, deg);
    k_scan1<<<NB, 256, 0, stream>>>(deg, N, rowptr, blockSums);
    k_scan2<<<1, 256, 0, stream>>>(blockSums, NB, blockOff);
    k_scan3<<<(N + 255) / 256, 256, 0, stream>>>(rowptr, cursor, blockOff, N, E);
    k_fill<<<gE, 256, 0, stream>>>(ei, attr, E, cursor, edges);

    k_conv1<<<(N + 255) / 256, 256, 0, stream>>>(x, rowptr, edges, w1, root1, b1, h1, N);
    k_bnstat<32><<<256, 256, 0, stream>>>(h1, N, bnsum1);
    k_bnfinal<<<1, 64, 0, stream>>>(bnsum1, g1, be1, 32, N, scsh1);
    k_bnelu32h<<<1024, 256, 0, stream>>>(h1, N, scsh1, h1h);

    for (int c0 = 0; c0 < N; c0 += NC) {
        int c1 = c0 + NC; if (c1 > N) c1 = N;
        int cnt = c1 - c0;
        k_agg<<<(cnt + 7) / 8, 512, 0, stream>>>(h1h, rowptr, edges, aggbuf, c0, c1);
        int ntiles = (cnt + 63) / 64;
        int grid = ntiles < 1184 ? ntiles : 1184;
        k_gemm2<<<grid, 256, 69632, stream>>>(aggbuf, h1h, w2f, b2, out2, c0, c1, ntiles);
    }

    k_bnstat<64><<<256, 256, 0, stream>>>(out2, N, bnsum2);
    k_bnfinal<<<1, 64, 0, stream>>>(bnsum2, g2, be2, 64, N, scsh2);
    k_bnelu<64><<<2048, 256, 0, stream>>>(out2, N, scsh2);

    int pairs = (N + 1) / 2;
    k_fc<<<(pairs + 255) / 256, 256, 0, stream>>>(out2, fc1w, fc1b, fc2w, fc2b, out, N);
}

// Round 5
// 740.698 us; speedup vs baseline: 2.4327x; 1.1108x over previous
//
#include <hip/hip_runtime.h>
#include <hip/hip_fp16.h>
#include <math.h>

// ---------------------------------------------------------------------------
// SplineCNN (K=4, dim=2, deg=2). v5: two-phase partition CSR build (bucketed
// runs + L2-local bucket sort) to kill scatter write amplification; MFMA conv2
// GEMM; BN2+ELU fused into final MLP.
// ---------------------------------------------------------------------------

typedef _Float16 half8 __attribute__((ext_vector_type(8)));
typedef float    f32x4 __attribute__((ext_vector_type(4)));

__device__ __forceinline__ void bspline4(float a, float B[4]) {
    a = fminf(fmaxf(a, 0.f), 1.f);
    float v  = a * 2.0f;          // K - DEG = 2
    float kv = floorf(v);
    float t  = v - kv;
    int   ik = (int)kv;           // 0..2
    float b0 = 0.5f * (1.f - t) * (1.f - t);
    float b1 = (t - t * t) + 0.5f;
    float b2 = 0.5f * t * t;
    int c0 = ik;
    int c1 = ik + 1;
    int c2 = ik + 2; if (c2 > 3) c2 = 3;
#pragma unroll
    for (int j = 0; j < 4; ++j)
        B[j] = (c0 == j ? b0 : 0.f) + (c1 == j ? b1 : 0.f) + (c2 == j ? b2 : 0.f);
}

__device__ __forceinline__ float eluf(float x) {
    return x > 0.f ? x : expm1f(x);
}

// unpack 16B edge record -> src + bu[4] + bv[4]
__device__ __forceinline__ void unpack_edge(uint4 rec, int& src,
                                            float bu[4], float bv[4]) {
    src = (int)rec.x;
    float2 f01 = __half22float2(*(const __half2*)&rec.y);
    float2 f23 = __half22float2(*(const __half2*)&rec.z);
    float2 f45 = __half22float2(*(const __half2*)&rec.w);
    bu[0] = f01.x; bu[1] = f01.y; bu[2] = f23.x;
    bu[3] = 1.f - (bu[0] + bu[1] + bu[2]);
    bv[0] = f23.y; bv[1] = f45.x; bv[2] = f45.y;
    bv[3] = 1.f - (bv[0] + bv[1] + bv[2]);
}

// ---------------- Phase A: bucketed partition (bucket = dst >> 8) ----------------

__global__ void kA1_hist(const int* __restrict__ dst, int E, int* __restrict__ cnt,
                         int nWG, int NBUK, int CHUNK) {
    extern __shared__ int hist[];   // NBUK ints
    int wg = blockIdx.x, tid = threadIdx.x;
    for (int b = tid; b < NBUK; b += 256) hist[b] = 0;
    __syncthreads();
    int base = wg * CHUNK;
    int end  = base + CHUNK; if (end > E) end = E;
    for (int i = base + tid; i < end; i += 256)
        atomicAdd(&hist[dst[i] >> 8], 1);
    __syncthreads();
    for (int b = tid; b < NBUK; b += 256) cnt[b * nWG + wg] = hist[b];
}

// generic exclusive scan (2-level), reused from previous rounds
__global__ void k_scan1(const int* __restrict__ in, int M,
                        int* __restrict__ outp, int* __restrict__ blockSums) {
    __shared__ int wsum[4];
    int tid  = threadIdx.x;
    int base = blockIdx.x * 1024 + tid * 4;
    int d0 = (base + 0) < M ? in[base + 0] : 0;
    int d1 = (base + 1) < M ? in[base + 1] : 0;
    int d2 = (base + 2) < M ? in[base + 2] : 0;
    int d3 = (base + 3) < M ? in[base + 3] : 0;
    int s4 = d0 + d1 + d2 + d3;
    int lane = tid & 63, wid = tid >> 6;
    int inc = s4;
#pragma unroll
    for (int off = 1; off < 64; off <<= 1) {
        int t = __shfl_up(inc, off);
        if (lane >= off) inc += t;
    }
    if (lane == 63) wsum[wid] = inc;
    __syncthreads();
    if (tid == 0) {
        int acc = 0;
#pragma unroll
        for (int w = 0; w < 4; ++w) { int t = wsum[w]; wsum[w] = acc; acc += t; }
    }
    __syncthreads();
    int ebase = wsum[wid] + inc - s4;
    if ((base + 0) < M) outp[base + 0] = ebase;
    if ((base + 1) < M) outp[base + 1] = ebase + d0;
    if ((base + 2) < M) outp[base + 2] = ebase + d0 + d1;
    if ((base + 3) < M) outp[base + 3] = ebase + d0 + d1 + d2;
    if (tid == 255) blockSums[blockIdx.x] = ebase + s4;
}

__global__ void k_scan2(const int* __restrict__ blockSums, int NB, int* __restrict__ blockOff) {
    __shared__ int sh[256];
    int tid = threadIdx.x;
    int own = (tid < NB) ? blockSums[tid] : 0;
    sh[tid] = own;
    __syncthreads();
    for (int off = 1; off < 256; off <<= 1) {
        int v = (tid >= off) ? sh[tid - off] : 0;
        __syncthreads();
        sh[tid] += v;
        __syncthreads();
    }
    if (tid < NB) blockOff[tid] = sh[tid] - own;
}

__global__ void k_scan3b(int* __restrict__ arr, const int* __restrict__ blockOff, int M) {
    int i = blockIdx.x * blockDim.x + threadIdx.x;
    if (i < M) arr[i] += blockOff[i >> 10];
}

// fill pass: each WG writes contiguous runs per bucket (LDS cursors from off[])
__global__ void kA2_fill(const int* __restrict__ ei, const float* __restrict__ attr, int E,
                         const int* __restrict__ off, int nWG, int NBUK, int CHUNK,
                         uint4* __restrict__ buf1, unsigned char* __restrict__ dl1) {
    extern __shared__ int cur[];    // NBUK ints
    int wg = blockIdx.x, tid = threadIdx.x;
    for (int b = tid; b < NBUK; b += 256) cur[b] = off[b * nWG + wg];
    __syncthreads();
    int base = wg * CHUNK;
    int end  = base + CHUNK; if (end > E) end = E;
    for (int i = base + tid; i < end; i += 256) {
        int d = ei[E + i];
        int pos = atomicAdd(&cur[d >> 8], 1);
        float Bu[4], Bv[4];
        bspline4(attr[2 * i + 0], Bu);
        bspline4(attr[2 * i + 1], Bv);
        __half2 p01 = __floats2half2_rn(Bu[0], Bu[1]);
        __half2 p23 = __floats2half2_rn(Bu[2], Bv[0]);
        __half2 p45 = __floats2half2_rn(Bv[1], Bv[2]);
        uint4 rec;
        rec.x = (unsigned)ei[i];
        rec.y = *(const unsigned*)&p01;
        rec.z = *(const unsigned*)&p23;
        rec.w = *(const unsigned*)&p45;
        buf1[pos] = rec;
        dl1[pos]  = (unsigned char)(d & 255);
    }
}

// ---------------- Phase B: per-bucket exact-dst sort + rowptr ----------------

__global__ __launch_bounds__(256) void kB_sort(
    const uint4* __restrict__ buf1, const unsigned char* __restrict__ dl1,
    const int* __restrict__ off, int nWG, int NBUK, int N, int E,
    uint4* __restrict__ edges, int* __restrict__ rowptr) {
    __shared__ int hist[256], pref[256], curs[256];
    __shared__ int sbase, ssize;
    int b = blockIdx.x, tid = threadIdx.x;
    if (tid == 0) {
        int s  = off[b * nWG];
        int e2 = (b + 1 < NBUK) ? off[(b + 1) * nWG] : E;
        sbase = s; ssize = e2 - s;
    }
    hist[tid] = 0;
    __syncthreads();
    int base = sbase, size = ssize;
    for (int i = tid; i < size; i += 256) atomicAdd(&hist[dl1[base + i]], 1);
    __syncthreads();
    if (tid == 0) {
        int acc = 0;
        for (int j = 0; j < 256; ++j) { pref[j] = acc; acc += hist[j]; }
    }
    __syncthreads();
    curs[tid] = pref[tid];
    int node = b * 256 + tid;
    if (node < N) rowptr[node] = base + pref[tid];
    if (b == NBUK - 1 && tid == 0) rowptr[N] = E;
    __syncthreads();
    for (int i = tid; i < size; i += 256) {
        int p = atomicAdd(&curs[dl1[base + i]], 1);
        edges[base + p] = buf1[base + i];
    }
}

// ---------------- w2 + root2 pre-pack into B-fragment order (fp16) ----------------

__global__ void k_w2pack(const float* __restrict__ w2, const float* __restrict__ root2,
                         _Float16* __restrict__ w2f) {
    int f = blockIdx.x * blockDim.x + threadIdx.x;
    int stride = gridDim.x * blockDim.x;
    for (; f < 34816; f += stride) {
        int j = f & 7, l = (f >> 3) & 63, t = (f >> 9) & 3;
        int o = t * 16 + (l & 15);
        float v;
        if (f < 32768) {
            int s = f >> 11;
            int p = s * 32 + ((l >> 4) << 3) + j;
            int lane_a = p >> 3, q = p & 7;
            int c = lane_a & 31, kidx = ((lane_a >> 5) << 3) + q;
            v = w2[(kidx * 32 + c) * 64 + o];
        } else {
            int c = ((l >> 4) << 3) + j;
            v = root2[c * 64 + o];
        }
        w2f[f] = (_Float16)v;
    }
}

// ---------------- Layer 1 conv (in=1 -> out=32), thread per node ----------------

__global__ void k_conv1(const float* __restrict__ x, const int* __restrict__ rowptr,
                        const uint4* __restrict__ edges,
                        const float* __restrict__ w1, const float* __restrict__ root1,
                        const float* __restrict__ b1, float* __restrict__ h1, int N) {
    __shared__ float w1s[16 * 32];
    __shared__ float r1s[32], b1s[32];
    int tid = threadIdx.x;
    for (int i = tid; i < 512; i += blockDim.x) w1s[i] = w1[i];
    if (tid < 32) { r1s[tid] = root1[tid]; b1s[tid] = b1[tid]; }
    __syncthreads();
    int n = blockIdx.x * blockDim.x + tid;
    if (n >= N) return;
    float agg[16] = {};
    int s = rowptr[n], e = rowptr[n + 1];
    for (int j = s; j < e; ++j) {
        uint4 rec = edges[j];
        int src; float bu[4], bv[4];
        unpack_edge(rec, src, bu, bv);
        float xs = x[src];
        float t0 = xs * bv[0], t1 = xs * bv[1], t2 = xs * bv[2], t3 = xs * bv[3];
        agg[0]  += bu[0] * t0; agg[1]  += bu[1] * t0; agg[2]  += bu[2] * t0; agg[3]  += bu[3] * t0;
        agg[4]  += bu[0] * t1; agg[5]  += bu[1] * t1; agg[6]  += bu[2] * t1; agg[7]  += bu[3] * t1;
        agg[8]  += bu[0] * t2; agg[9]  += bu[1] * t2; agg[10] += bu[2] * t2; agg[11] += bu[3] * t2;
        agg[12] += bu[0] * t3; agg[13] += bu[1] * t3; agg[14] += bu[2] * t3; agg[15] += bu[3] * t3;
    }
    float xn = x[n];
#pragma unroll 4
    for (int o = 0; o < 32; ++o) {
        float acc = b1s[o] + xn * r1s[o];
#pragma unroll
        for (int k = 0; k < 16; ++k) acc += agg[k] * w1s[k * 32 + o];
        h1[n * 32 + o] = acc;
    }
}

// ---------------- BatchNorm ----------------

template <int C>
__global__ void k_bnstat(const float* __restrict__ h, int N, double* __restrict__ sums) {
    __shared__ float sh1[C], sh2[C];
    int tid  = blockIdx.x * blockDim.x + threadIdx.x;
    int c    = tid & (C - 1);
    int row  = tid / C;
    int rstr = (gridDim.x * blockDim.x) / C;
    float s1 = 0.f, s2 = 0.f;
    for (int r = row; r < N; r += rstr) {
        float v = h[(size_t)r * C + c];
        s1 += v; s2 += v * v;
    }
    if (threadIdx.x < C) { sh1[threadIdx.x] = 0.f; sh2[threadIdx.x] = 0.f; }
    __syncthreads();
    atomicAdd(&sh1[c], s1);
    atomicAdd(&sh2[c], s2);
    __syncthreads();
    if (threadIdx.x < C) {
        atomicAdd(&sums[threadIdx.x],     (double)sh1[threadIdx.x]);
        atomicAdd(&sums[C + threadIdx.x], (double)sh2[threadIdx.x]);
    }
}

__global__ void k_bnfinal(const double* __restrict__ sums, const float* __restrict__ gamma,
                          const float* __restrict__ beta, int C, int N, float* __restrict__ scsh) {
    int c = threadIdx.x;
    if (c < C) {
        double m   = sums[c] / (double)N;
        double var = sums[C + c] / (double)N - m * m;
        float vpe  = (float)var + 1e-5f;
        float sc   = gamma[c] / sqrtf(vpe);
        scsh[c]     = sc;
        scsh[C + c] = beta[c] - (float)m * sc;
    }
}

// BN + ELU for h1 (C=32), output fp16
__global__ void k_bnelu32h(const float* __restrict__ h, int N,
                           const float* __restrict__ scsh, _Float16* __restrict__ hh) {
    int total = N * 4;   // groups of 8 floats
    int i = blockIdx.x * blockDim.x + threadIdx.x;
    int stride = gridDim.x * blockDim.x;
    const float4* hp = (const float4*)h;
    for (; i < total; i += stride) {
        float4 v0 = hp[2 * i], v1 = hp[2 * i + 1];
        int c0 = (i * 8) & 31;
        half8 r;
        r[0] = (_Float16)eluf(v0.x * scsh[c0 + 0] + scsh[32 + c0 + 0]);
        r[1] = (_Float16)eluf(v0.y * scsh[c0 + 1] + scsh[32 + c0 + 1]);
        r[2] = (_Float16)eluf(v0.z * scsh[c0 + 2] + scsh[32 + c0 + 2]);
        r[3] = (_Float16)eluf(v0.w * scsh[c0 + 3] + scsh[32 + c0 + 3]);
        r[4] = (_Float16)eluf(v1.x * scsh[c0 + 4] + scsh[32 + c0 + 4]);
        r[5] = (_Float16)eluf(v1.y * scsh[c0 + 5] + scsh[32 + c0 + 5]);
        r[6] = (_Float16)eluf(v1.z * scsh[c0 + 6] + scsh[32 + c0 + 6]);
        r[7] = (_Float16)eluf(v1.w * scsh[c0 + 7] + scsh[32 + c0 + 7]);
        *(half8*)(hh + (size_t)i * 8) = r;
    }
}

// ---------------- Layer 2: aggregation (wave per node), A-frag-order fp16 out ----------------

__global__ __launch_bounds__(512) void k_agg(
    const _Float16* __restrict__ h1h, const int* __restrict__ rowptr,
    const uint4* __restrict__ edges, _Float16* __restrict__ agg,
    int n0, int n1) {
    int tid   = threadIdx.x;
    int lane  = tid & 63;
    int w     = tid >> 6;
    int c     = lane & 31;
    int khalf = lane >> 5;
    int n = n0 + blockIdx.x * 8 + w;
    if (n >= n1) return;
    float a[8] = {};
    int s = __builtin_amdgcn_readfirstlane(rowptr[n]);
    int e = __builtin_amdgcn_readfirstlane(rowptr[n + 1]);
    for (int j = s; j < e; ++j) {
        uint4 rec = edges[j];
        int src; float bu[4], bv[4];
        unpack_edge(rec, src, bu, bv);
        float hc = (float)h1h[(size_t)src * 32 + c];
        float bvlo = khalf ? bv[2] : bv[0];
        float bvhi = khalf ? bv[3] : bv[1];
        float t0 = hc * bvlo, t1 = hc * bvhi;
        a[0] += bu[0] * t0; a[1] += bu[1] * t0; a[2] += bu[2] * t0; a[3] += bu[3] * t0;
        a[4] += bu[0] * t1; a[5] += bu[1] * t1; a[6] += bu[2] * t1; a[7] += bu[3] * t1;
    }
    half8 hv;
#pragma unroll
    for (int q = 0; q < 8; ++q) hv[q] = (_Float16)a[q];
    *(half8*)(agg + (size_t)(n - n0) * 512 + lane * 8) = hv;
}

// ---------------- Layer 2: MFMA GEMM  out2 = [agg|h1h] @ w2f + b2 ----------------

__global__ __launch_bounds__(256) void k_gemm2(
    const _Float16* __restrict__ agg, const _Float16* __restrict__ h1h,
    const _Float16* __restrict__ w2f, const float* __restrict__ b2,
    float* __restrict__ out2, int n0, int n1, int ntiles) {
    extern __shared__ _Float16 w2s[];
    int tid = threadIdx.x;
    {
        const uint4* s4 = (const uint4*)w2f;
        uint4* d4 = (uint4*)w2s;
        for (int i = tid; i < 4352; i += 256) d4[i] = s4[i];   // 69632 B
    }
    __syncthreads();
    const half8* bp = (const half8*)w2s;
    int l   = tid & 63, w = tid >> 6;
    int klo = (l >> 4) << 3;
    int m   = l & 15;
    float bv0 = b2[m], bv1 = b2[16 + m], bv2 = b2[32 + m], bv3 = b2[48 + m];
    for (int tile = blockIdx.x; tile < ntiles; tile += gridDim.x) {
        int wavebase = n0 + tile * 64 + w * 16;
        if (wavebase >= n1) continue;
        int arow = wavebase + m; if (arow > n1 - 1) arow = n1 - 1;
        const half8* ap = (const half8*)(agg + (size_t)(arow - n0) * 512 + klo);
        f32x4 acc0 = {0.f,0.f,0.f,0.f}, acc1 = acc0, acc2 = acc0, acc3 = acc0;
#pragma unroll
        for (int s = 0; s < 16; ++s) {
            half8 a = ap[s * 4];
            int bi = (s << 8) + l;
            acc0 = __builtin_amdgcn_mfma_f32_16x16x32_f16(a, bp[bi      ], acc0, 0, 0, 0);
            acc1 = __builtin_amdgcn_mfma_f32_16x16x32_f16(a, bp[bi +  64], acc1, 0, 0, 0);
            acc2 = __builtin_amdgcn_mfma_f32_16x16x32_f16(a, bp[bi + 128], acc2, 0, 0, 0);
            acc3 = __builtin_amdgcn_mfma_f32_16x16x32_f16(a, bp[bi + 192], acc3, 0, 0, 0);
        }
        {
            half8 a = *(const half8*)(h1h + (size_t)arow * 32 + klo);
            int bi = (16 << 8) + l;
            acc0 = __builtin_amdgcn_mfma_f32_16x16x32_f16(a, bp[bi      ], acc0, 0, 0, 0);
            acc1 = __builtin_amdgcn_mfma_f32_16x16x32_f16(a, bp[bi +  64], acc1, 0, 0, 0);
            acc2 = __builtin_amdgcn_mfma_f32_16x16x32_f16(a, bp[bi + 128], acc2, 0, 0, 0);
            acc3 = __builtin_amdgcn_mfma_f32_16x16x32_f16(a, bp[bi + 192], acc3, 0, 0, 0);
        }
        int rbase = wavebase + ((l >> 4) << 2);
#pragma unroll
        for (int r = 0; r < 4; ++r) {
            int node = rbase + r;
            if (node < n1) {
                size_t o = (size_t)node * 64;
                out2[o + m]      = acc0[r] + bv0;
                out2[o + 16 + m] = acc1[r] + bv1;
                out2[o + 32 + m] = acc2[r] + bv2;
                out2[o + 48 + m] = acc3[r] + bv3;
            }
        }
    }
}

// ---------------- Final MLP with fused BN2+ELU: 64 -> 128 (ELU) -> 1 ----------------

__global__ __launch_bounds__(256) void k_fc(
    const float* __restrict__ h2raw, const float* __restrict__ scsh,
    const float* __restrict__ fc1w, const float* __restrict__ fc1b,
    const float* __restrict__ fc2w, const float* __restrict__ fc2b,
    float* __restrict__ out, int N) {
    __shared__ float w1t[128 * 64];  // transposed [o][cd]
    __shared__ float b1s[128], w2sv[128], scs[64], shs[64];
    int tid = threadIdx.x;
    for (int i = tid; i < 8192; i += 256) {
        int o = i >> 6, cd = i & 63;
        w1t[o * 64 + cd] = fc1w[cd * 128 + o];
    }
    if (tid < 128) { b1s[tid] = fc1b[tid]; w2sv[tid] = fc2w[tid]; }
    if (tid < 64)  { scs[tid] = scsh[tid]; shs[tid] = scsh[64 + tid]; }
    __syncthreads();
    int n0 = (blockIdx.x * 256 + tid) * 2;
    if (n0 >= N) return;
    int n1i = (n0 + 1 < N) ? n0 + 1 : n0;
    float h0[64], h1v[64];
    {
        const float4* p0 = (const float4*)(h2raw + (size_t)n0 * 64);
        const float4* p1 = (const float4*)(h2raw + (size_t)n1i * 64);
#pragma unroll
        for (int i = 0; i < 16; ++i) {
            int c = 4 * i;
            float4 a = p0[i];
            h0[c + 0] = eluf(a.x * scs[c + 0] + shs[c + 0]);
            h0[c + 1] = eluf(a.y * scs[c + 1] + shs[c + 1]);
            h0[c + 2] = eluf(a.z * scs[c + 2] + shs[c + 2]);
            h0[c + 3] = eluf(a.w * scs[c + 3] + shs[c + 3]);
            float4 b = p1[i];
            h1v[c + 0] = eluf(b.x * scs[c + 0] + shs[c + 0]);
            h1v[c + 1] = eluf(b.y * scs[c + 1] + shs[c + 1]);
            h1v[c + 2] = eluf(b.z * scs[c + 2] + shs[c + 2]);
            h1v[c + 3] = eluf(b.w * scs[c + 3] + shs[c + 3]);
        }
    }
    float acc0 = fc2b[0], acc1 = acc0;
    for (int o = 0; o < 128; ++o) {
        float p0 = b1s[o], p1 = p0;
        const float4* wp = (const float4*)(w1t + o * 64);
#pragma unroll
        for (int q = 0; q < 16; ++q) {
            float4 wv = wp[q];
            p0 += h0[4 * q] * wv.x + h0[4 * q + 1] * wv.y + h0[4 * q + 2] * wv.z + h0[4 * q + 3] * wv.w;
            p1 += h1v[4 * q] * wv.x + h1v[4 * q + 1] * wv.y + h1v[4 * q + 2] * wv.z + h1v[4 * q + 3] * wv.w;
        }
        float w2v = w2sv[o];
        acc0 += eluf(p0) * w2v;
        acc1 += eluf(p1) * w2v;
    }
    out[n0] = acc0;
    if (n0 + 1 < N) out[n0 + 1] = acc1;
}

// ---------------------------------------------------------------------------

extern "C" void kernel_launch(void* const* d_in, const int* in_sizes, int n_in,
                              void* d_out, int out_size, void* d_ws, size_t ws_size,
                              hipStream_t stream) {
    const float* x     = (const float*)d_in[0];
    const int*   ei    = (const int*)  d_in[1];
    const float* attr  = (const float*)d_in[2];
    const float* w1    = (const float*)d_in[3];
    const float* root1 = (const float*)d_in[4];
    const float* b1    = (const float*)d_in[5];
    const float* g1    = (const float*)d_in[6];
    const float* be1   = (const float*)d_in[7];
    const float* w2    = (const float*)d_in[8];
    const float* root2 = (const float*)d_in[9];
    const float* b2    = (const float*)d_in[10];
    const float* g2    = (const float*)d_in[11];
    const float* be2   = (const float*)d_in[12];
    const float* fc1w  = (const float*)d_in[13];
    const float* fc1b  = (const float*)d_in[14];
    const float* fc2w  = (const float*)d_in[15];
    const float* fc2b  = (const float*)d_in[16];
    float* out = (float*)d_out;

    int N = in_sizes[0];          // 150000
    int E = in_sizes[1] / 2;      // 3000000

    const int CHUNK = 16384;
    int nWG  = (E + CHUNK - 1) / CHUNK;     // 184
    int NBUK = (N + 255) >> 8;              // 586
    int M    = NBUK * nWG;                  // ~108k

    char* ws = (char*)d_ws;
    size_t off = 0;
    auto alloc = [&](size_t bytes) -> void* {
        void* p = ws + off;
        off = (off + bytes + 255) & ~(size_t)255;
        return p;
    };
    int*      rowptr    = (int*)     alloc((size_t)(N + 1) * 4);
    int*      blockSums = (int*)     alloc(1024 * 4);
    int*      blockOff  = (int*)     alloc(1024 * 4);
    double*   bnsum1    = (double*)  alloc(128 * 8);
    double*   bnsum2    = (double*)  alloc(128 * 8);
    float*    scsh1     = (float*)   alloc(64 * 4);
    float*    scsh2     = (float*)   alloc(128 * 4);
    _Float16* w2f       = (_Float16*)alloc(34816 * 2);
    int*      cnt       = (int*)     alloc((size_t)M * 4);
    int*      offs      = (int*)     alloc((size_t)M * 4);
    uint4*    edges     = (uint4*)   alloc((size_t)E * 16);
    size_t    Roff      = off;              // start of aliasable region
    float*    h1        = (float*)   alloc((size_t)N * 32 * 4);   // 19.2 MB
    _Float16* h1h       = (_Float16*)alloc((size_t)N * 32 * 2);   //  9.6 MB
    float*    out2      = (float*)   alloc((size_t)N * 64 * 4);   // 38.4 MB
    // buf1 + dl1 alias [h1|h1h|out2] (51 MB <= 67 MB); dead before conv1 runs
    uint4*         buf1 = (uint4*)(ws + Roff);
    unsigned char* dl1  = (unsigned char*)(ws + Roff + (size_t)E * 16);
    // agg buffer takes the remainder (512 fp16 = 1024 B/node)
    size_t avail = (ws_size > off) ? (ws_size - off) : 0;
    int NC = (int)(avail / 1024);
    if (NC > N) NC = N;
    NC &= ~255;
    if (NC < 256) NC = 256;
    _Float16* aggbuf = (_Float16*)alloc((size_t)NC * 1024);
    (void)n_in; (void)out_size;

    hipMemsetAsync(bnsum1, 0, 128 * 8, stream);
    hipMemsetAsync(bnsum2, 0, 128 * 8, stream);

    size_t ldsA = (size_t)NBUK * 4;
    int NBs = (M + 1023) / 1024;            // ~106 <= 256

    k_w2pack<<<136, 256, 0, stream>>>(w2, root2, w2f);
    kA1_hist<<<nWG, 256, ldsA, stream>>>(ei + E, E, cnt, nWG, NBUK, CHUNK);
    k_scan1<<<NBs, 256, 0, stream>>>(cnt, M, offs, blockSums);
    k_scan2<<<1, 256, 0, stream>>>(blockSums, NBs, blockOff);
    k_scan3b<<<(M + 255) / 256, 256, 0, stream>>>(offs, blockOff, M);
    kA2_fill<<<nWG, 256, ldsA, stream>>>(ei, attr, E, offs, nWG, NBUK, CHUNK, buf1, dl1);
    kB_sort<<<NBUK, 256, 0, stream>>>(buf1, dl1, offs, nWG, NBUK, N, E, edges, rowptr);

    k_conv1<<<(N + 255) / 256, 256, 0, stream>>>(x, rowptr, edges, w1, root1, b1, h1, N);
    k_bnstat<32><<<256, 256, 0, stream>>>(h1, N, bnsum1);
    k_bnfinal<<<1, 64, 0, stream>>>(bnsum1, g1, be1, 32, N, scsh1);
    k_bnelu32h<<<1024, 256, 0, stream>>>(h1, N, scsh1, h1h);

    for (int c0 = 0; c0 < N; c0 += NC) {
        int c1 = c0 + NC; if (c1 > N) c1 = N;
        int cnt2 = c1 - c0;
        k_agg<<<(cnt2 + 7) / 8, 512, 0, stream>>>(h1h, rowptr, edges, aggbuf, c0, c1);
        int ntiles = (cnt2 + 63) / 64;
        int grid = ntiles < 1184 ? ntiles : 1184;
        k_gemm2<<<grid, 256, 69632, stream>>>(aggbuf, h1h, w2f, b2, out2, c0, c1, ntiles);
    }

    k_bnstat<64><<<256, 256, 0, stream>>>(out2, N, bnsum2);
    k_bnfinal<<<1, 64, 0, stream>>>(bnsum2, g2, be2, 64, N, scsh2);

    int pairs = (N + 1) / 2;
    k_fc<<<(pairs + 255) / 256, 256, 0, stream>>>(out2, scsh2, fc1w, fc1b, fc2w, fc2b, out, N);
}

// Round 6
// 655.039 us; speedup vs baseline: 2.7509x; 1.1308x over previous
//
#include <hip/hip_runtime.h>
#include <hip/hip_fp16.h>
#include <math.h>

// ---------------------------------------------------------------------------
// SplineCNN (K=4, dim=2, deg=2). v6: k_agg processes 2 edges/wave-iter
// (half-wave split) with 4 edges in flight; conv1 gather unrolled 4-wide.
// ---------------------------------------------------------------------------

typedef _Float16 half8 __attribute__((ext_vector_type(8)));
typedef float    f32x4 __attribute__((ext_vector_type(4)));

__device__ __forceinline__ void bspline4(float a, float B[4]) {
    a = fminf(fmaxf(a, 0.f), 1.f);
    float v  = a * 2.0f;          // K - DEG = 2
    float kv = floorf(v);
    float t  = v - kv;
    int   ik = (int)kv;           // 0..2
    float b0 = 0.5f * (1.f - t) * (1.f - t);
    float b1 = (t - t * t) + 0.5f;
    float b2 = 0.5f * t * t;
    int c0 = ik;
    int c1 = ik + 1;
    int c2 = ik + 2; if (c2 > 3) c2 = 3;
#pragma unroll
    for (int j = 0; j < 4; ++j)
        B[j] = (c0 == j ? b0 : 0.f) + (c1 == j ? b1 : 0.f) + (c2 == j ? b2 : 0.f);
}

__device__ __forceinline__ float eluf(float x) {
    return x > 0.f ? x : expm1f(x);
}

// unpack 16B edge record -> bu[4], bv[4] (src handled by caller)
__device__ __forceinline__ void unpack_basis(uint4 rec, float bu[4], float bv[4]) {
    float2 f01 = __half22float2(*(const __half2*)&rec.y);
    float2 f23 = __half22float2(*(const __half2*)&rec.z);
    float2 f45 = __half22float2(*(const __half2*)&rec.w);
    bu[0] = f01.x; bu[1] = f01.y; bu[2] = f23.x;
    bu[3] = 1.f - (bu[0] + bu[1] + bu[2]);
    bv[0] = f23.y; bv[1] = f45.x; bv[2] = f45.y;
    bv[3] = 1.f - (bv[0] + bv[1] + bv[2]);
}

// ---------------- Phase A: bucketed partition (bucket = dst >> 8) ----------------

__global__ void kA1_hist(const int* __restrict__ dst, int E, int* __restrict__ cnt,
                         int nWG, int NBUK, int CHUNK) {
    extern __shared__ int hist[];   // NBUK ints
    int wg = blockIdx.x, tid = threadIdx.x;
    for (int b = tid; b < NBUK; b += 256) hist[b] = 0;
    __syncthreads();
    int base = wg * CHUNK;
    int end  = base + CHUNK; if (end > E) end = E;
    for (int i = base + tid; i < end; i += 256)
        atomicAdd(&hist[dst[i] >> 8], 1);
    __syncthreads();
    for (int b = tid; b < NBUK; b += 256) cnt[b * nWG + wg] = hist[b];
}

__global__ void k_scan1(const int* __restrict__ in, int M,
                        int* __restrict__ outp, int* __restrict__ blockSums) {
    __shared__ int wsum[4];
    int tid  = threadIdx.x;
    int base = blockIdx.x * 1024 + tid * 4;
    int d0 = (base + 0) < M ? in[base + 0] : 0;
    int d1 = (base + 1) < M ? in[base + 1] : 0;
    int d2 = (base + 2) < M ? in[base + 2] : 0;
    int d3 = (base + 3) < M ? in[base + 3] : 0;
    int s4 = d0 + d1 + d2 + d3;
    int lane = tid & 63, wid = tid >> 6;
    int inc = s4;
#pragma unroll
    for (int off = 1; off < 64; off <<= 1) {
        int t = __shfl_up(inc, off);
        if (lane >= off) inc += t;
    }
    if (lane == 63) wsum[wid] = inc;
    __syncthreads();
    if (tid == 0) {
        int acc = 0;
#pragma unroll
        for (int w = 0; w < 4; ++w) { int t = wsum[w]; wsum[w] = acc; acc += t; }
    }
    __syncthreads();
    int ebase = wsum[wid] + inc - s4;
    if ((base + 0) < M) outp[base + 0] = ebase;
    if ((base + 1) < M) outp[base + 1] = ebase + d0;
    if ((base + 2) < M) outp[base + 2] = ebase + d0 + d1;
    if ((base + 3) < M) outp[base + 3] = ebase + d0 + d1 + d2;
    if (tid == 255) blockSums[blockIdx.x] = ebase + s4;
}

__global__ void k_scan2(const int* __restrict__ blockSums, int NB, int* __restrict__ blockOff) {
    __shared__ int sh[256];
    int tid = threadIdx.x;
    int own = (tid < NB) ? blockSums[tid] : 0;
    sh[tid] = own;
    __syncthreads();
    for (int off = 1; off < 256; off <<= 1) {
        int v = (tid >= off) ? sh[tid - off] : 0;
        __syncthreads();
        sh[tid] += v;
        __syncthreads();
    }
    if (tid < NB) blockOff[tid] = sh[tid] - own;
}

__global__ void k_scan3b(int* __restrict__ arr, const int* __restrict__ blockOff, int M) {
    int i = blockIdx.x * blockDim.x + threadIdx.x;
    if (i < M) arr[i] += blockOff[i >> 10];
}

// fill pass: each WG writes contiguous runs per bucket (LDS cursors from off[])
__global__ void kA2_fill(const int* __restrict__ ei, const float* __restrict__ attr, int E,
                         const int* __restrict__ off, int nWG, int NBUK, int CHUNK,
                         uint4* __restrict__ buf1, unsigned char* __restrict__ dl1) {
    extern __shared__ int cur[];    // NBUK ints
    int wg = blockIdx.x, tid = threadIdx.x;
    for (int b = tid; b < NBUK; b += 256) cur[b] = off[b * nWG + wg];
    __syncthreads();
    int base = wg * CHUNK;
    int end  = base + CHUNK; if (end > E) end = E;
    for (int i = base + tid; i < end; i += 256) {
        int d = ei[E + i];
        int pos = atomicAdd(&cur[d >> 8], 1);
        float Bu[4], Bv[4];
        bspline4(attr[2 * i + 0], Bu);
        bspline4(attr[2 * i + 1], Bv);
        __half2 p01 = __floats2half2_rn(Bu[0], Bu[1]);
        __half2 p23 = __floats2half2_rn(Bu[2], Bv[0]);
        __half2 p45 = __floats2half2_rn(Bv[1], Bv[2]);
        uint4 rec;
        rec.x = (unsigned)ei[i];
        rec.y = *(const unsigned*)&p01;
        rec.z = *(const unsigned*)&p23;
        rec.w = *(const unsigned*)&p45;
        buf1[pos] = rec;
        dl1[pos]  = (unsigned char)(d & 255);
    }
}

// ---------------- Phase B: per-bucket exact-dst sort + rowptr ----------------

__global__ __launch_bounds__(256) void kB_sort(
    const uint4* __restrict__ buf1, const unsigned char* __restrict__ dl1,
    const int* __restrict__ off, int nWG, int NBUK, int N, int E,
    uint4* __restrict__ edges, int* __restrict__ rowptr) {
    __shared__ int hist[256], pref[256], curs[256];
    __shared__ int sbase, ssize;
    int b = blockIdx.x, tid = threadIdx.x;
    if (tid == 0) {
        int s  = off[b * nWG];
        int e2 = (b + 1 < NBUK) ? off[(b + 1) * nWG] : E;
        sbase = s; ssize = e2 - s;
    }
    hist[tid] = 0;
    __syncthreads();
    int base = sbase, size = ssize;
    for (int i = tid; i < size; i += 256) atomicAdd(&hist[dl1[base + i]], 1);
    __syncthreads();
    if (tid == 0) {
        int acc = 0;
        for (int j = 0; j < 256; ++j) { pref[j] = acc; acc += hist[j]; }
    }
    __syncthreads();
    curs[tid] = pref[tid];
    int node = b * 256 + tid;
    if (node < N) rowptr[node] = base + pref[tid];
    if (b == NBUK - 1 && tid == 0) rowptr[N] = E;
    __syncthreads();
    for (int i = tid; i < size; i += 256) {
        int p = atomicAdd(&curs[dl1[base + i]], 1);
        edges[base + p] = buf1[base + i];
    }
}

// ---------------- w2 + root2 pre-pack into B-fragment order (fp16) ----------------

__global__ void k_w2pack(const float* __restrict__ w2, const float* __restrict__ root2,
                         _Float16* __restrict__ w2f) {
    int f = blockIdx.x * blockDim.x + threadIdx.x;
    int stride = gridDim.x * blockDim.x;
    for (; f < 34816; f += stride) {
        int j = f & 7, l = (f >> 3) & 63, t = (f >> 9) & 3;
        int o = t * 16 + (l & 15);
        float v;
        if (f < 32768) {
            int s = f >> 11;
            int p = s * 32 + ((l >> 4) << 3) + j;
            int lane_a = p >> 3, q = p & 7;
            int c = lane_a & 31, kidx = ((lane_a >> 5) << 3) + q;
            v = w2[(kidx * 32 + c) * 64 + o];
        } else {
            int c = ((l >> 4) << 3) + j;
            v = root2[c * 64 + o];
        }
        w2f[f] = (_Float16)v;
    }
}

// ---------------- Layer 1 conv (in=1 -> out=32), thread per node ----------------

__global__ void k_conv1(const float* __restrict__ x, const int* __restrict__ rowptr,
                        const uint4* __restrict__ edges,
                        const float* __restrict__ w1, const float* __restrict__ root1,
                        const float* __restrict__ b1, float* __restrict__ h1, int N) {
    __shared__ float w1s[16 * 32];
    __shared__ float r1s[32], b1s[32];
    int tid = threadIdx.x;
    for (int i = tid; i < 512; i += blockDim.x) w1s[i] = w1[i];
    if (tid < 32) { r1s[tid] = root1[tid]; b1s[tid] = b1[tid]; }
    __syncthreads();
    int n = blockIdx.x * blockDim.x + tid;
    if (n >= N) return;
    float agg[16] = {};
    int s = rowptr[n], e = rowptr[n + 1];

#define P1(rec, xs) { \
    float bu[4], bv[4]; \
    unpack_basis(rec, bu, bv); \
    float t0 = (xs) * bv[0], t1 = (xs) * bv[1], t2 = (xs) * bv[2], t3 = (xs) * bv[3]; \
    agg[0]  += bu[0] * t0; agg[1]  += bu[1] * t0; agg[2]  += bu[2] * t0; agg[3]  += bu[3] * t0; \
    agg[4]  += bu[0] * t1; agg[5]  += bu[1] * t1; agg[6]  += bu[2] * t1; agg[7]  += bu[3] * t1; \
    agg[8]  += bu[0] * t2; agg[9]  += bu[1] * t2; agg[10] += bu[2] * t2; agg[11] += bu[3] * t2; \
    agg[12] += bu[0] * t3; agg[13] += bu[1] * t3; agg[14] += bu[2] * t3; agg[15] += bu[3] * t3; }

    int j = s;
    for (; j + 3 < e; j += 4) {
        uint4 r0 = edges[j], r1 = edges[j + 1], r2 = edges[j + 2], r3 = edges[j + 3];
        float x0 = x[r0.x], x1 = x[r1.x], x2 = x[r2.x], x3 = x[r3.x];
        P1(r0, x0); P1(r1, x1); P1(r2, x2); P1(r3, x3);
    }
    for (; j < e; ++j) {
        uint4 r = edges[j];
        float xs = x[r.x];
        P1(r, xs);
    }
#undef P1

    float xn = x[n];
#pragma unroll 4
    for (int o = 0; o < 32; ++o) {
        float acc = b1s[o] + xn * r1s[o];
#pragma unroll
        for (int k = 0; k < 16; ++k) acc += agg[k] * w1s[k * 32 + o];
        h1[n * 32 + o] = acc;
    }
}

// ---------------- BatchNorm ----------------

template <int C>
__global__ void k_bnstat(const float* __restrict__ h, int N, double* __restrict__ sums) {
    __shared__ float sh1[C], sh2[C];
    int tid  = blockIdx.x * blockDim.x + threadIdx.x;
    int c    = tid & (C - 1);
    int row  = tid / C;
    int rstr = (gridDim.x * blockDim.x) / C;
    float s1 = 0.f, s2 = 0.f;
    for (int r = row; r < N; r += rstr) {
        float v = h[(size_t)r * C + c];
        s1 += v; s2 += v * v;
    }
    if (threadIdx.x < C) { sh1[threadIdx.x] = 0.f; sh2[threadIdx.x] = 0.f; }
    __syncthreads();
    atomicAdd(&sh1[c], s1);
    atomicAdd(&sh2[c], s2);
    __syncthreads();
    if (threadIdx.x < C) {
        atomicAdd(&sums[threadIdx.x],     (double)sh1[threadIdx.x]);
        atomicAdd(&sums[C + threadIdx.x], (double)sh2[threadIdx.x]);
    }
}

__global__ void k_bnfinal(const double* __restrict__ sums, const float* __restrict__ gamma,
                          const float* __restrict__ beta, int C, int N, float* __restrict__ scsh) {
    int c = threadIdx.x;
    if (c < C) {
        double m   = sums[c] / (double)N;
        double var = sums[C + c] / (double)N - m * m;
        float vpe  = (float)var + 1e-5f;
        float sc   = gamma[c] / sqrtf(vpe);
        scsh[c]     = sc;
        scsh[C + c] = beta[c] - (float)m * sc;
    }
}

// BN + ELU for h1 (C=32), output fp16
__global__ void k_bnelu32h(const float* __restrict__ h, int N,
                           const float* __restrict__ scsh, _Float16* __restrict__ hh) {
    int total = N * 4;   // groups of 8 floats
    int i = blockIdx.x * blockDim.x + threadIdx.x;
    int stride = gridDim.x * blockDim.x;
    const float4* hp = (const float4*)h;
    for (; i < total; i += stride) {
        float4 v0 = hp[2 * i], v1 = hp[2 * i + 1];
        int c0 = (i * 8) & 31;
        half8 r;
        r[0] = (_Float16)eluf(v0.x * scsh[c0 + 0] + scsh[32 + c0 + 0]);
        r[1] = (_Float16)eluf(v0.y * scsh[c0 + 1] + scsh[32 + c0 + 1]);
        r[2] = (_Float16)eluf(v0.z * scsh[c0 + 2] + scsh[32 + c0 + 2]);
        r[3] = (_Float16)eluf(v0.w * scsh[c0 + 3] + scsh[32 + c0 + 3]);
        r[4] = (_Float16)eluf(v1.x * scsh[c0 + 4] + scsh[32 + c0 + 4]);
        r[5] = (_Float16)eluf(v1.y * scsh[c0 + 5] + scsh[32 + c0 + 5]);
        r[6] = (_Float16)eluf(v1.z * scsh[c0 + 6] + scsh[32 + c0 + 6]);
        r[7] = (_Float16)eluf(v1.w * scsh[c0 + 7] + scsh[32 + c0 + 7]);
        *(half8*)(hh + (size_t)i * 8) = r;
    }
}

// ---------------- Layer 2: aggregation, 2 edges per wave-iter, 4 in flight ----------------
// Each lane accumulates all 16 k-products for its channel c = lane&31; half-waves
// process different edges; cross-half shfl reduce at the end; A-frag-order store.

__global__ __launch_bounds__(512) void k_agg(
    const _Float16* __restrict__ h1h, const int* __restrict__ rowptr,
    const uint4* __restrict__ edges, _Float16* __restrict__ agg,
    int n0, int n1) {
    int tid   = threadIdx.x;
    int lane  = tid & 63;
    int w     = tid >> 6;
    int c     = lane & 31;
    int khalf = lane >> 5;
    int n = n0 + blockIdx.x * 8 + w;
    if (n >= n1) return;
    float a[16] = {};
    int s = __builtin_amdgcn_readfirstlane(rowptr[n]);
    int e = __builtin_amdgcn_readfirstlane(rowptr[n + 1]);

#define P16(rec, hc) { \
    float bu[4], bv[4]; \
    unpack_basis(rec, bu, bv); \
    float t0 = (hc) * bv[0], t1 = (hc) * bv[1], t2 = (hc) * bv[2], t3 = (hc) * bv[3]; \
    a[0]  += bu[0] * t0; a[1]  += bu[1] * t0; a[2]  += bu[2] * t0; a[3]  += bu[3] * t0; \
    a[4]  += bu[0] * t1; a[5]  += bu[1] * t1; a[6]  += bu[2] * t1; a[7]  += bu[3] * t1; \
    a[8]  += bu[0] * t2; a[9]  += bu[1] * t2; a[10] += bu[2] * t2; a[11] += bu[3] * t2; \
    a[12] += bu[0] * t3; a[13] += bu[1] * t3; a[14] += bu[2] * t3; a[15] += bu[3] * t3; }

    int j = s;
    for (; j + 3 < e; j += 4) {
        uint4 rA = edges[j + khalf];          // halves take j / j+1
        uint4 rB = edges[j + 2 + khalf];      // and j+2 / j+3
        float hA = (float)h1h[(size_t)rA.x * 32 + c];
        float hB = (float)h1h[(size_t)rB.x * 32 + c];
        P16(rA, hA);
        P16(rB, hB);
    }
    for (; j < e; j += 2) {
        int jj = j + khalf;
        bool act = jj < e;
        uint4 r = edges[act ? jj : (e - 1)];
        float hc = act ? (float)h1h[(size_t)r.x * 32 + c] : 0.f;
        P16(r, hc);
    }
#undef P16

    half8 hv;
#pragma unroll
    for (int q = 0; q < 8; ++q) {
        float lo = a[q]     + __shfl_xor(a[q], 32);
        float hi = a[8 + q] + __shfl_xor(a[8 + q], 32);
        hv[q] = (_Float16)(khalf ? hi : lo);
    }
    *(half8*)(agg + (size_t)(n - n0) * 512 + lane * 8) = hv;
}

// ---------------- Layer 2: MFMA GEMM  out2 = [agg|h1h] @ w2f + b2 ----------------

__global__ __launch_bounds__(256) void k_gemm2(
    const _Float16* __restrict__ agg, const _Float16* __restrict__ h1h,
    const _Float16* __restrict__ w2f, const float* __restrict__ b2,
    float* __restrict__ out2, int n0, int n1, int ntiles) {
    extern __shared__ _Float16 w2s[];
    int tid = threadIdx.x;
    {
        const uint4* s4 = (const uint4*)w2f;
        uint4* d4 = (uint4*)w2s;
        for (int i = tid; i < 4352; i += 256) d4[i] = s4[i];   // 69632 B
    }
    __syncthreads();
    const half8* bp = (const half8*)w2s;
    int l   = tid & 63, w = tid >> 6;
    int klo = (l >> 4) << 3;
    int m   = l & 15;
    float bv0 = b2[m], bv1 = b2[16 + m], bv2 = b2[32 + m], bv3 = b2[48 + m];
    for (int tile = blockIdx.x; tile < ntiles; tile += gridDim.x) {
        int wavebase = n0 + tile * 64 + w * 16;
        if (wavebase >= n1) continue;
        int arow = wavebase + m; if (arow > n1 - 1) arow = n1 - 1;
        const half8* ap = (const half8*)(agg + (size_t)(arow - n0) * 512 + klo);
        f32x4 acc0 = {0.f,0.f,0.f,0.f}, acc1 = acc0, acc2 = acc0, acc3 = acc0;
#pragma unroll
        for (int s = 0; s < 16; ++s) {
            half8 a = ap[s * 4];
            int bi = (s << 8) + l;
            acc0 = __builtin_amdgcn_mfma_f32_16x16x32_f16(a, bp[bi      ], acc0, 0, 0, 0);
            acc1 = __builtin_amdgcn_mfma_f32_16x16x32_f16(a, bp[bi +  64], acc1, 0, 0, 0);
            acc2 = __builtin_amdgcn_mfma_f32_16x16x32_f16(a, bp[bi + 128], acc2, 0, 0, 0);
            acc3 = __builtin_amdgcn_mfma_f32_16x16x32_f16(a, bp[bi + 192], acc3, 0, 0, 0);
        }
        {
            half8 a = *(const half8*)(h1h + (size_t)arow * 32 + klo);
            int bi = (16 << 8) + l;
            acc0 = __builtin_amdgcn_mfma_f32_16x16x32_f16(a, bp[bi      ], acc0, 0, 0, 0);
            acc1 = __builtin_amdgcn_mfma_f32_16x16x32_f16(a, bp[bi +  64], acc1, 0, 0, 0);
            acc2 = __builtin_amdgcn_mfma_f32_16x16x32_f16(a, bp[bi + 128], acc2, 0, 0, 0);
            acc3 = __builtin_amdgcn_mfma_f32_16x16x32_f16(a, bp[bi + 192], acc3, 0, 0, 0);
        }
        int rbase = wavebase + ((l >> 4) << 2);
#pragma unroll
        for (int r = 0; r < 4; ++r) {
            int node = rbase + r;
            if (node < n1) {
                size_t o = (size_t)node * 64;
                out2[o + m]      = acc0[r] + bv0;
                out2[o + 16 + m] = acc1[r] + bv1;
                out2[o + 32 + m] = acc2[r] + bv2;
                out2[o + 48 + m] = acc3[r] + bv3;
            }
        }
    }
}

// ---------------- Final MLP with fused BN2+ELU: 64 -> 128 (ELU) -> 1 ----------------

__global__ __launch_bounds__(256) void k_fc(
    const float* __restrict__ h2raw, const float* __restrict__ scsh,
    const float* __restrict__ fc1w, const float* __restrict__ fc1b,
    const float* __restrict__ fc2w, const float* __restrict__ fc2b,
    float* __restrict__ out, int N) {
    __shared__ float w1t[128 * 64];  // transposed [o][cd]
    __shared__ float b1s[128], w2sv[128], scs[64], shs[64];
    int tid = threadIdx.x;
    for (int i = tid; i < 8192; i += 256) {
        int o = i >> 6, cd = i & 63;
        w1t[o * 64 + cd] = fc1w[cd * 128 + o];
    }
    if (tid < 128) { b1s[tid] = fc1b[tid]; w2sv[tid] = fc2w[tid]; }
    if (tid < 64)  { scs[tid] = scsh[tid]; shs[tid] = scsh[64 + tid]; }
    __syncthreads();
    int n0 = (blockIdx.x * 256 + tid) * 2;
    if (n0 >= N) return;
    int n1i = (n0 + 1 < N) ? n0 + 1 : n0;
    float h0[64], h1v[64];
    {
        const float4* p0 = (const float4*)(h2raw + (size_t)n0 * 64);
        const float4* p1 = (const float4*)(h2raw + (size_t)n1i * 64);
#pragma unroll
        for (int i = 0; i < 16; ++i) {
            int c = 4 * i;
            float4 a = p0[i];
            h0[c + 0] = eluf(a.x * scs[c + 0] + shs[c + 0]);
            h0[c + 1] = eluf(a.y * scs[c + 1] + shs[c + 1]);
            h0[c + 2] = eluf(a.z * scs[c + 2] + shs[c + 2]);
            h0[c + 3] = eluf(a.w * scs[c + 3] + shs[c + 3]);
            float4 b = p1[i];
            h1v[c + 0] = eluf(b.x * scs[c + 0] + shs[c + 0]);
            h1v[c + 1] = eluf(b.y * scs[c + 1] + shs[c + 1]);
            h1v[c + 2] = eluf(b.z * scs[c + 2] + shs[c + 2]);
            h1v[c + 3] = eluf(b.w * scs[c + 3] + shs[c + 3]);
        }
    }
    float acc0 = fc2b[0], acc1 = acc0;
    for (int o = 0; o < 128; ++o) {
        float p0 = b1s[o], p1 = p0;
        const float4* wp = (const float4*)(w1t + o * 64);
#pragma unroll
        for (int q = 0; q < 16; ++q) {
            float4 wv = wp[q];
            p0 += h0[4 * q] * wv.x + h0[4 * q + 1] * wv.y + h0[4 * q + 2] * wv.z + h0[4 * q + 3] * wv.w;
            p1 += h1v[4 * q] * wv.x + h1v[4 * q + 1] * wv.y + h1v[4 * q + 2] * wv.z + h1v[4 * q + 3] * wv.w;
        }
        float w2v = w2sv[o];
        acc0 += eluf(p0) * w2v;
        acc1 += eluf(p1) * w2v;
    }
    out[n0] = acc0;
    if (n0 + 1 < N) out[n0 + 1] = acc1;
}

// ---------------------------------------------------------------------------

extern "C" void kernel_launch(void* const* d_in, const int* in_sizes, int n_in,
                              void* d_out, int out_size, void* d_ws, size_t ws_size,
                              hipStream_t stream) {
    const float* x     = (const float*)d_in[0];
    const int*   ei    = (const int*)  d_in[1];
    const float* attr  = (const float*)d_in[2];
    const float* w1    = (const float*)d_in[3];
    const float* root1 = (const float*)d_in[4];
    const float* b1    = (const float*)d_in[5];
    const float* g1    = (const float*)d_in[6];
    const float* be1   = (const float*)d_in[7];
    const float* w2    = (const float*)d_in[8];
    const float* root2 = (const float*)d_in[9];
    const float* b2    = (const float*)d_in[10];
    const float* g2    = (const float*)d_in[11];
    const float* be2   = (const float*)d_in[12];
    const float* fc1w  = (const float*)d_in[13];
    const float* fc1b  = (const float*)d_in[14];
    const float* fc2w  = (const float*)d_in[15];
    const float* fc2b  = (const float*)d_in[16];
    float* out = (float*)d_out;

    int N = in_sizes[0];          // 150000
    int E = in_sizes[1] / 2;      // 3000000

    const int CHUNK = 16384;
    int nWG  = (E + CHUNK - 1) / CHUNK;     // 184
    int NBUK = (N + 255) >> 8;              // 586
    int M    = NBUK * nWG;                  // ~108k

    char* ws = (char*)d_ws;
    size_t off = 0;
    auto alloc = [&](size_t bytes) -> void* {
        void* p = ws + off;
        off = (off + bytes + 255) & ~(size_t)255;
        return p;
    };
    int*      rowptr    = (int*)     alloc((size_t)(N + 1) * 4);
    int*      blockSums = (int*)     alloc(1024 * 4);
    int*      blockOff  = (int*)     alloc(1024 * 4);
    double*   bnsum1    = (double*)  alloc(128 * 8);
    double*   bnsum2    = (double*)  alloc(128 * 8);
    float*    scsh1     = (float*)   alloc(64 * 4);
    float*    scsh2     = (float*)   alloc(128 * 4);
    _Float16* w2f       = (_Float16*)alloc(34816 * 2);
    int*      cnt       = (int*)     alloc((size_t)M * 4);
    int*      offs      = (int*)     alloc((size_t)M * 4);
    uint4*    edges     = (uint4*)   alloc((size_t)E * 16);
    size_t    Roff      = off;              // start of aliasable region
    float*    h1        = (float*)   alloc((size_t)N * 32 * 4);   // 19.2 MB
    _Float16* h1h       = (_Float16*)alloc((size_t)N * 32 * 2);   //  9.6 MB
    float*    out2      = (float*)   alloc((size_t)N * 64 * 4);   // 38.4 MB
    // buf1 + dl1 alias [h1|h1h|out2] (51 MB <= 67 MB); dead before conv1 runs
    uint4*         buf1 = (uint4*)(ws + Roff);
    unsigned char* dl1  = (unsigned char*)(ws + Roff + (size_t)E * 16);
    // agg buffer takes the remainder (512 fp16 = 1024 B/node)
    size_t avail = (ws_size > off) ? (ws_size - off) : 0;
    int NC = (int)(avail / 1024);
    if (NC > N) NC = N;
    NC &= ~255;
    if (NC < 256) NC = 256;
    _Float16* aggbuf = (_Float16*)alloc((size_t)NC * 1024);
    (void)n_in; (void)out_size;

    hipMemsetAsync(bnsum1, 0, 128 * 8, stream);
    hipMemsetAsync(bnsum2, 0, 128 * 8, stream);

    size_t ldsA = (size_t)NBUK * 4;
    int NBs = (M + 1023) / 1024;            // ~106 <= 256

    k_w2pack<<<136, 256, 0, stream>>>(w2, root2, w2f);
    kA1_hist<<<nWG, 256, ldsA, stream>>>(ei + E, E, cnt, nWG, NBUK, CHUNK);
    k_scan1<<<NBs, 256, 0, stream>>>(cnt, M, offs, blockSums);
    k_scan2<<<1, 256, 0, stream>>>(blockSums, NBs, blockOff);
    k_scan3b<<<(M + 255) / 256, 256, 0, stream>>>(offs, blockOff, M);
    kA2_fill<<<nWG, 256, ldsA, stream>>>(ei, attr, E, offs, nWG, NBUK, CHUNK, buf1, dl1);
    kB_sort<<<NBUK, 256, 0, stream>>>(buf1, dl1, offs, nWG, NBUK, N, E, edges, rowptr);

    k_conv1<<<(N + 255) / 256, 256, 0, stream>>>(x, rowptr, edges, w1, root1, b1, h1, N);
    k_bnstat<32><<<256, 256, 0, stream>>>(h1, N, bnsum1);
    k_bnfinal<<<1, 64, 0, stream>>>(bnsum1, g1, be1, 32, N, scsh1);
    k_bnelu32h<<<1024, 256, 0, stream>>>(h1, N, scsh1, h1h);

    for (int c0 = 0; c0 < N; c0 += NC) {
        int c1 = c0 + NC; if (c1 > N) c1 = N;
        int cnt2 = c1 - c0;
        k_agg<<<(cnt2 + 7) / 8, 512, 0, stream>>>(h1h, rowptr, edges, aggbuf, c0, c1);
        int ntiles = (cnt2 + 63) / 64;
        int grid = ntiles < 1184 ? ntiles : 1184;
        k_gemm2<<<grid, 256, 69632, stream>>>(aggbuf, h1h, w2f, b2, out2, c0, c1, ntiles);
    }

    k_bnstat<64><<<256, 256, 0, stream>>>(out2, N, bnsum2);
    k_bnfinal<<<1, 64, 0, stream>>>(bnsum2, g2, be2, 64, N, scsh2);

    int pairs = (N + 1) / 2;
    k_fc<<<(pairs + 255) / 256, 256, 0, stream>>>(out2, scsh2, fc1w, fc1b, fc2w, fc2b, out, N);
}

// Round 7
// 544.443 us; speedup vs baseline: 3.3097x; 1.2031x over previous
//
#include <hip/hip_runtime.h>
#include <hip/hip_fp16.h>
#include <math.h>

// ---------------------------------------------------------------------------
// SplineCNN (K=4, dim=2, deg=2). v7: MFMA final MLP (BN2+ELU fused into
// A-fragment), fp16 h1/out2 storage end-to-end after conv1.
// ---------------------------------------------------------------------------

typedef _Float16 half8 __attribute__((ext_vector_type(8)));
typedef float    f32x4 __attribute__((ext_vector_type(4)));

__device__ __forceinline__ void bspline4(float a, float B[4]) {
    a = fminf(fmaxf(a, 0.f), 1.f);
    float v  = a * 2.0f;          // K - DEG = 2
    float kv = floorf(v);
    float t  = v - kv;
    int   ik = (int)kv;           // 0..2
    float b0 = 0.5f * (1.f - t) * (1.f - t);
    float b1 = (t - t * t) + 0.5f;
    float b2 = 0.5f * t * t;
    int c0 = ik;
    int c1 = ik + 1;
    int c2 = ik + 2; if (c2 > 3) c2 = 3;
#pragma unroll
    for (int j = 0; j < 4; ++j)
        B[j] = (c0 == j ? b0 : 0.f) + (c1 == j ? b1 : 0.f) + (c2 == j ? b2 : 0.f);
}

__device__ __forceinline__ float eluf(float x) {
    return x > 0.f ? x : expm1f(x);
}

// unpack 16B edge record -> bu[4], bv[4] (src handled by caller)
__device__ __forceinline__ void unpack_basis(uint4 rec, float bu[4], float bv[4]) {
    float2 f01 = __half22float2(*(const __half2*)&rec.y);
    float2 f23 = __half22float2(*(const __half2*)&rec.z);
    float2 f45 = __half22float2(*(const __half2*)&rec.w);
    bu[0] = f01.x; bu[1] = f01.y; bu[2] = f23.x;
    bu[3] = 1.f - (bu[0] + bu[1] + bu[2]);
    bv[0] = f23.y; bv[1] = f45.x; bv[2] = f45.y;
    bv[3] = 1.f - (bv[0] + bv[1] + bv[2]);
}

// ---------------- Phase A: bucketed partition (bucket = dst >> 8) ----------------

__global__ void kA1_hist(const int* __restrict__ dst, int E, int* __restrict__ cnt,
                         int nWG, int NBUK, int CHUNK) {
    extern __shared__ int hist[];   // NBUK ints
    int wg = blockIdx.x, tid = threadIdx.x;
    for (int b = tid; b < NBUK; b += 256) hist[b] = 0;
    __syncthreads();
    int base = wg * CHUNK;
    int end  = base + CHUNK; if (end > E) end = E;
    for (int i = base + tid; i < end; i += 256)
        atomicAdd(&hist[dst[i] >> 8], 1);
    __syncthreads();
    for (int b = tid; b < NBUK; b += 256) cnt[b * nWG + wg] = hist[b];
}

__global__ void k_scan1(const int* __restrict__ in, int M,
                        int* __restrict__ outp, int* __restrict__ blockSums) {
    __shared__ int wsum[4];
    int tid  = threadIdx.x;
    int base = blockIdx.x * 1024 + tid * 4;
    int d0 = (base + 0) < M ? in[base + 0] : 0;
    int d1 = (base + 1) < M ? in[base + 1] : 0;
    int d2 = (base + 2) < M ? in[base + 2] : 0;
    int d3 = (base + 3) < M ? in[base + 3] : 0;
    int s4 = d0 + d1 + d2 + d3;
    int lane = tid & 63, wid = tid >> 6;
    int inc = s4;
#pragma unroll
    for (int off = 1; off < 64; off <<= 1) {
        int t = __shfl_up(inc, off);
        if (lane >= off) inc += t;
    }
    if (lane == 63) wsum[wid] = inc;
    __syncthreads();
    if (tid == 0) {
        int acc = 0;
#pragma unroll
        for (int w = 0; w < 4; ++w) { int t = wsum[w]; wsum[w] = acc; acc += t; }
    }
    __syncthreads();
    int ebase = wsum[wid] + inc - s4;
    if ((base + 0) < M) outp[base + 0] = ebase;
    if ((base + 1) < M) outp[base + 1] = ebase + d0;
    if ((base + 2) < M) outp[base + 2] = ebase + d0 + d1;
    if ((base + 3) < M) outp[base + 3] = ebase + d0 + d1 + d2;
    if (tid == 255) blockSums[blockIdx.x] = ebase + s4;
}

__global__ void k_scan2(const int* __restrict__ blockSums, int NB, int* __restrict__ blockOff) {
    __shared__ int sh[256];
    int tid = threadIdx.x;
    int own = (tid < NB) ? blockSums[tid] : 0;
    sh[tid] = own;
    __syncthreads();
    for (int off = 1; off < 256; off <<= 1) {
        int v = (tid >= off) ? sh[tid - off] : 0;
        __syncthreads();
        sh[tid] += v;
        __syncthreads();
    }
    if (tid < NB) blockOff[tid] = sh[tid] - own;
}

__global__ void k_scan3b(int* __restrict__ arr, const int* __restrict__ blockOff, int M) {
    int i = blockIdx.x * blockDim.x + threadIdx.x;
    if (i < M) arr[i] += blockOff[i >> 10];
}

// fill pass: each WG writes contiguous runs per bucket (LDS cursors from off[])
__global__ void kA2_fill(const int* __restrict__ ei, const float* __restrict__ attr, int E,
                         const int* __restrict__ off, int nWG, int NBUK, int CHUNK,
                         uint4* __restrict__ buf1, unsigned char* __restrict__ dl1) {
    extern __shared__ int cur[];    // NBUK ints
    int wg = blockIdx.x, tid = threadIdx.x;
    for (int b = tid; b < NBUK; b += 256) cur[b] = off[b * nWG + wg];
    __syncthreads();
    int base = wg * CHUNK;
    int end  = base + CHUNK; if (end > E) end = E;
    for (int i = base + tid; i < end; i += 256) {
        int d = ei[E + i];
        int pos = atomicAdd(&cur[d >> 8], 1);
        float Bu[4], Bv[4];
        bspline4(attr[2 * i + 0], Bu);
        bspline4(attr[2 * i + 1], Bv);
        __half2 p01 = __floats2half2_rn(Bu[0], Bu[1]);
        __half2 p23 = __floats2half2_rn(Bu[2], Bv[0]);
        __half2 p45 = __floats2half2_rn(Bv[1], Bv[2]);
        uint4 rec;
        rec.x = (unsigned)ei[i];
        rec.y = *(const unsigned*)&p01;
        rec.z = *(const unsigned*)&p23;
        rec.w = *(const unsigned*)&p45;
        buf1[pos] = rec;
        dl1[pos]  = (unsigned char)(d & 255);
    }
}

// ---------------- Phase B: per-bucket exact-dst sort + rowptr ----------------

__global__ __launch_bounds__(256) void kB_sort(
    const uint4* __restrict__ buf1, const unsigned char* __restrict__ dl1,
    const int* __restrict__ off, int nWG, int NBUK, int N, int E,
    uint4* __restrict__ edges, int* __restrict__ rowptr) {
    __shared__ int hist[256], pref[256], curs[256];
    __shared__ int sbase, ssize;
    int b = blockIdx.x, tid = threadIdx.x;
    if (tid == 0) {
        int s  = off[b * nWG];
        int e2 = (b + 1 < NBUK) ? off[(b + 1) * nWG] : E;
        sbase = s; ssize = e2 - s;
    }
    hist[tid] = 0;
    __syncthreads();
    int base = sbase, size = ssize;
    for (int i = tid; i < size; i += 256) atomicAdd(&hist[dl1[base + i]], 1);
    __syncthreads();
    if (tid == 0) {
        int acc = 0;
        for (int j = 0; j < 256; ++j) { pref[j] = acc; acc += hist[j]; }
    }
    __syncthreads();
    curs[tid] = pref[tid];
    int node = b * 256 + tid;
    if (node < N) rowptr[node] = base + pref[tid];
    if (b == NBUK - 1 && tid == 0) rowptr[N] = E;
    __syncthreads();
    for (int i = tid; i < size; i += 256) {
        int p = atomicAdd(&curs[dl1[base + i]], 1);
        edges[base + p] = buf1[base + i];
    }
}

// ---------------- w2 + root2 pre-pack into B-fragment order (fp16) ----------------

__global__ void k_w2pack(const float* __restrict__ w2, const float* __restrict__ root2,
                         _Float16* __restrict__ w2f) {
    int f = blockIdx.x * blockDim.x + threadIdx.x;
    int stride = gridDim.x * blockDim.x;
    for (; f < 34816; f += stride) {
        int j = f & 7, l = (f >> 3) & 63, t = (f >> 9) & 3;
        int o = t * 16 + (l & 15);
        float v;
        if (f < 32768) {
            int s = f >> 11;
            int p = s * 32 + ((l >> 4) << 3) + j;
            int lane_a = p >> 3, q = p & 7;
            int c = lane_a & 31, kidx = ((lane_a >> 5) << 3) + q;
            v = w2[(kidx * 32 + c) * 64 + o];
        } else {
            int c = ((l >> 4) << 3) + j;
            v = root2[c * 64 + o];
        }
        w2f[f] = (_Float16)v;
    }
}

// ---------------- fc1w pre-pack into B-fragment order (fp16) ----------------
// slot f = ((s*8 + t)*64 + l)*8 + j ; k = s*32 + (l>>4)*8 + j ; o = t*16 + (l&15)

__global__ void k_fcpack(const float* __restrict__ fc1w, _Float16* __restrict__ fc1wf) {
    int f = blockIdx.x * blockDim.x + threadIdx.x;
    if (f >= 8192) return;
    int j = f & 7, l = (f >> 3) & 63, t = (f >> 9) & 7, s = f >> 12;
    int k = s * 32 + ((l >> 4) << 3) + j;
    int o = t * 16 + (l & 15);
    fc1wf[f] = (_Float16)fc1w[k * 128 + o];
}

// ---------------- Layer 1 conv (in=1 -> out=32), thread per node, fp16 out ----------------

__global__ void k_conv1(const float* __restrict__ x, const int* __restrict__ rowptr,
                        const uint4* __restrict__ edges,
                        const float* __restrict__ w1, const float* __restrict__ root1,
                        const float* __restrict__ b1, _Float16* __restrict__ h1h, int N) {
    __shared__ float w1s[16 * 32];
    __shared__ float r1s[32], b1s[32];
    int tid = threadIdx.x;
    for (int i = tid; i < 512; i += blockDim.x) w1s[i] = w1[i];
    if (tid < 32) { r1s[tid] = root1[tid]; b1s[tid] = b1[tid]; }
    __syncthreads();
    int n = blockIdx.x * blockDim.x + tid;
    if (n >= N) return;
    float agg[16] = {};
    int s = rowptr[n], e = rowptr[n + 1];

#define P1(rec, xs) { \
    float bu[4], bv[4]; \
    unpack_basis(rec, bu, bv); \
    float t0 = (xs) * bv[0], t1 = (xs) * bv[1], t2 = (xs) * bv[2], t3 = (xs) * bv[3]; \
    agg[0]  += bu[0] * t0; agg[1]  += bu[1] * t0; agg[2]  += bu[2] * t0; agg[3]  += bu[3] * t0; \
    agg[4]  += bu[0] * t1; agg[5]  += bu[1] * t1; agg[6]  += bu[2] * t1; agg[7]  += bu[3] * t1; \
    agg[8]  += bu[0] * t2; agg[9]  += bu[1] * t2; agg[10] += bu[2] * t2; agg[11] += bu[3] * t2; \
    agg[12] += bu[0] * t3; agg[13] += bu[1] * t3; agg[14] += bu[2] * t3; agg[15] += bu[3] * t3; }

    int j = s;
    for (; j + 3 < e; j += 4) {
        uint4 r0 = edges[j], r1 = edges[j + 1], r2 = edges[j + 2], r3 = edges[j + 3];
        float x0 = x[r0.x], x1 = x[r1.x], x2 = x[r2.x], x3 = x[r3.x];
        P1(r0, x0); P1(r1, x1); P1(r2, x2); P1(r3, x3);
    }
    for (; j < e; ++j) {
        uint4 r = edges[j];
        float xs = x[r.x];
        P1(r, xs);
    }
#undef P1

    float xn = x[n];
    _Float16* hp = h1h + (size_t)n * 32;
#pragma unroll
    for (int o8 = 0; o8 < 4; ++o8) {
        half8 hv;
#pragma unroll
        for (int oo = 0; oo < 8; ++oo) {
            int o = o8 * 8 + oo;
            float acc = b1s[o] + xn * r1s[o];
#pragma unroll
            for (int k = 0; k < 16; ++k) acc += agg[k] * w1s[k * 32 + o];
            hv[oo] = (_Float16)acc;
        }
        *(half8*)(hp + o8 * 8) = hv;
    }
}

// ---------------- BatchNorm (fp16 input stats) ----------------

template <int C>
__global__ void k_bnstath(const _Float16* __restrict__ h, int N, double* __restrict__ sums) {
    __shared__ float sh1[C], sh2[C];
    int tid  = blockIdx.x * blockDim.x + threadIdx.x;
    int c    = tid & (C - 1);
    int row  = tid / C;
    int rstr = (gridDim.x * blockDim.x) / C;
    float s1 = 0.f, s2 = 0.f;
    for (int r = row; r < N; r += rstr) {
        float v = (float)h[(size_t)r * C + c];
        s1 += v; s2 += v * v;
    }
    if (threadIdx.x < C) { sh1[threadIdx.x] = 0.f; sh2[threadIdx.x] = 0.f; }
    __syncthreads();
    atomicAdd(&sh1[c], s1);
    atomicAdd(&sh2[c], s2);
    __syncthreads();
    if (threadIdx.x < C) {
        atomicAdd(&sums[threadIdx.x],     (double)sh1[threadIdx.x]);
        atomicAdd(&sums[C + threadIdx.x], (double)sh2[threadIdx.x]);
    }
}

__global__ void k_bnfinal(const double* __restrict__ sums, const float* __restrict__ gamma,
                          const float* __restrict__ beta, int C, int N, float* __restrict__ scsh) {
    int c = threadIdx.x;
    if (c < C) {
        double m   = sums[c] / (double)N;
        double var = sums[C + c] / (double)N - m * m;
        float vpe  = (float)var + 1e-5f;
        float sc   = gamma[c] / sqrtf(vpe);
        scsh[c]     = sc;
        scsh[C + c] = beta[c] - (float)m * sc;
    }
}

// BN + ELU for h1h (C=32), in place fp16
__global__ void k_bnelu32h(_Float16* __restrict__ hh, int N, const float* __restrict__ scsh) {
    int total = N * 4;   // groups of 8 halves
    int i = blockIdx.x * blockDim.x + threadIdx.x;
    int stride = gridDim.x * blockDim.x;
    for (; i < total; i += stride) {
        half8 v = *(half8*)(hh + (size_t)i * 8);
        int c0 = (i * 8) & 31;
        half8 r;
#pragma unroll
        for (int j = 0; j < 8; ++j)
            r[j] = (_Float16)eluf((float)v[j] * scsh[c0 + j] + scsh[32 + c0 + j]);
        *(half8*)(hh + (size_t)i * 8) = r;
    }
}

// ---------------- Layer 2: aggregation, 2 edges per wave-iter, 4 in flight ----------------

__global__ __launch_bounds__(512) void k_agg(
    const _Float16* __restrict__ h1h, const int* __restrict__ rowptr,
    const uint4* __restrict__ edges, _Float16* __restrict__ agg,
    int n0, int n1) {
    int tid   = threadIdx.x;
    int lane  = tid & 63;
    int w     = tid >> 6;
    int c     = lane & 31;
    int khalf = lane >> 5;
    int n = n0 + blockIdx.x * 8 + w;
    if (n >= n1) return;
    float a[16] = {};
    int s = __builtin_amdgcn_readfirstlane(rowptr[n]);
    int e = __builtin_amdgcn_readfirstlane(rowptr[n + 1]);

#define P16(rec, hc) { \
    float bu[4], bv[4]; \
    unpack_basis(rec, bu, bv); \
    float t0 = (hc) * bv[0], t1 = (hc) * bv[1], t2 = (hc) * bv[2], t3 = (hc) * bv[3]; \
    a[0]  += bu[0] * t0; a[1]  += bu[1] * t0; a[2]  += bu[2] * t0; a[3]  += bu[3] * t0; \
    a[4]  += bu[0] * t1; a[5]  += bu[1] * t1; a[6]  += bu[2] * t1; a[7]  += bu[3] * t1; \
    a[8]  += bu[0] * t2; a[9]  += bu[1] * t2; a[10] += bu[2] * t2; a[11] += bu[3] * t2; \
    a[12] += bu[0] * t3; a[13] += bu[1] * t3; a[14] += bu[2] * t3; a[15] += bu[3] * t3; }

    int j = s;
    for (; j + 3 < e; j += 4) {
        uint4 rA = edges[j + khalf];
        uint4 rB = edges[j + 2 + khalf];
        float hA = (float)h1h[(size_t)rA.x * 32 + c];
        float hB = (float)h1h[(size_t)rB.x * 32 + c];
        P16(rA, hA);
        P16(rB, hB);
    }
    for (; j < e; j += 2) {
        int jj = j + khalf;
        bool act = jj < e;
        uint4 r = edges[act ? jj : (e - 1)];
        float hc = act ? (float)h1h[(size_t)r.x * 32 + c] : 0.f;
        P16(r, hc);
    }
#undef P16

    half8 hv;
#pragma unroll
    for (int q = 0; q < 8; ++q) {
        float lo = a[q]     + __shfl_xor(a[q], 32);
        float hi = a[8 + q] + __shfl_xor(a[8 + q], 32);
        hv[q] = (_Float16)(khalf ? hi : lo);
    }
    *(half8*)(agg + (size_t)(n - n0) * 512 + lane * 8) = hv;
}

// ---------------- Layer 2: MFMA GEMM  out2h = [agg|h1h] @ w2f + b2 (fp16 out) ----------------

__global__ __launch_bounds__(256) void k_gemm2(
    const _Float16* __restrict__ agg, const _Float16* __restrict__ h1h,
    const _Float16* __restrict__ w2f, const float* __restrict__ b2,
    _Float16* __restrict__ out2h, int n0, int n1, int ntiles) {
    extern __shared__ _Float16 w2s[];
    int tid = threadIdx.x;
    {
        const uint4* s4 = (const uint4*)w2f;
        uint4* d4 = (uint4*)w2s;
        for (int i = tid; i < 4352; i += 256) d4[i] = s4[i];   // 69632 B
    }
    __syncthreads();
    const half8* bp = (const half8*)w2s;
    int l   = tid & 63, w = tid >> 6;
    int klo = (l >> 4) << 3;
    int m   = l & 15;
    float bv0 = b2[m], bv1 = b2[16 + m], bv2 = b2[32 + m], bv3 = b2[48 + m];
    for (int tile = blockIdx.x; tile < ntiles; tile += gridDim.x) {
        int wavebase = n0 + tile * 64 + w * 16;
        if (wavebase >= n1) continue;
        int arow = wavebase + m; if (arow > n1 - 1) arow = n1 - 1;
        const half8* ap = (const half8*)(agg + (size_t)(arow - n0) * 512 + klo);
        f32x4 acc0 = {0.f,0.f,0.f,0.f}, acc1 = acc0, acc2 = acc0, acc3 = acc0;
#pragma unroll
        for (int s = 0; s < 16; ++s) {
            half8 a = ap[s * 4];
            int bi = (s << 8) + l;
            acc0 = __builtin_amdgcn_mfma_f32_16x16x32_f16(a, bp[bi      ], acc0, 0, 0, 0);
            acc1 = __builtin_amdgcn_mfma_f32_16x16x32_f16(a, bp[bi +  64], acc1, 0, 0, 0);
            acc2 = __builtin_amdgcn_mfma_f32_16x16x32_f16(a, bp[bi + 128], acc2, 0, 0, 0);
            acc3 = __builtin_amdgcn_mfma_f32_16x16x32_f16(a, bp[bi + 192], acc3, 0, 0, 0);
        }
        {
            half8 a = *(const half8*)(h1h + (size_t)arow * 32 + klo);
            int bi = (16 << 8) + l;
            acc0 = __builtin_amdgcn_mfma_f32_16x16x32_f16(a, bp[bi      ], acc0, 0, 0, 0);
            acc1 = __builtin_amdgcn_mfma_f32_16x16x32_f16(a, bp[bi +  64], acc1, 0, 0, 0);
            acc2 = __builtin_amdgcn_mfma_f32_16x16x32_f16(a, bp[bi + 128], acc2, 0, 0, 0);
            acc3 = __builtin_amdgcn_mfma_f32_16x16x32_f16(a, bp[bi + 192], acc3, 0, 0, 0);
        }
        int rbase = wavebase + ((l >> 4) << 2);
#pragma unroll
        for (int r = 0; r < 4; ++r) {
            int node = rbase + r;
            if (node < n1) {
                size_t o = (size_t)node * 64;
                out2h[o + m]      = (_Float16)(acc0[r] + bv0);
                out2h[o + 16 + m] = (_Float16)(acc1[r] + bv1);
                out2h[o + 32 + m] = (_Float16)(acc2[r] + bv2);
                out2h[o + 48 + m] = (_Float16)(acc3[r] + bv3);
            }
        }
    }
}

// ---------------- Final MLP via MFMA: elu(bn(out2h)) @ fc1w -> elu -> @ fc2w ----------------
// wave = 16 nodes; BN2+ELU applied in-register on the A fragment.

__global__ __launch_bounds__(256) void k_fcm(
    const _Float16* __restrict__ out2h, const _Float16* __restrict__ fc1wf,
    const float* __restrict__ scsh, const float* __restrict__ fc1b,
    const float* __restrict__ fc2w, const float* __restrict__ fc2b,
    float* __restrict__ out, int N, int ntiles) {
    __shared__ _Float16 fw[8192];
    __shared__ float scs[64], shs[64], b1s[128], w2sv[128];
    int tid = threadIdx.x;
    {
        const uint4* s4 = (const uint4*)fc1wf;
        uint4* d4 = (uint4*)fw;
        for (int i = tid; i < 1024; i += 256) d4[i] = s4[i];
    }
    if (tid < 128) { b1s[tid] = fc1b[tid]; w2sv[tid] = fc2w[tid]; }
    if (tid < 64)  { scs[tid] = scsh[tid]; shs[tid] = scsh[64 + tid]; }
    __syncthreads();
    const half8* bp = (const half8*)fw;
    int l = tid & 63, w = tid >> 6;
    int g = l >> 4, m = l & 15, klo = g * 8;
    float f2b = fc2b[0];
    for (int tile = blockIdx.x * 4 + w; tile < ntiles; tile += gridDim.x * 4) {
        int base = tile * 16;
        int arow = base + m; if (arow > N - 1) arow = N - 1;
        const half8* hp = (const half8*)(out2h + (size_t)arow * 64 + klo);
        half8 r0 = hp[0];   // k = klo + j
        half8 r1 = hp[4];   // k = 32 + klo + j
        half8 a0, a1;
#pragma unroll
        for (int j = 0; j < 8; ++j) {
            int c0 = klo + j, c1 = 32 + klo + j;
            a0[j] = (_Float16)eluf((float)r0[j] * scs[c0] + shs[c0]);
            a1[j] = (_Float16)eluf((float)r1[j] * scs[c1] + shs[c1]);
        }
        f32x4 acc[8];
#pragma unroll
        for (int t = 0; t < 8; ++t) {
            f32x4 z = {0.f, 0.f, 0.f, 0.f};
            acc[t] = __builtin_amdgcn_mfma_f32_16x16x32_f16(a0, bp[t * 64 + l], z, 0, 0, 0);
            acc[t] = __builtin_amdgcn_mfma_f32_16x16x32_f16(a1, bp[(8 + t) * 64 + l], acc[t], 0, 0, 0);
        }
#pragma unroll
        for (int r = 0; r < 4; ++r) {
            float sum = 0.f;
#pragma unroll
            for (int t = 0; t < 8; ++t) {
                int o = t * 16 + m;
                sum += eluf(acc[t][r] + b1s[o]) * w2sv[o];
            }
            sum += __shfl_xor(sum, 1);
            sum += __shfl_xor(sum, 2);
            sum += __shfl_xor(sum, 4);
            sum += __shfl_xor(sum, 8);
            int node = base + g * 4 + r;
            if (m == 0 && node < N) out[node] = sum + f2b;
        }
    }
}

// ---------------------------------------------------------------------------

extern "C" void kernel_launch(void* const* d_in, const int* in_sizes, int n_in,
                              void* d_out, int out_size, void* d_ws, size_t ws_size,
                              hipStream_t stream) {
    const float* x     = (const float*)d_in[0];
    const int*   ei    = (const int*)  d_in[1];
    const float* attr  = (const float*)d_in[2];
    const float* w1    = (const float*)d_in[3];
    const float* root1 = (const float*)d_in[4];
    const float* b1    = (const float*)d_in[5];
    const float* g1    = (const float*)d_in[6];
    const float* be1   = (const float*)d_in[7];
    const float* w2    = (const float*)d_in[8];
    const float* root2 = (const float*)d_in[9];
    const float* b2    = (const float*)d_in[10];
    const float* g2    = (const float*)d_in[11];
    const float* be2   = (const float*)d_in[12];
    const float* fc1w  = (const float*)d_in[13];
    const float* fc1b  = (const float*)d_in[14];
    const float* fc2w  = (const float*)d_in[15];
    const float* fc2b  = (const float*)d_in[16];
    float* out = (float*)d_out;

    int N = in_sizes[0];          // 150000
    int E = in_sizes[1] / 2;      // 3000000

    const int CHUNK = 16384;
    int nWG  = (E + CHUNK - 1) / CHUNK;     // 184
    int NBUK = (N + 255) >> 8;              // 586
    int M    = NBUK * nWG;                  // ~108k

    char* ws = (char*)d_ws;
    size_t off = 0;
    auto alloc = [&](size_t bytes) -> void* {
        void* p = ws + off;
        off = (off + bytes + 255) & ~(size_t)255;
        return p;
    };
    int*      rowptr    = (int*)     alloc((size_t)(N + 1) * 4);
    int*      blockSums = (int*)     alloc(1024 * 4);
    int*      blockOff  = (int*)     alloc(1024 * 4);
    double*   bnsum1    = (double*)  alloc(128 * 8);
    double*   bnsum2    = (double*)  alloc(128 * 8);
    float*    scsh1     = (float*)   alloc(64 * 4);
    float*    scsh2     = (float*)   alloc(128 * 4);
    _Float16* w2f       = (_Float16*)alloc(34816 * 2);
    _Float16* fc1wf     = (_Float16*)alloc(8192 * 2);
    int*      cnt       = (int*)     alloc((size_t)M * 4);
    int*      offs      = (int*)     alloc((size_t)M * 4);
    uint4*    edges     = (uint4*)   alloc((size_t)E * 16);
    size_t    Roff      = off;              // start of aliasable region
    _Float16* h1h       = (_Float16*)alloc((size_t)N * 32 * 2);   //  9.6 MB
    _Float16* out2h     = (_Float16*)alloc((size_t)N * 64 * 2);   // 19.2 MB
    // buf1 + dl1 alias [h1h|out2h|aggbuf...] (51 MB); dead before conv1 runs
    uint4*         buf1 = (uint4*)(ws + Roff);
    unsigned char* dl1  = (unsigned char*)(ws + Roff + (size_t)E * 16);
    // agg buffer takes the remainder (512 fp16 = 1024 B/node)
    size_t avail = (ws_size > off) ? (ws_size - off) : 0;
    int NC = (int)(avail / 1024);
    if (NC > N) NC = N;
    NC &= ~255;
    if (NC < 256) NC = 256;
    _Float16* aggbuf = (_Float16*)alloc((size_t)NC * 1024);
    (void)n_in; (void)out_size;

    hipMemsetAsync(bnsum1, 0, 128 * 8, stream);
    hipMemsetAsync(bnsum2, 0, 128 * 8, stream);

    size_t ldsA = (size_t)NBUK * 4;
    int NBs = (M + 1023) / 1024;            // ~106 <= 256

    k_w2pack<<<136, 256, 0, stream>>>(w2, root2, w2f);
    k_fcpack<<<32, 256, 0, stream>>>(fc1w, fc1wf);
    kA1_hist<<<nWG, 256, ldsA, stream>>>(ei + E, E, cnt, nWG, NBUK, CHUNK);
    k_scan1<<<NBs, 256, 0, stream>>>(cnt, M, offs, blockSums);
    k_scan2<<<1, 256, 0, stream>>>(blockSums, NBs, blockOff);
    k_scan3b<<<(M + 255) / 256, 256, 0, stream>>>(offs, blockOff, M);
    kA2_fill<<<nWG, 256, ldsA, stream>>>(ei, attr, E, offs, nWG, NBUK, CHUNK, buf1, dl1);
    kB_sort<<<NBUK, 256, 0, stream>>>(buf1, dl1, offs, nWG, NBUK, N, E, edges, rowptr);

    k_conv1<<<(N + 255) / 256, 256, 0, stream>>>(x, rowptr, edges, w1, root1, b1, h1h, N);
    k_bnstath<32><<<256, 256, 0, stream>>>(h1h, N, bnsum1);
    k_bnfinal<<<1, 64, 0, stream>>>(bnsum1, g1, be1, 32, N, scsh1);
    k_bnelu32h<<<1024, 256, 0, stream>>>(h1h, N, scsh1);

    for (int c0 = 0; c0 < N; c0 += NC) {
        int c1 = c0 + NC; if (c1 > N) c1 = N;
        int cnt2 = c1 - c0;
        k_agg<<<(cnt2 + 7) / 8, 512, 0, stream>>>(h1h, rowptr, edges, aggbuf, c0, c1);
        int ntiles = (cnt2 + 63) / 64;
        int grid = ntiles < 1184 ? ntiles : 1184;
        k_gemm2<<<grid, 256, 69632, stream>>>(aggbuf, h1h, w2f, b2, out2h, c0, c1, ntiles);
    }

    k_bnstath<64><<<256, 256, 0, stream>>>(out2h, N, bnsum2);
    k_bnfinal<<<1, 64, 0, stream>>>(bnsum2, g2, be2, 64, N, scsh2);

    int ntilesF = (N + 15) / 16;
    int gridF = (ntilesF + 3) / 4; if (gridF > 2344) gridF = 2344;
    k_fcm<<<gridF, 256, 0, stream>>>(out2h, fc1wf, scsh2, fc1b, fc2w, fc2b, out, N, ntilesF);
}

// Round 8
// 498.819 us; speedup vs baseline: 3.6124x; 1.0915x over previous
//
#include <hip/hip_runtime.h>
#include <hip/hip_fp16.h>
#include <math.h>

// ---------------------------------------------------------------------------
// SplineCNN (K=4, dim=2, deg=2). v8: kA2_fill does per-WG LDS counting sort
// and emits bucket-runs in sorted slot order (coalesced writes, amp ~1.1).
// MFMA conv2-GEMM and final-MLP as in v7.
// ---------------------------------------------------------------------------

typedef _Float16 half8 __attribute__((ext_vector_type(8)));
typedef float    f32x4 __attribute__((ext_vector_type(4)));

#define ACHUNK 8192   // edges per partition WG (32 per thread)

__device__ __forceinline__ void bspline4(float a, float B[4]) {
    a = fminf(fmaxf(a, 0.f), 1.f);
    float v  = a * 2.0f;          // K - DEG = 2
    float kv = floorf(v);
    float t  = v - kv;
    int   ik = (int)kv;           // 0..2
    float b0 = 0.5f * (1.f - t) * (1.f - t);
    float b1 = (t - t * t) + 0.5f;
    float b2 = 0.5f * t * t;
    int c0 = ik;
    int c1 = ik + 1;
    int c2 = ik + 2; if (c2 > 3) c2 = 3;
#pragma unroll
    for (int j = 0; j < 4; ++j)
        B[j] = (c0 == j ? b0 : 0.f) + (c1 == j ? b1 : 0.f) + (c2 == j ? b2 : 0.f);
}

__device__ __forceinline__ float eluf(float x) {
    return x > 0.f ? x : expm1f(x);
}

// unpack 16B edge record -> bu[4], bv[4] (src handled by caller)
__device__ __forceinline__ void unpack_basis(uint4 rec, float bu[4], float bv[4]) {
    float2 f01 = __half22float2(*(const __half2*)&rec.y);
    float2 f23 = __half22float2(*(const __half2*)&rec.z);
    float2 f45 = __half22float2(*(const __half2*)&rec.w);
    bu[0] = f01.x; bu[1] = f01.y; bu[2] = f23.x;
    bu[3] = 1.f - (bu[0] + bu[1] + bu[2]);
    bv[0] = f23.y; bv[1] = f45.x; bv[2] = f45.y;
    bv[3] = 1.f - (bv[0] + bv[1] + bv[2]);
}

__device__ __forceinline__ uint4 make_edge_rec(unsigned src, float u, float v) {
    float Bu[4], Bv[4];
    bspline4(u, Bu);
    bspline4(v, Bv);
    __half2 p01 = __floats2half2_rn(Bu[0], Bu[1]);
    __half2 p23 = __floats2half2_rn(Bu[2], Bv[0]);
    __half2 p45 = __floats2half2_rn(Bv[1], Bv[2]);
    uint4 rec;
    rec.x = src;
    rec.y = *(const unsigned*)&p01;
    rec.z = *(const unsigned*)&p23;
    rec.w = *(const unsigned*)&p45;
    return rec;
}

// ---------------- Phase A: bucketed partition (bucket = dst >> 8) ----------------

__global__ void kA1_hist(const int* __restrict__ dst, int E, int* __restrict__ cnt,
                         int nWG, int NBUK) {
    extern __shared__ int hist[];   // NBUK ints
    int wg = blockIdx.x, tid = threadIdx.x;
    for (int b = tid; b < NBUK; b += 256) hist[b] = 0;
    __syncthreads();
    int base = wg * ACHUNK;
    int end  = base + ACHUNK; if (end > E) end = E;
    for (int i = base + tid; i < end; i += 256)
        atomicAdd(&hist[dst[i] >> 8], 1);
    __syncthreads();
    for (int b = tid; b < NBUK; b += 256) cnt[b * nWG + wg] = hist[b];
}

__global__ void k_scan1(const int* __restrict__ in, int M,
                        int* __restrict__ outp, int* __restrict__ blockSums) {
    __shared__ int wsum[4];
    int tid  = threadIdx.x;
    int base = blockIdx.x * 1024 + tid * 4;
    int d0 = (base + 0) < M ? in[base + 0] : 0;
    int d1 = (base + 1) < M ? in[base + 1] : 0;
    int d2 = (base + 2) < M ? in[base + 2] : 0;
    int d3 = (base + 3) < M ? in[base + 3] : 0;
    int s4 = d0 + d1 + d2 + d3;
    int lane = tid & 63, wid = tid >> 6;
    int inc = s4;
#pragma unroll
    for (int off = 1; off < 64; off <<= 1) {
        int t = __shfl_up(inc, off);
        if (lane >= off) inc += t;
    }
    if (lane == 63) wsum[wid] = inc;
    __syncthreads();
    if (tid == 0) {
        int acc = 0;
#pragma unroll
        for (int w = 0; w < 4; ++w) { int t = wsum[w]; wsum[w] = acc; acc += t; }
    }
    __syncthreads();
    int ebase = wsum[wid] + inc - s4;
    if ((base + 0) < M) outp[base + 0] = ebase;
    if ((base + 1) < M) outp[base + 1] = ebase + d0;
    if ((base + 2) < M) outp[base + 2] = ebase + d0 + d1;
    if ((base + 3) < M) outp[base + 3] = ebase + d0 + d1 + d2;
    if (tid == 255) blockSums[blockIdx.x] = ebase + s4;
}

__global__ void k_scan2(const int* __restrict__ blockSums, int NB, int* __restrict__ blockOff) {
    __shared__ int sh[256];
    int tid = threadIdx.x;
    int own = (tid < NB) ? blockSums[tid] : 0;
    sh[tid] = own;
    __syncthreads();
    for (int off = 1; off < 256; off <<= 1) {
        int v = (tid >= off) ? sh[tid - off] : 0;
        __syncthreads();
        sh[tid] += v;
        __syncthreads();
    }
    if (tid < NB) blockOff[tid] = sh[tid] - own;
}

__global__ void k_scan3b(int* __restrict__ arr, const int* __restrict__ blockOff, int M) {
    int i = blockIdx.x * blockDim.x + threadIdx.x;
    if (i < M) arr[i] += blockOff[i >> 10];
}

// fill pass v2: LDS counting sort by bucket, then emit slots in order so
// global writes are contiguous runs (full 64B lines at issue time).
__global__ __launch_bounds__(256) void kA2_fill(
    const int* __restrict__ ei, const float* __restrict__ attr, int E,
    const int* __restrict__ offs, int nWG, int NBUK,
    uint4* __restrict__ buf1, unsigned char* __restrict__ dl1) {
    extern __shared__ int lds[];
    int*            hist  = lds;                       // NBUK
    int*            pref  = hist + NBUK;               // NBUK
    unsigned short* s2e   = (unsigned short*)(pref + NBUK);   // ACHUNK
    unsigned short* bslot = s2e + ACHUNK;              // ACHUNK
    __shared__ int wsum[4];
    int wg = blockIdx.x, tid = threadIdx.x;
    int base  = wg * ACHUNK;
    int csize = E - base; if (csize > ACHUNK) csize = ACHUNK;

    for (int b = tid; b < NBUK; b += 256) hist[b] = 0;
    __syncthreads();

    int ranks[32];
#pragma unroll
    for (int k = 0; k < 32; ++k) {
        int i = tid + (k << 8);
        if (i < csize) {
            int b = ei[E + base + i] >> 8;
            ranks[k] = atomicAdd(&hist[b], 1);
        }
    }
    __syncthreads();

    // exclusive scan of hist[0..NBUK) -> pref (blocked per-thread + block scan)
    int IT = (NBUK + 255) >> 8;
    int b0 = tid * IT;
    int lsum = 0;
    for (int k = 0; k < IT; ++k) {
        int b = b0 + k;
        if (b < NBUK) lsum += hist[b];
    }
    int lane = tid & 63, wid = tid >> 6;
    int inc = lsum;
#pragma unroll
    for (int off = 1; off < 64; off <<= 1) {
        int t = __shfl_up(inc, off);
        if (lane >= off) inc += t;
    }
    if (lane == 63) wsum[wid] = inc;
    __syncthreads();
    if (tid == 0) {
        int acc = 0;
#pragma unroll
        for (int w = 0; w < 4; ++w) { int t = wsum[w]; wsum[w] = acc; acc += t; }
    }
    __syncthreads();
    int run = wsum[wid] + inc - lsum;
    for (int k = 0; k < IT; ++k) {
        int b = b0 + k;
        if (b < NBUK) { pref[b] = run; run += hist[b]; }
    }
    __syncthreads();

    // place: slot -> edge (inverse map)
#pragma unroll
    for (int k = 0; k < 32; ++k) {
        int i = tid + (k << 8);
        if (i < csize) {
            int b = ei[E + base + i] >> 8;
            int s = pref[b] + ranks[k];
            s2e[s]   = (unsigned short)i;
            bslot[s] = (unsigned short)b;
        }
    }
    __syncthreads();

    // emit in sorted slot order: consecutive threads -> consecutive global pos
    for (int s = tid; s < csize; s += 256) {
        int i  = s2e[s];
        int b  = bslot[s];
        int gi = base + i;
        int gpos = offs[b * nWG + wg] + (s - pref[b]);
        int d  = ei[E + gi];
        uint4 rec = make_edge_rec((unsigned)ei[gi], attr[2 * gi], attr[2 * gi + 1]);
        buf1[gpos] = rec;
        dl1[gpos]  = (unsigned char)(d & 255);
    }
}

// ---------------- Phase B: per-bucket exact-dst sort + rowptr ----------------

__global__ __launch_bounds__(256) void kB_sort(
    const uint4* __restrict__ buf1, const unsigned char* __restrict__ dl1,
    const int* __restrict__ off, int nWG, int NBUK, int N, int E,
    uint4* __restrict__ edges, int* __restrict__ rowptr) {
    __shared__ int hist[256], pref[256], curs[256];
    __shared__ int sbase, ssize;
    int b = blockIdx.x, tid = threadIdx.x;
    if (tid == 0) {
        int s  = off[b * nWG];
        int e2 = (b + 1 < NBUK) ? off[(b + 1) * nWG] : E;
        sbase = s; ssize = e2 - s;
    }
    hist[tid] = 0;
    __syncthreads();
    int base = sbase, size = ssize;
    for (int i = tid; i < size; i += 256) atomicAdd(&hist[dl1[base + i]], 1);
    __syncthreads();
    if (tid == 0) {
        int acc = 0;
        for (int j = 0; j < 256; ++j) { pref[j] = acc; acc += hist[j]; }
    }
    __syncthreads();
    curs[tid] = pref[tid];
    int node = b * 256 + tid;
    if (node < N) rowptr[node] = base + pref[tid];
    if (b == NBUK - 1 && tid == 0) rowptr[N] = E;
    __syncthreads();
    for (int i = tid; i < size; i += 256) {
        int p = atomicAdd(&curs[dl1[base + i]], 1);
        edges[base + p] = buf1[base + i];
    }
}

// ---------------- w2 + root2 pre-pack into B-fragment order (fp16) ----------------

__global__ void k_w2pack(const float* __restrict__ w2, const float* __restrict__ root2,
                         _Float16* __restrict__ w2f) {
    int f = blockIdx.x * blockDim.x + threadIdx.x;
    int stride = gridDim.x * blockDim.x;
    for (; f < 34816; f += stride) {
        int j = f & 7, l = (f >> 3) & 63, t = (f >> 9) & 3;
        int o = t * 16 + (l & 15);
        float v;
        if (f < 32768) {
            int s = f >> 11;
            int p = s * 32 + ((l >> 4) << 3) + j;
            int lane_a = p >> 3, q = p & 7;
            int c = lane_a & 31, kidx = ((lane_a >> 5) << 3) + q;
            v = w2[(kidx * 32 + c) * 64 + o];
        } else {
            int c = ((l >> 4) << 3) + j;
            v = root2[c * 64 + o];
        }
        w2f[f] = (_Float16)v;
    }
}

// ---------------- fc1w pre-pack into B-fragment order (fp16) ----------------

__global__ void k_fcpack(const float* __restrict__ fc1w, _Float16* __restrict__ fc1wf) {
    int f = blockIdx.x * blockDim.x + threadIdx.x;
    if (f >= 8192) return;
    int j = f & 7, l = (f >> 3) & 63, t = (f >> 9) & 7, s = f >> 12;
    int k = s * 32 + ((l >> 4) << 3) + j;
    int o = t * 16 + (l & 15);
    fc1wf[f] = (_Float16)fc1w[k * 128 + o];
}

// ---------------- Layer 1 conv (in=1 -> out=32), thread per node, fp16 out ----------------

__global__ void k_conv1(const float* __restrict__ x, const int* __restrict__ rowptr,
                        const uint4* __restrict__ edges,
                        const float* __restrict__ w1, const float* __restrict__ root1,
                        const float* __restrict__ b1, _Float16* __restrict__ h1h, int N) {
    __shared__ float w1s[16 * 32];
    __shared__ float r1s[32], b1s[32];
    int tid = threadIdx.x;
    for (int i = tid; i < 512; i += blockDim.x) w1s[i] = w1[i];
    if (tid < 32) { r1s[tid] = root1[tid]; b1s[tid] = b1[tid]; }
    __syncthreads();
    int n = blockIdx.x * blockDim.x + tid;
    if (n >= N) return;
    float agg[16] = {};
    int s = rowptr[n], e = rowptr[n + 1];

#define P1(rec, xs) { \
    float bu[4], bv[4]; \
    unpack_basis(rec, bu, bv); \
    float t0 = (xs) * bv[0], t1 = (xs) * bv[1], t2 = (xs) * bv[2], t3 = (xs) * bv[3]; \
    agg[0]  += bu[0] * t0; agg[1]  += bu[1] * t0; agg[2]  += bu[2] * t0; agg[3]  += bu[3] * t0; \
    agg[4]  += bu[0] * t1; agg[5]  += bu[1] * t1; agg[6]  += bu[2] * t1; agg[7]  += bu[3] * t1; \
    agg[8]  += bu[0] * t2; agg[9]  += bu[1] * t2; agg[10] += bu[2] * t2; agg[11] += bu[3] * t2; \
    agg[12] += bu[0] * t3; agg[13] += bu[1] * t3; agg[14] += bu[2] * t3; agg[15] += bu[3] * t3; }

    int j = s;
    for (; j + 3 < e; j += 4) {
        uint4 r0 = edges[j], r1 = edges[j + 1], r2 = edges[j + 2], r3 = edges[j + 3];
        float x0 = x[r0.x], x1 = x[r1.x], x2 = x[r2.x], x3 = x[r3.x];
        P1(r0, x0); P1(r1, x1); P1(r2, x2); P1(r3, x3);
    }
    for (; j < e; ++j) {
        uint4 r = edges[j];
        float xs = x[r.x];
        P1(r, xs);
    }
#undef P1

    float xn = x[n];
    _Float16* hp = h1h + (size_t)n * 32;
#pragma unroll
    for (int o8 = 0; o8 < 4; ++o8) {
        half8 hv;
#pragma unroll
        for (int oo = 0; oo < 8; ++oo) {
            int o = o8 * 8 + oo;
            float acc = b1s[o] + xn * r1s[o];
#pragma unroll
            for (int k = 0; k < 16; ++k) acc += agg[k] * w1s[k * 32 + o];
            hv[oo] = (_Float16)acc;
        }
        *(half8*)(hp + o8 * 8) = hv;
    }
}

// ---------------- BatchNorm (fp16 input stats) ----------------

template <int C>
__global__ void k_bnstath(const _Float16* __restrict__ h, int N, double* __restrict__ sums) {
    __shared__ float sh1[C], sh2[C];
    int tid  = blockIdx.x * blockDim.x + threadIdx.x;
    int c    = tid & (C - 1);
    int row  = tid / C;
    int rstr = (gridDim.x * blockDim.x) / C;
    float s1 = 0.f, s2 = 0.f;
    for (int r = row; r < N; r += rstr) {
        float v = (float)h[(size_t)r * C + c];
        s1 += v; s2 += v * v;
    }
    if (threadIdx.x < C) { sh1[threadIdx.x] = 0.f; sh2[threadIdx.x] = 0.f; }
    __syncthreads();
    atomicAdd(&sh1[c], s1);
    atomicAdd(&sh2[c], s2);
    __syncthreads();
    if (threadIdx.x < C) {
        atomicAdd(&sums[threadIdx.x],     (double)sh1[threadIdx.x]);
        atomicAdd(&sums[C + threadIdx.x], (double)sh2[threadIdx.x]);
    }
}

__global__ void k_bnfinal(const double* __restrict__ sums, const float* __restrict__ gamma,
                          const float* __restrict__ beta, int C, int N, float* __restrict__ scsh) {
    int c = threadIdx.x;
    if (c < C) {
        double m   = sums[c] / (double)N;
        double var = sums[C + c] / (double)N - m * m;
        float vpe  = (float)var + 1e-5f;
        float sc   = gamma[c] / sqrtf(vpe);
        scsh[c]     = sc;
        scsh[C + c] = beta[c] - (float)m * sc;
    }
}

// BN + ELU for h1h (C=32), in place fp16
__global__ void k_bnelu32h(_Float16* __restrict__ hh, int N, const float* __restrict__ scsh) {
    int total = N * 4;   // groups of 8 halves
    int i = blockIdx.x * blockDim.x + threadIdx.x;
    int stride = gridDim.x * blockDim.x;
    for (; i < total; i += stride) {
        half8 v = *(half8*)(hh + (size_t)i * 8);
        int c0 = (i * 8) & 31;
        half8 r;
#pragma unroll
        for (int j = 0; j < 8; ++j)
            r[j] = (_Float16)eluf((float)v[j] * scsh[c0 + j] + scsh[32 + c0 + j]);
        *(half8*)(hh + (size_t)i * 8) = r;
    }
}

// ---------------- Layer 2: aggregation, 2 edges per wave-iter, 4 in flight ----------------

__global__ __launch_bounds__(512) void k_agg(
    const _Float16* __restrict__ h1h, const int* __restrict__ rowptr,
    const uint4* __restrict__ edges, _Float16* __restrict__ agg,
    int n0, int n1) {
    int tid   = threadIdx.x;
    int lane  = tid & 63;
    int w     = tid >> 6;
    int c     = lane & 31;
    int khalf = lane >> 5;
    int n = n0 + blockIdx.x * 8 + w;
    if (n >= n1) return;
    float a[16] = {};
    int s = __builtin_amdgcn_readfirstlane(rowptr[n]);
    int e = __builtin_amdgcn_readfirstlane(rowptr[n + 1]);

#define P16(rec, hc) { \
    float bu[4], bv[4]; \
    unpack_basis(rec, bu, bv); \
    float t0 = (hc) * bv[0], t1 = (hc) * bv[1], t2 = (hc) * bv[2], t3 = (hc) * bv[3]; \
    a[0]  += bu[0] * t0; a[1]  += bu[1] * t0; a[2]  += bu[2] * t0; a[3]  += bu[3] * t0; \
    a[4]  += bu[0] * t1; a[5]  += bu[1] * t1; a[6]  += bu[2] * t1; a[7]  += bu[3] * t1; \
    a[8]  += bu[0] * t2; a[9]  += bu[1] * t2; a[10] += bu[2] * t2; a[11] += bu[3] * t2; \
    a[12] += bu[0] * t3; a[13] += bu[1] * t3; a[14] += bu[2] * t3; a[15] += bu[3] * t3; }

    int j = s;
    for (; j + 3 < e; j += 4) {
        uint4 rA = edges[j + khalf];
        uint4 rB = edges[j + 2 + khalf];
        float hA = (float)h1h[(size_t)rA.x * 32 + c];
        float hB = (float)h1h[(size_t)rB.x * 32 + c];
        P16(rA, hA);
        P16(rB, hB);
    }
    for (; j < e; j += 2) {
        int jj = j + khalf;
        bool act = jj < e;
        uint4 r = edges[act ? jj : (e - 1)];
        float hc = act ? (float)h1h[(size_t)r.x * 32 + c] : 0.f;
        P16(r, hc);
    }
#undef P16

    half8 hv;
#pragma unroll
    for (int q = 0; q < 8; ++q) {
        float lo = a[q]     + __shfl_xor(a[q], 32);
        float hi = a[8 + q] + __shfl_xor(a[8 + q], 32);
        hv[q] = (_Float16)(khalf ? hi : lo);
    }
    *(half8*)(agg + (size_t)(n - n0) * 512 + lane * 8) = hv;
}

// ---------------- Layer 2: MFMA GEMM  out2h = [agg|h1h] @ w2f + b2 (fp16 out) ----------------

__global__ __launch_bounds__(256) void k_gemm2(
    const _Float16* __restrict__ agg, const _Float16* __restrict__ h1h,
    const _Float16* __restrict__ w2f, const float* __restrict__ b2,
    _Float16* __restrict__ out2h, int n0, int n1, int ntiles) {
    extern __shared__ _Float16 w2s[];
    int tid = threadIdx.x;
    {
        const uint4* s4 = (const uint4*)w2f;
        uint4* d4 = (uint4*)w2s;
        for (int i = tid; i < 4352; i += 256) d4[i] = s4[i];   // 69632 B
    }
    __syncthreads();
    const half8* bp = (const half8*)w2s;
    int l   = tid & 63, w = tid >> 6;
    int klo = (l >> 4) << 3;
    int m   = l & 15;
    float bv0 = b2[m], bv1 = b2[16 + m], bv2 = b2[32 + m], bv3 = b2[48 + m];
    for (int tile = blockIdx.x; tile < ntiles; tile += gridDim.x) {
        int wavebase = n0 + tile * 64 + w * 16;
        if (wavebase >= n1) continue;
        int arow = wavebase + m; if (arow > n1 - 1) arow = n1 - 1;
        const half8* ap = (const half8*)(agg + (size_t)(arow - n0) * 512 + klo);
        f32x4 acc0 = {0.f,0.f,0.f,0.f}, acc1 = acc0, acc2 = acc0, acc3 = acc0;
#pragma unroll
        for (int s = 0; s < 16; ++s) {
            half8 a = ap[s * 4];
            int bi = (s << 8) + l;
            acc0 = __builtin_amdgcn_mfma_f32_16x16x32_f16(a, bp[bi      ], acc0, 0, 0, 0);
            acc1 = __builtin_amdgcn_mfma_f32_16x16x32_f16(a, bp[bi +  64], acc1, 0, 0, 0);
            acc2 = __builtin_amdgcn_mfma_f32_16x16x32_f16(a, bp[bi + 128], acc2, 0, 0, 0);
            acc3 = __builtin_amdgcn_mfma_f32_16x16x32_f16(a, bp[bi + 192], acc3, 0, 0, 0);
        }
        {
            half8 a = *(const half8*)(h1h + (size_t)arow * 32 + klo);
            int bi = (16 << 8) + l;
            acc0 = __builtin_amdgcn_mfma_f32_16x16x32_f16(a, bp[bi      ], acc0, 0, 0, 0);
            acc1 = __builtin_amdgcn_mfma_f32_16x16x32_f16(a, bp[bi +  64], acc1, 0, 0, 0);
            acc2 = __builtin_amdgcn_mfma_f32_16x16x32_f16(a, bp[bi + 128], acc2, 0, 0, 0);
            acc3 = __builtin_amdgcn_mfma_f32_16x16x32_f16(a, bp[bi + 192], acc3, 0, 0, 0);
        }
        int rbase = wavebase + ((l >> 4) << 2);
#pragma unroll
        for (int r = 0; r < 4; ++r) {
            int node = rbase + r;
            if (node < n1) {
                size_t o = (size_t)node * 64;
                out2h[o + m]      = (_Float16)(acc0[r] + bv0);
                out2h[o + 16 + m] = (_Float16)(acc1[r] + bv1);
                out2h[o + 32 + m] = (_Float16)(acc2[r] + bv2);
                out2h[o + 48 + m] = (_Float16)(acc3[r] + bv3);
            }
        }
    }
}

// ---------------- Final MLP via MFMA: elu(bn(out2h)) @ fc1w -> elu -> @ fc2w ----------------

__global__ __launch_bounds__(256) void k_fcm(
    const _Float16* __restrict__ out2h, const _Float16* __restrict__ fc1wf,
    const float* __restrict__ scsh, const float* __restrict__ fc1b,
    const float* __restrict__ fc2w, const float* __restrict__ fc2b,
    float* __restrict__ out, int N, int ntiles) {
    __shared__ _Float16 fw[8192];
    __shared__ float scs[64], shs[64], b1s[128], w2sv[128];
    int tid = threadIdx.x;
    {
        const uint4* s4 = (const uint4*)fc1wf;
        uint4* d4 = (uint4*)fw;
        for (int i = tid; i < 1024; i += 256) d4[i] = s4[i];
    }
    if (tid < 128) { b1s[tid] = fc1b[tid]; w2sv[tid] = fc2w[tid]; }
    if (tid < 64)  { scs[tid] = scsh[tid]; shs[tid] = scsh[64 + tid]; }
    __syncthreads();
    const half8* bp = (const half8*)fw;
    int l = tid & 63, w = tid >> 6;
    int g = l >> 4, m = l & 15, klo = g * 8;
    float f2b = fc2b[0];
    for (int tile = blockIdx.x * 4 + w; tile < ntiles; tile += gridDim.x * 4) {
        int base = tile * 16;
        int arow = base + m; if (arow > N - 1) arow = N - 1;
        const half8* hp = (const half8*)(out2h + (size_t)arow * 64 + klo);
        half8 r0 = hp[0];   // k = klo + j
        half8 r1 = hp[4];   // k = 32 + klo + j
        half8 a0, a1;
#pragma unroll
        for (int j = 0; j < 8; ++j) {
            int c0 = klo + j, c1 = 32 + klo + j;
            a0[j] = (_Float16)eluf((float)r0[j] * scs[c0] + shs[c0]);
            a1[j] = (_Float16)eluf((float)r1[j] * scs[c1] + shs[c1]);
        }
        f32x4 acc[8];
#pragma unroll
        for (int t = 0; t < 8; ++t) {
            f32x4 z = {0.f, 0.f, 0.f, 0.f};
            acc[t] = __builtin_amdgcn_mfma_f32_16x16x32_f16(a0, bp[t * 64 + l], z, 0, 0, 0);
            acc[t] = __builtin_amdgcn_mfma_f32_16x16x32_f16(a1, bp[(8 + t) * 64 + l], acc[t], 0, 0, 0);
        }
#pragma unroll
        for (int r = 0; r < 4; ++r) {
            float sum = 0.f;
#pragma unroll
            for (int t = 0; t < 8; ++t) {
                int o = t * 16 + m;
                sum += eluf(acc[t][r] + b1s[o]) * w2sv[o];
            }
            sum += __shfl_xor(sum, 1);
            sum += __shfl_xor(sum, 2);
            sum += __shfl_xor(sum, 4);
            sum += __shfl_xor(sum, 8);
            int node = base + g * 4 + r;
            if (m == 0 && node < N) out[node] = sum + f2b;
        }
    }
}

// ---------------------------------------------------------------------------

extern "C" void kernel_launch(void* const* d_in, const int* in_sizes, int n_in,
                              void* d_out, int out_size, void* d_ws, size_t ws_size,
                              hipStream_t stream) {
    const float* x     = (const float*)d_in[0];
    const int*   ei    = (const int*)  d_in[1];
    const float* attr  = (const float*)d_in[2];
    const float* w1    = (const float*)d_in[3];
    const float* root1 = (const float*)d_in[4];
    const float* b1    = (const float*)d_in[5];
    const float* g1    = (const float*)d_in[6];
    const float* be1   = (const float*)d_in[7];
    const float* w2    = (const float*)d_in[8];
    const float* root2 = (const float*)d_in[9];
    const float* b2    = (const float*)d_in[10];
    const float* g2    = (const float*)d_in[11];
    const float* be2   = (const float*)d_in[12];
    const float* fc1w  = (const float*)d_in[13];
    const float* fc1b  = (const float*)d_in[14];
    const float* fc2w  = (const float*)d_in[15];
    const float* fc2b  = (const float*)d_in[16];
    float* out = (float*)d_out;

    int N = in_sizes[0];          // 150000
    int E = in_sizes[1] / 2;      // 3000000

    int nWG  = (E + ACHUNK - 1) / ACHUNK;   // 367
    int NBUK = (N + 255) >> 8;              // 586
    int M    = NBUK * nWG;                  // ~215k

    char* ws = (char*)d_ws;
    size_t off = 0;
    auto alloc = [&](size_t bytes) -> void* {
        void* p = ws + off;
        off = (off + bytes + 255) & ~(size_t)255;
        return p;
    };
    int*      rowptr    = (int*)     alloc((size_t)(N + 1) * 4);
    int*      blockSums = (int*)     alloc(1024 * 4);
    int*      blockOff  = (int*)     alloc(1024 * 4);
    double*   bnsum1    = (double*)  alloc(128 * 8);
    double*   bnsum2    = (double*)  alloc(128 * 8);
    float*    scsh1     = (float*)   alloc(64 * 4);
    float*    scsh2     = (float*)   alloc(128 * 4);
    _Float16* w2f       = (_Float16*)alloc(34816 * 2);
    _Float16* fc1wf     = (_Float16*)alloc(8192 * 2);
    int*      cnt       = (int*)     alloc((size_t)M * 4);
    int*      offs      = (int*)     alloc((size_t)M * 4);
    uint4*    edges     = (uint4*)   alloc((size_t)E * 16);
    size_t    Roff      = off;              // start of aliasable region
    _Float16* h1h       = (_Float16*)alloc((size_t)N * 32 * 2);   //  9.6 MB
    _Float16* out2h     = (_Float16*)alloc((size_t)N * 64 * 2);   // 19.2 MB
    // buf1 + dl1 alias [h1h|out2h|aggbuf...] (51 MB); dead before conv1 runs
    uint4*         buf1 = (uint4*)(ws + Roff);
    unsigned char* dl1  = (unsigned char*)(ws + Roff + (size_t)E * 16);
    // agg buffer takes the remainder (512 fp16 = 1024 B/node)
    size_t avail = (ws_size > off) ? (ws_size - off) : 0;
    int NC = (int)(avail / 1024);
    if (NC > N) NC = N;
    NC &= ~255;
    if (NC < 256) NC = 256;
    _Float16* aggbuf = (_Float16*)alloc((size_t)NC * 1024);
    (void)n_in; (void)out_size;

    hipMemsetAsync(bnsum1, 0, 128 * 8, stream);
    hipMemsetAsync(bnsum2, 0, 128 * 8, stream);

    size_t ldsA1 = (size_t)NBUK * 4;
    size_t ldsA2 = (size_t)NBUK * 8 + (size_t)ACHUNK * 4;   // hist+pref+s2e+bslot
    int NBs = (M + 1023) / 1024;            // ~211 <= 256

    k_w2pack<<<136, 256, 0, stream>>>(w2, root2, w2f);
    k_fcpack<<<32, 256, 0, stream>>>(fc1w, fc1wf);
    kA1_hist<<<nWG, 256, ldsA1, stream>>>(ei + E, E, cnt, nWG, NBUK);
    k_scan1<<<NBs, 256, 0, stream>>>(cnt, M, offs, blockSums);
    k_scan2<<<1, 256, 0, stream>>>(blockSums, NBs, blockOff);
    k_scan3b<<<(M + 255) / 256, 256, 0, stream>>>(offs, blockOff, M);
    kA2_fill<<<nWG, 256, ldsA2, stream>>>(ei, attr, E, offs, nWG, NBUK, buf1, dl1);
    kB_sort<<<NBUK, 256, 0, stream>>>(buf1, dl1, offs, nWG, NBUK, N, E, edges, rowptr);

    k_conv1<<<(N + 255) / 256, 256, 0, stream>>>(x, rowptr, edges, w1, root1, b1, h1h, N);
    k_bnstath<32><<<256, 256, 0, stream>>>(h1h, N, bnsum1);
    k_bnfinal<<<1, 64, 0, stream>>>(bnsum1, g1, be1, 32, N, scsh1);
    k_bnelu32h<<<1024, 256, 0, stream>>>(h1h, N, scsh1);

    for (int c0 = 0; c0 < N; c0 += NC) {
        int c1 = c0 + NC; if (c1 > N) c1 = N;
        int cnt2 = c1 - c0;
        k_agg<<<(cnt2 + 7) / 8, 512, 0, stream>>>(h1h, rowptr, edges, aggbuf, c0, c1);
        int ntiles = (cnt2 + 63) / 64;
        int grid = ntiles < 1184 ? ntiles : 1184;
        k_gemm2<<<grid, 256, 69632, stream>>>(aggbuf, h1h, w2f, b2, out2h, c0, c1, ntiles);
    }

    k_bnstath<64><<<256, 256, 0, stream>>>(out2h, N, bnsum2);
    k_bnfinal<<<1, 64, 0, stream>>>(bnsum2, g2, be2, 64, N, scsh2);

    int ntilesF = (N + 15) / 16;
    int gridF = (ntilesF + 3) / 4; if (gridF > 2344) gridF = 2344;
    k_fcm<<<gridF, 256, 0, stream>>>(out2h, fc1wf, scsh2, fc1b, fc2w, fc2b, out, N, ntilesF);
}

// Round 9
// 378.190 us; speedup vs baseline: 4.7646x; 1.3190x over previous
//
#include <hip/hip_runtime.h>
#include <hip/hip_fp16.h>
#include <math.h>

// ---------------------------------------------------------------------------
// SplineCNN (K=4, dim=2, deg=2). v9: fused MFMA aggregation+GEMM for conv2
// (k_ag2): basis outer-product on matrix cores, agg kept in LDS, no global
// agg round-trip. Partition CSR build + MFMA final MLP as in v8.
// ---------------------------------------------------------------------------

typedef _Float16 half8 __attribute__((ext_vector_type(8)));
typedef _Float16 half4 __attribute__((ext_vector_type(4)));
typedef float    f32x4 __attribute__((ext_vector_type(4)));
typedef int      iv4   __attribute__((ext_vector_type(4)));

#define ACHUNK 8192   // edges per partition WG (32 per thread)

__device__ __forceinline__ void bspline4(float a, float B[4]) {
    a = fminf(fmaxf(a, 0.f), 1.f);
    float v  = a * 2.0f;          // K - DEG = 2
    float kv = floorf(v);
    float t  = v - kv;
    int   ik = (int)kv;           // 0..2
    float b0 = 0.5f * (1.f - t) * (1.f - t);
    float b1 = (t - t * t) + 0.5f;
    float b2 = 0.5f * t * t;
    int c0 = ik;
    int c1 = ik + 1;
    int c2 = ik + 2; if (c2 > 3) c2 = 3;
#pragma unroll
    for (int j = 0; j < 4; ++j)
        B[j] = (c0 == j ? b0 : 0.f) + (c1 == j ? b1 : 0.f) + (c2 == j ? b2 : 0.f);
}

__device__ __forceinline__ float eluf(float x) {
    return x > 0.f ? x : expm1f(x);
}

__device__ __forceinline__ void unpack_basis(uint4 rec, float bu[4], float bv[4]) {
    float2 f01 = __half22float2(*(const __half2*)&rec.y);
    float2 f23 = __half22float2(*(const __half2*)&rec.z);
    float2 f45 = __half22float2(*(const __half2*)&rec.w);
    bu[0] = f01.x; bu[1] = f01.y; bu[2] = f23.x;
    bu[3] = 1.f - (bu[0] + bu[1] + bu[2]);
    bv[0] = f23.y; bv[1] = f45.x; bv[2] = f45.y;
    bv[3] = 1.f - (bv[0] + bv[1] + bv[2]);
}

__device__ __forceinline__ uint4 make_edge_rec(unsigned src, float u, float v) {
    float Bu[4], Bv[4];
    bspline4(u, Bu);
    bspline4(v, Bv);
    __half2 p01 = __floats2half2_rn(Bu[0], Bu[1]);
    __half2 p23 = __floats2half2_rn(Bu[2], Bv[0]);
    __half2 p45 = __floats2half2_rn(Bv[1], Bv[2]);
    uint4 rec;
    rec.x = src;
    rec.y = *(const unsigned*)&p01;
    rec.z = *(const unsigned*)&p23;
    rec.w = *(const unsigned*)&p45;
    return rec;
}

// ---------------- Phase A: bucketed partition (bucket = dst >> 8) ----------------

__global__ void kA1_hist(const int* __restrict__ dst, int E, int* __restrict__ cnt,
                         int nWG, int NBUK) {
    extern __shared__ int hist[];   // NBUK ints
    int wg = blockIdx.x, tid = threadIdx.x;
    for (int b = tid; b < NBUK; b += 256) hist[b] = 0;
    __syncthreads();
    int base = wg * ACHUNK;
    int end  = base + ACHUNK; if (end > E) end = E;
    for (int i = base + tid; i < end; i += 256)
        atomicAdd(&hist[dst[i] >> 8], 1);
    __syncthreads();
    for (int b = tid; b < NBUK; b += 256) cnt[b * nWG + wg] = hist[b];
}

__global__ void k_scan1(const int* __restrict__ in, int M,
                        int* __restrict__ outp, int* __restrict__ blockSums) {
    __shared__ int wsum[4];
    int tid  = threadIdx.x;
    int base = blockIdx.x * 1024 + tid * 4;
    int d0 = (base + 0) < M ? in[base + 0] : 0;
    int d1 = (base + 1) < M ? in[base + 1] : 0;
    int d2 = (base + 2) < M ? in[base + 2] : 0;
    int d3 = (base + 3) < M ? in[base + 3] : 0;
    int s4 = d0 + d1 + d2 + d3;
    int lane = tid & 63, wid = tid >> 6;
    int inc = s4;
#pragma unroll
    for (int off = 1; off < 64; off <<= 1) {
        int t = __shfl_up(inc, off);
        if (lane >= off) inc += t;
    }
    if (lane == 63) wsum[wid] = inc;
    __syncthreads();
    if (tid == 0) {
        int acc = 0;
#pragma unroll
        for (int w = 0; w < 4; ++w) { int t = wsum[w]; wsum[w] = acc; acc += t; }
    }
    __syncthreads();
    int ebase = wsum[wid] + inc - s4;
    if ((base + 0) < M) outp[base + 0] = ebase;
    if ((base + 1) < M) outp[base + 1] = ebase + d0;
    if ((base + 2) < M) outp[base + 2] = ebase + d0 + d1;
    if ((base + 3) < M) outp[base + 3] = ebase + d0 + d1 + d2;
    if (tid == 255) blockSums[blockIdx.x] = ebase + s4;
}

__global__ void k_scan2(const int* __restrict__ blockSums, int NB, int* __restrict__ blockOff) {
    __shared__ int sh[256];
    int tid = threadIdx.x;
    int own = (tid < NB) ? blockSums[tid] : 0;
    sh[tid] = own;
    __syncthreads();
    for (int off = 1; off < 256; off <<= 1) {
        int v = (tid >= off) ? sh[tid - off] : 0;
        __syncthreads();
        sh[tid] += v;
        __syncthreads();
    }
    if (tid < NB) blockOff[tid] = sh[tid] - own;
}

__global__ void k_scan3b(int* __restrict__ arr, const int* __restrict__ blockOff, int M) {
    int i = blockIdx.x * blockDim.x + threadIdx.x;
    if (i < M) arr[i] += blockOff[i >> 10];
}

// fill pass: LDS counting sort by bucket, emit slots in order (coalesced)
__global__ __launch_bounds__(256) void kA2_fill(
    const int* __restrict__ ei, const float* __restrict__ attr, int E,
    const int* __restrict__ offs, int nWG, int NBUK,
    uint4* __restrict__ buf1, unsigned char* __restrict__ dl1) {
    extern __shared__ int lds[];
    int*            hist  = lds;                       // NBUK
    int*            pref  = hist + NBUK;               // NBUK
    unsigned short* s2e   = (unsigned short*)(pref + NBUK);   // ACHUNK
    unsigned short* bslot = s2e + ACHUNK;              // ACHUNK
    __shared__ int wsum[4];
    int wg = blockIdx.x, tid = threadIdx.x;
    int base  = wg * ACHUNK;
    int csize = E - base; if (csize > ACHUNK) csize = ACHUNK;

    for (int b = tid; b < NBUK; b += 256) hist[b] = 0;
    __syncthreads();

    int ranks[32];
#pragma unroll
    for (int k = 0; k < 32; ++k) {
        int i = tid + (k << 8);
        if (i < csize) {
            int b = ei[E + base + i] >> 8;
            ranks[k] = atomicAdd(&hist[b], 1);
        }
    }
    __syncthreads();

    int IT = (NBUK + 255) >> 8;
    int b0 = tid * IT;
    int lsum = 0;
    for (int k = 0; k < IT; ++k) {
        int b = b0 + k;
        if (b < NBUK) lsum += hist[b];
    }
    int lane = tid & 63, wid = tid >> 6;
    int inc = lsum;
#pragma unroll
    for (int off = 1; off < 64; off <<= 1) {
        int t = __shfl_up(inc, off);
        if (lane >= off) inc += t;
    }
    if (lane == 63) wsum[wid] = inc;
    __syncthreads();
    if (tid == 0) {
        int acc = 0;
#pragma unroll
        for (int w = 0; w < 4; ++w) { int t = wsum[w]; wsum[w] = acc; acc += t; }
    }
    __syncthreads();
    int run = wsum[wid] + inc - lsum;
    for (int k = 0; k < IT; ++k) {
        int b = b0 + k;
        if (b < NBUK) { pref[b] = run; run += hist[b]; }
    }
    __syncthreads();

#pragma unroll
    for (int k = 0; k < 32; ++k) {
        int i = tid + (k << 8);
        if (i < csize) {
            int b = ei[E + base + i] >> 8;
            int s = pref[b] + ranks[k];
            s2e[s]   = (unsigned short)i;
            bslot[s] = (unsigned short)b;
        }
    }
    __syncthreads();

    for (int s = tid; s < csize; s += 256) {
        int i  = s2e[s];
        int b  = bslot[s];
        int gi = base + i;
        int gpos = offs[b * nWG + wg] + (s - pref[b]);
        int d  = ei[E + gi];
        uint4 rec = make_edge_rec((unsigned)ei[gi], attr[2 * gi], attr[2 * gi + 1]);
        buf1[gpos] = rec;
        dl1[gpos]  = (unsigned char)(d & 255);
    }
}

// ---------------- Phase B: per-bucket exact-dst sort + rowptr ----------------

__global__ __launch_bounds__(256) void kB_sort(
    const uint4* __restrict__ buf1, const unsigned char* __restrict__ dl1,
    const int* __restrict__ off, int nWG, int NBUK, int N, int E,
    uint4* __restrict__ edges, int* __restrict__ rowptr) {
    __shared__ int hist[256], pref[256], curs[256];
    __shared__ int sbase, ssize;
    int b = blockIdx.x, tid = threadIdx.x;
    if (tid == 0) {
        int s  = off[b * nWG];
        int e2 = (b + 1 < NBUK) ? off[(b + 1) * nWG] : E;
        sbase = s; ssize = e2 - s;
    }
    hist[tid] = 0;
    __syncthreads();
    int base = sbase, size = ssize;
    for (int i = tid; i < size; i += 256) atomicAdd(&hist[dl1[base + i]], 1);
    __syncthreads();
    if (tid == 0) {
        int acc = 0;
        for (int j = 0; j < 256; ++j) { pref[j] = acc; acc += hist[j]; }
    }
    __syncthreads();
    curs[tid] = pref[tid];
    int node = b * 256 + tid;
    if (node < N) rowptr[node] = base + pref[tid];
    if (b == NBUK - 1 && tid == 0) rowptr[N] = E;
    __syncthreads();
    for (int i = tid; i < size; i += 256) {
        int p = atomicAdd(&curs[dl1[base + i]], 1);
        edges[base + p] = buf1[base + i];
    }
}

// ---------------- w2 + root2 pre-pack into B-fragment order (fp16) ----------------
// agg k-position p = ch*16 + k  (ch in [0,32), k = ku+4kv in [0,16)).
// slot f = ((s*4 + t)*64 + l)*8 + j ; within-step k-pos = (l>>4)*8 + j.

__global__ void k_w2pack(const float* __restrict__ w2, const float* __restrict__ root2,
                         _Float16* __restrict__ w2f) {
    int f = blockIdx.x * blockDim.x + threadIdx.x;
    int stride = gridDim.x * blockDim.x;
    for (; f < 34816; f += stride) {
        int j = f & 7, l = (f >> 3) & 63, t = (f >> 9) & 3;
        int o = t * 16 + (l & 15);
        float v;
        if (f < 32768) {
            int s = f >> 11;                         // K-step 0..15
            int p = s * 32 + ((l >> 4) << 3) + j;    // global p 0..511
            int ch = p >> 4, k = p & 15;
            v = w2[(k * 32 + ch) * 64 + o];
        } else {
            int ci = ((l >> 4) << 3) + j;
            v = root2[ci * 64 + o];
        }
        w2f[f] = (_Float16)v;
    }
}

// ---------------- fc1w pre-pack into B-fragment order (fp16) ----------------

__global__ void k_fcpack(const float* __restrict__ fc1w, _Float16* __restrict__ fc1wf) {
    int f = blockIdx.x * blockDim.x + threadIdx.x;
    if (f >= 8192) return;
    int j = f & 7, l = (f >> 3) & 63, t = (f >> 9) & 7, s = f >> 12;
    int k = s * 32 + ((l >> 4) << 3) + j;
    int o = t * 16 + (l & 15);
    fc1wf[f] = (_Float16)fc1w[k * 128 + o];
}

// ---------------- Layer 1 conv (in=1 -> out=32), thread per node, fp16 out ----------------

__global__ void k_conv1(const float* __restrict__ x, const int* __restrict__ rowptr,
                        const uint4* __restrict__ edges,
                        const float* __restrict__ w1, const float* __restrict__ root1,
                        const float* __restrict__ b1, _Float16* __restrict__ h1h, int N) {
    __shared__ float w1s[16 * 32];
    __shared__ float r1s[32], b1s[32];
    int tid = threadIdx.x;
    for (int i = tid; i < 512; i += blockDim.x) w1s[i] = w1[i];
    if (tid < 32) { r1s[tid] = root1[tid]; b1s[tid] = b1[tid]; }
    __syncthreads();
    int n = blockIdx.x * blockDim.x + tid;
    if (n >= N) return;
    float agg[16] = {};
    int s = rowptr[n], e = rowptr[n + 1];

#define P1(rec, xs) { \
    float bu[4], bv[4]; \
    unpack_basis(rec, bu, bv); \
    float t0 = (xs) * bv[0], t1 = (xs) * bv[1], t2 = (xs) * bv[2], t3 = (xs) * bv[3]; \
    agg[0]  += bu[0] * t0; agg[1]  += bu[1] * t0; agg[2]  += bu[2] * t0; agg[3]  += bu[3] * t0; \
    agg[4]  += bu[0] * t1; agg[5]  += bu[1] * t1; agg[6]  += bu[2] * t1; agg[7]  += bu[3] * t1; \
    agg[8]  += bu[0] * t2; agg[9]  += bu[1] * t2; agg[10] += bu[2] * t2; agg[11] += bu[3] * t2; \
    agg[12] += bu[0] * t3; agg[13] += bu[1] * t3; agg[14] += bu[2] * t3; agg[15] += bu[3] * t3; }

    int j = s;
    for (; j + 3 < e; j += 4) {
        uint4 r0 = edges[j], r1 = edges[j + 1], r2 = edges[j + 2], r3 = edges[j + 3];
        float x0 = x[r0.x], x1 = x[r1.x], x2 = x[r2.x], x3 = x[r3.x];
        P1(r0, x0); P1(r1, x1); P1(r2, x2); P1(r3, x3);
    }
    for (; j < e; ++j) {
        uint4 r = edges[j];
        float xs = x[r.x];
        P1(r, xs);
    }
#undef P1

    float xn = x[n];
    _Float16* hp = h1h + (size_t)n * 32;
#pragma unroll
    for (int o8 = 0; o8 < 4; ++o8) {
        half8 hv;
#pragma unroll
        for (int oo = 0; oo < 8; ++oo) {
            int o = o8 * 8 + oo;
            float acc = b1s[o] + xn * r1s[o];
#pragma unroll
            for (int k = 0; k < 16; ++k) acc += agg[k] * w1s[k * 32 + o];
            hv[oo] = (_Float16)acc;
        }
        *(half8*)(hp + o8 * 8) = hv;
    }
}

// ---------------- BatchNorm (fp16 input stats) ----------------

template <int C>
__global__ void k_bnstath(const _Float16* __restrict__ h, int N, double* __restrict__ sums) {
    __shared__ float sh1[C], sh2[C];
    int tid  = blockIdx.x * blockDim.x + threadIdx.x;
    int c    = tid & (C - 1);
    int row  = tid / C;
    int rstr = (gridDim.x * blockDim.x) / C;
    float s1 = 0.f, s2 = 0.f;
    for (int r = row; r < N; r += rstr) {
        float v = (float)h[(size_t)r * C + c];
        s1 += v; s2 += v * v;
    }
    if (threadIdx.x < C) { sh1[threadIdx.x] = 0.f; sh2[threadIdx.x] = 0.f; }
    __syncthreads();
    atomicAdd(&sh1[c], s1);
    atomicAdd(&sh2[c], s2);
    __syncthreads();
    if (threadIdx.x < C) {
        atomicAdd(&sums[threadIdx.x],     (double)sh1[threadIdx.x]);
        atomicAdd(&sums[C + threadIdx.x], (double)sh2[threadIdx.x]);
    }
}

__global__ void k_bnfinal(const double* __restrict__ sums, const float* __restrict__ gamma,
                          const float* __restrict__ beta, int C, int N, float* __restrict__ scsh) {
    int c = threadIdx.x;
    if (c < C) {
        double m   = sums[c] / (double)N;
        double var = sums[C + c] / (double)N - m * m;
        float vpe  = (float)var + 1e-5f;
        float sc   = gamma[c] / sqrtf(vpe);
        scsh[c]     = sc;
        scsh[C + c] = beta[c] - (float)m * sc;
    }
}

// BN + ELU for h1h (C=32), in place fp16
__global__ void k_bnelu32h(_Float16* __restrict__ hh, int N, const float* __restrict__ scsh) {
    int total = N * 4;
    int i = blockIdx.x * blockDim.x + threadIdx.x;
    int stride = gridDim.x * blockDim.x;
    for (; i < total; i += stride) {
        half8 v = *(half8*)(hh + (size_t)i * 8);
        int c0 = (i * 8) & 31;
        half8 r;
#pragma unroll
        for (int j = 0; j < 8; ++j)
            r[j] = (_Float16)eluf((float)v[j] * scsh[c0 + j] + scsh[32 + c0 + j]);
        *(half8*)(hh + (size_t)i * 8) = r;
    }
}

// ---------------- Layer 2 fused: MFMA aggregation + GEMM (k_ag2) ----------------
// Block: 256 thr = 4 waves, 16 nodes. Phase 1: wave w aggregates nodes
// w*4+q via mfma(basis[16k x 32e], hgather[32e x 16ch]) -> agg LDS tile.
// Phase 2: wave w computes col-tile w of [16n x 544] @ w2f + b2.

__global__ __launch_bounds__(256) void k_ag2(
    const _Float16* __restrict__ h1h, const int* __restrict__ rowptr,
    const uint4* __restrict__ edges, const _Float16* __restrict__ w2f,
    const float* __restrict__ b2, _Float16* __restrict__ out2h, int N) {
    __shared__ __align__(16) _Float16 aggL[16][520];    // p = ch*16+k, pad to 520
    __shared__ __align__(16) _Float16 basisL[4][16][72]; // [wave][k][edge(+pad)]
    __shared__ __align__(16) int      srcL[4][64];
    int tid = threadIdx.x, l = tid & 63, w = tid >> 6;
    int g = l >> 4, m = l & 15;
    int n0 = blockIdx.x * 16;

    // ---- phase 1: aggregation ----
    for (int q = 0; q < 4; ++q) {
        int row = w * 4 + q;
        int n = n0 + row;
        if (n < N) {
            int s = __builtin_amdgcn_readfirstlane(rowptr[n]);
            int e = __builtin_amdgcn_readfirstlane(rowptr[n + 1]);
            f32x4 C0 = {0.f, 0.f, 0.f, 0.f}, C1 = C0;
            for (int t = s; t < e; t += 64) {
                int eg = t + l;
                bool act = eg < e;
                uint4 rec = edges[act ? eg : e - 1];
                srcL[w][l] = act ? (int)rec.x : 0;
                float bu[4], bv[4];
                unpack_basis(rec, bu, bv);
#pragma unroll
                for (int kv = 0; kv < 4; ++kv)
#pragma unroll
                    for (int ku = 0; ku < 4; ++ku)
                        basisL[w][kv * 4 + ku][l] = (_Float16)(bu[ku] * bv[kv]);
                int rem = e - t;
#pragma unroll
                for (int kh = 0; kh < 2; ++kh) {
                    if (kh == 1 && rem <= 32) break;
                    int ebase = kh * 32 + g * 8;
                    half8 a = *(const half8*)&basisL[w][m][ebase];
                    iv4 sA = *(const iv4*)&srcL[w][ebase];
                    iv4 sB = *(const iv4*)&srcL[w][ebase + 4];
                    half8 b0, b1;
#pragma unroll
                    for (int j = 0; j < 8; ++j) {
                        int sj = (j < 4) ? sA[j] : sB[j - 4];
                        bool aj = (t + ebase + j) < e;
                        _Float16 v0 = h1h[(size_t)sj * 32 + m];
                        _Float16 v1 = h1h[(size_t)sj * 32 + 16 + m];
                        b0[j] = aj ? v0 : (_Float16)0.f;
                        b1[j] = aj ? v1 : (_Float16)0.f;
                    }
                    C0 = __builtin_amdgcn_mfma_f32_16x16x32_f16(a, b0, C0, 0, 0, 0);
                    C1 = __builtin_amdgcn_mfma_f32_16x16x32_f16(a, b1, C1, 0, 0, 0);
                }
            }
            // write C tiles: D[row=k=(g*4+r)][col=ch=m (C0) / 16+m (C1)]
            half4 c0, c1;
#pragma unroll
            for (int r = 0; r < 4; ++r) { c0[r] = (_Float16)C0[r]; c1[r] = (_Float16)C1[r]; }
            *(half4*)&aggL[row][m * 16 + g * 4]        = c0;   // p = ch*16 + k
            *(half4*)&aggL[row][(16 + m) * 16 + g * 4] = c1;
        }
    }
    __syncthreads();

    // ---- phase 2: [16 nodes x 544] @ w2f -> out2h ----
    f32x4 acc = {0.f, 0.f, 0.f, 0.f};
#pragma unroll
    for (int s = 0; s < 16; ++s) {
        half8 a = *(const half8*)&aggL[m][s * 32 + g * 8];
        half8 b = *(const half8*)&w2f[(size_t)(((s * 4 + w) * 64) + l) * 8];
        acc = __builtin_amdgcn_mfma_f32_16x16x32_f16(a, b, acc, 0, 0, 0);
    }
    {   // root term
        int nn = n0 + m; if (nn > N - 1) nn = N - 1;
        half8 a = *(const half8*)&h1h[(size_t)nn * 32 + g * 8];
        half8 b = *(const half8*)&w2f[(size_t)(((64 + w) * 64) + l) * 8];
        acc = __builtin_amdgcn_mfma_f32_16x16x32_f16(a, b, acc, 0, 0, 0);
    }
    int o = w * 16 + m;
    float bb = b2[o];
#pragma unroll
    for (int r = 0; r < 4; ++r) {
        int node = n0 + g * 4 + r;
        if (node < N) out2h[(size_t)node * 64 + o] = (_Float16)(acc[r] + bb);
    }
}

// ---------------- Final MLP via MFMA: elu(bn(out2h)) @ fc1w -> elu -> @ fc2w ----------------

__global__ __launch_bounds__(256) void k_fcm(
    const _Float16* __restrict__ out2h, const _Float16* __restrict__ fc1wf,
    const float* __restrict__ scsh, const float* __restrict__ fc1b,
    const float* __restrict__ fc2w, const float* __restrict__ fc2b,
    float* __restrict__ out, int N, int ntiles) {
    __shared__ _Float16 fw[8192];
    __shared__ float scs[64], shs[64], b1s[128], w2sv[128];
    int tid = threadIdx.x;
    {
        const uint4* s4 = (const uint4*)fc1wf;
        uint4* d4 = (uint4*)fw;
        for (int i = tid; i < 1024; i += 256) d4[i] = s4[i];
    }
    if (tid < 128) { b1s[tid] = fc1b[tid]; w2sv[tid] = fc2w[tid]; }
    if (tid < 64)  { scs[tid] = scsh[tid]; shs[tid] = scsh[64 + tid]; }
    __syncthreads();
    const half8* bp = (const half8*)fw;
    int l = tid & 63, w = tid >> 6;
    int g = l >> 4, m = l & 15, klo = g * 8;
    float f2b = fc2b[0];
    for (int tile = blockIdx.x * 4 + w; tile < ntiles; tile += gridDim.x * 4) {
        int base = tile * 16;
        int arow = base + m; if (arow > N - 1) arow = N - 1;
        const half8* hp = (const half8*)(out2h + (size_t)arow * 64 + klo);
        half8 r0 = hp[0];
        half8 r1 = hp[4];
        half8 a0, a1;
#pragma unroll
        for (int j = 0; j < 8; ++j) {
            int c0 = klo + j, c1 = 32 + klo + j;
            a0[j] = (_Float16)eluf((float)r0[j] * scs[c0] + shs[c0]);
            a1[j] = (_Float16)eluf((float)r1[j] * scs[c1] + shs[c1]);
        }
        f32x4 acc[8];
#pragma unroll
        for (int t = 0; t < 8; ++t) {
            f32x4 z = {0.f, 0.f, 0.f, 0.f};
            acc[t] = __builtin_amdgcn_mfma_f32_16x16x32_f16(a0, bp[t * 64 + l], z, 0, 0, 0);
            acc[t] = __builtin_amdgcn_mfma_f32_16x16x32_f16(a1, bp[(8 + t) * 64 + l], acc[t], 0, 0, 0);
        }
#pragma unroll
        for (int r = 0; r < 4; ++r) {
            float sum = 0.f;
#pragma unroll
            for (int t = 0; t < 8; ++t) {
                int o = t * 16 + m;
                sum += eluf(acc[t][r] + b1s[o]) * w2sv[o];
            }
            sum += __shfl_xor(sum, 1);
            sum += __shfl_xor(sum, 2);
            sum += __shfl_xor(sum, 4);
            sum += __shfl_xor(sum, 8);
            int node = base + g * 4 + r;
            if (m == 0 && node < N) out[node] = sum + f2b;
        }
    }
}

// ---------------------------------------------------------------------------

extern "C" void kernel_launch(void* const* d_in, const int* in_sizes, int n_in,
                              void* d_out, int out_size, void* d_ws, size_t ws_size,
                              hipStream_t stream) {
    const float* x     = (const float*)d_in[0];
    const int*   ei    = (const int*)  d_in[1];
    const float* attr  = (const float*)d_in[2];
    const float* w1    = (const float*)d_in[3];
    const float* root1 = (const float*)d_in[4];
    const float* b1    = (const float*)d_in[5];
    const float* g1    = (const float*)d_in[6];
    const float* be1   = (const float*)d_in[7];
    const float* w2    = (const float*)d_in[8];
    const float* root2 = (const float*)d_in[9];
    const float* b2    = (const float*)d_in[10];
    const float* g2    = (const float*)d_in[11];
    const float* be2   = (const float*)d_in[12];
    const float* fc1w  = (const float*)d_in[13];
    const float* fc1b  = (const float*)d_in[14];
    const float* fc2w  = (const float*)d_in[15];
    const float* fc2b  = (const float*)d_in[16];
    float* out = (float*)d_out;

    int N = in_sizes[0];          // 150000
    int E = in_sizes[1] / 2;      // 3000000

    int nWG  = (E + ACHUNK - 1) / ACHUNK;   // 367
    int NBUK = (N + 255) >> 8;              // 586
    int M    = NBUK * nWG;                  // ~215k

    char* ws = (char*)d_ws;
    size_t off = 0;
    auto alloc = [&](size_t bytes) -> void* {
        void* p = ws + off;
        off = (off + bytes + 255) & ~(size_t)255;
        return p;
    };
    int*      rowptr    = (int*)     alloc((size_t)(N + 1) * 4);
    int*      blockSums = (int*)     alloc(1024 * 4);
    int*      blockOff  = (int*)     alloc(1024 * 4);
    double*   bnsum1    = (double*)  alloc(128 * 8);
    double*   bnsum2    = (double*)  alloc(128 * 8);
    float*    scsh1     = (float*)   alloc(64 * 4);
    float*    scsh2     = (float*)   alloc(128 * 4);
    _Float16* w2f       = (_Float16*)alloc(34816 * 2);
    _Float16* fc1wf     = (_Float16*)alloc(8192 * 2);
    int*      cnt       = (int*)     alloc((size_t)M * 4);
    int*      offs      = (int*)     alloc((size_t)M * 4);
    uint4*    edges     = (uint4*)   alloc((size_t)E * 16);
    size_t    Roff      = off;              // start of aliasable region
    _Float16* h1h       = (_Float16*)alloc((size_t)N * 32 * 2);   //  9.6 MB
    _Float16* out2h     = (_Float16*)alloc((size_t)N * 64 * 2);   // 19.2 MB
    // buf1 + dl1 alias [h1h|out2h|free space] (51 MB); dead before conv1 runs
    uint4*         buf1 = (uint4*)(ws + Roff);
    unsigned char* dl1  = (unsigned char*)(ws + Roff + (size_t)E * 16);
    (void)n_in; (void)out_size; (void)ws_size;

    hipMemsetAsync(bnsum1, 0, 128 * 8, stream);
    hipMemsetAsync(bnsum2, 0, 128 * 8, stream);

    size_t ldsA1 = (size_t)NBUK * 4;
    size_t ldsA2 = (size_t)NBUK * 8 + (size_t)ACHUNK * 4;
    int NBs = (M + 1023) / 1024;

    k_w2pack<<<136, 256, 0, stream>>>(w2, root2, w2f);
    k_fcpack<<<32, 256, 0, stream>>>(fc1w, fc1wf);
    kA1_hist<<<nWG, 256, ldsA1, stream>>>(ei + E, E, cnt, nWG, NBUK);
    k_scan1<<<NBs, 256, 0, stream>>>(cnt, M, offs, blockSums);
    k_scan2<<<1, 256, 0, stream>>>(blockSums, NBs, blockOff);
    k_scan3b<<<(M + 255) / 256, 256, 0, stream>>>(offs, blockOff, M);
    kA2_fill<<<nWG, 256, ldsA2, stream>>>(ei, attr, E, offs, nWG, NBUK, buf1, dl1);
    kB_sort<<<NBUK, 256, 0, stream>>>(buf1, dl1, offs, nWG, NBUK, N, E, edges, rowptr);

    k_conv1<<<(N + 255) / 256, 256, 0, stream>>>(x, rowptr, edges, w1, root1, b1, h1h, N);
    k_bnstath<32><<<256, 256, 0, stream>>>(h1h, N, bnsum1);
    k_bnfinal<<<1, 64, 0, stream>>>(bnsum1, g1, be1, 32, N, scsh1);
    k_bnelu32h<<<1024, 256, 0, stream>>>(h1h, N, scsh1);

    k_ag2<<<(N + 15) / 16, 256, 0, stream>>>(h1h, rowptr, edges, w2f, b2, out2h, N);

    k_bnstath<64><<<256, 256, 0, stream>>>(out2h, N, bnsum2);
    k_bnfinal<<<1, 64, 0, stream>>>(bnsum2, g2, be2, 64, N, scsh2);

    int ntilesF = (N + 15) / 16;
    int gridF = (ntilesF + 3) / 4; if (gridF > 2344) gridF = 2344;
    k_fcm<<<gridF, 256, 0, stream>>>(out2h, fc1wf, scsh2, fc1b, fc2w, fc2b, out, N, ntilesF);
}

// Round 10
// 316.429 us; speedup vs baseline: 5.6945x; 1.1952x over previous
//
#include <hip/hip_runtime.h>
#include <hip/hip_fp16.h>
#include <math.h>

// ---------------------------------------------------------------------------
// SplineCNN (K=4, dim=2, deg=2). v10: kA2_fill stages the whole chunk in LDS
// (coalesced read-once, coalesced write-once); fused MFMA agg+GEMM (k_ag2);
// MFMA final MLP.
// ---------------------------------------------------------------------------

typedef _Float16 half8 __attribute__((ext_vector_type(8)));
typedef _Float16 half4 __attribute__((ext_vector_type(4)));
typedef float    f32x4 __attribute__((ext_vector_type(4)));
typedef int      iv4   __attribute__((ext_vector_type(4)));

#define ACHUNK 4096   // edges per partition WG (16 per thread)

__device__ __forceinline__ void bspline4(float a, float B[4]) {
    a = fminf(fmaxf(a, 0.f), 1.f);
    float v  = a * 2.0f;          // K - DEG = 2
    float kv = floorf(v);
    float t  = v - kv;
    int   ik = (int)kv;           // 0..2
    float b0 = 0.5f * (1.f - t) * (1.f - t);
    float b1 = (t - t * t) + 0.5f;
    float b2 = 0.5f * t * t;
    int c0 = ik;
    int c1 = ik + 1;
    int c2 = ik + 2; if (c2 > 3) c2 = 3;
#pragma unroll
    for (int j = 0; j < 4; ++j)
        B[j] = (c0 == j ? b0 : 0.f) + (c1 == j ? b1 : 0.f) + (c2 == j ? b2 : 0.f);
}

__device__ __forceinline__ float eluf(float x) {
    return x > 0.f ? x : expm1f(x);
}

__device__ __forceinline__ void unpack_basis(uint4 rec, float bu[4], float bv[4]) {
    float2 f01 = __half22float2(*(const __half2*)&rec.y);
    float2 f23 = __half22float2(*(const __half2*)&rec.z);
    float2 f45 = __half22float2(*(const __half2*)&rec.w);
    bu[0] = f01.x; bu[1] = f01.y; bu[2] = f23.x;
    bu[3] = 1.f - (bu[0] + bu[1] + bu[2]);
    bv[0] = f23.y; bv[1] = f45.x; bv[2] = f45.y;
    bv[3] = 1.f - (bv[0] + bv[1] + bv[2]);
}

__device__ __forceinline__ uint4 make_edge_rec(unsigned src, float u, float v) {
    float Bu[4], Bv[4];
    bspline4(u, Bu);
    bspline4(v, Bv);
    __half2 p01 = __floats2half2_rn(Bu[0], Bu[1]);
    __half2 p23 = __floats2half2_rn(Bu[2], Bv[0]);
    __half2 p45 = __floats2half2_rn(Bv[1], Bv[2]);
    uint4 rec;
    rec.x = src;
    rec.y = *(const unsigned*)&p01;
    rec.z = *(const unsigned*)&p23;
    rec.w = *(const unsigned*)&p45;
    return rec;
}

// ---------------- Phase A: bucketed partition (bucket = dst >> 8) ----------------

__global__ void kA1_hist(const int* __restrict__ dst, int E, int* __restrict__ cnt,
                         int nWG, int NBUK) {
    extern __shared__ int hist[];   // NBUK ints
    int wg = blockIdx.x, tid = threadIdx.x;
    for (int b = tid; b < NBUK; b += 256) hist[b] = 0;
    __syncthreads();
    int base = wg * ACHUNK;
    int end  = base + ACHUNK; if (end > E) end = E;
    for (int i = base + tid; i < end; i += 256)
        atomicAdd(&hist[dst[i] >> 8], 1);
    __syncthreads();
    for (int b = tid; b < NBUK; b += 256) cnt[b * nWG + wg] = hist[b];
}

__global__ void k_scan1(const int* __restrict__ in, int M,
                        int* __restrict__ outp, int* __restrict__ blockSums) {
    __shared__ int wsum[4];
    int tid  = threadIdx.x;
    int base = blockIdx.x * 1024 + tid * 4;
    int d0 = (base + 0) < M ? in[base + 0] : 0;
    int d1 = (base + 1) < M ? in[base + 1] : 0;
    int d2 = (base + 2) < M ? in[base + 2] : 0;
    int d3 = (base + 3) < M ? in[base + 3] : 0;
    int s4 = d0 + d1 + d2 + d3;
    int lane = tid & 63, wid = tid >> 6;
    int inc = s4;
#pragma unroll
    for (int off = 1; off < 64; off <<= 1) {
        int t = __shfl_up(inc, off);
        if (lane >= off) inc += t;
    }
    if (lane == 63) wsum[wid] = inc;
    __syncthreads();
    if (tid == 0) {
        int acc = 0;
#pragma unroll
        for (int w = 0; w < 4; ++w) { int t = wsum[w]; wsum[w] = acc; acc += t; }
    }
    __syncthreads();
    int ebase = wsum[wid] + inc - s4;
    if ((base + 0) < M) outp[base + 0] = ebase;
    if ((base + 1) < M) outp[base + 1] = ebase + d0;
    if ((base + 2) < M) outp[base + 2] = ebase + d0 + d1;
    if ((base + 3) < M) outp[base + 3] = ebase + d0 + d1 + d2;
    if (tid == 255) blockSums[blockIdx.x] = ebase + s4;
}

// capacity 512 (2 elems per thread)
__global__ void k_scan2(const int* __restrict__ blockSums, int NB, int* __restrict__ blockOff) {
    __shared__ int sh[256];
    int tid = threadIdx.x;
    int i0 = 2 * tid, i1 = 2 * tid + 1;
    int a = (i0 < NB) ? blockSums[i0] : 0;
    int b = (i1 < NB) ? blockSums[i1] : 0;
    int p = a + b;
    sh[tid] = p;
    __syncthreads();
    for (int off = 1; off < 256; off <<= 1) {
        int v = (tid >= off) ? sh[tid - off] : 0;
        __syncthreads();
        sh[tid] += v;
        __syncthreads();
    }
    int excl = sh[tid] - p;
    if (i0 < NB) blockOff[i0] = excl;
    if (i1 < NB) blockOff[i1] = excl + a;
}

__global__ void k_scan3b(int* __restrict__ arr, const int* __restrict__ blockOff, int M) {
    int i = blockIdx.x * blockDim.x + threadIdx.x;
    if (i < M) arr[i] += blockOff[i >> 10];
}

// fill pass v3: whole chunk staged in LDS (src + fp16 attr + slot meta);
// global reads coalesced-once, global writes contiguous runs.
__global__ __launch_bounds__(256) void kA2_fill(
    const int* __restrict__ ei, const float* __restrict__ attr, int E,
    const int* __restrict__ offs, int nWG, int NBUK,
    uint4* __restrict__ buf1, unsigned char* __restrict__ dl1) {
    extern __shared__ int lds[];
    int*      hist  = lds;                         // NBUK (becomes pref)
    int*      srcS  = hist + NBUK;                 // ACHUNK
    unsigned* attrS = (unsigned*)(srcS + ACHUNK);  // ACHUNK (fp16 u,v)
    unsigned* meta  = attrS + ACHUNK;              // ACHUNK: i | b<<12 | dlow<<22
    __shared__ int wsum[4];
    int wg = blockIdx.x, tid = threadIdx.x;
    int base  = wg * ACHUNK;
    int csize = E - base; if (csize > ACHUNK) csize = ACHUNK;

    for (int b = tid; b < NBUK; b += 256) hist[b] = 0;
    __syncthreads();

    int dArr[16], ranks[16];
#pragma unroll
    for (int k = 0; k < 16; ++k) {
        int i = tid + (k << 8);
        if (i < csize) {
            int d = ei[E + base + i];
            dArr[k]  = d;
            ranks[k] = atomicAdd(&hist[d >> 8], 1);
        }
    }
    __syncthreads();

    // in-place exclusive scan: hist -> pref
    int IT = (NBUK + 255) >> 8;
    int b0 = tid * IT;
    int lsum = 0;
    for (int k = 0; k < IT; ++k) {
        int b = b0 + k;
        if (b < NBUK) lsum += hist[b];
    }
    int lane = tid & 63, wid = tid >> 6;
    int inc = lsum;
#pragma unroll
    for (int off = 1; off < 64; off <<= 1) {
        int t = __shfl_up(inc, off);
        if (lane >= off) inc += t;
    }
    if (lane == 63) wsum[wid] = inc;
    __syncthreads();
    if (tid == 0) {
        int acc = 0;
#pragma unroll
        for (int w = 0; w < 4; ++w) { int t = wsum[w]; wsum[w] = acc; acc += t; }
    }
    __syncthreads();
    int run = wsum[wid] + inc - lsum;
    for (int k = 0; k < IT; ++k) {
        int b = b0 + k;
        if (b < NBUK) { int h = hist[b]; hist[b] = run; run += h; }
    }
    __syncthreads();   // hist[] now holds pref[]

    // place meta + stage src/attr (coalesced global reads, once)
#pragma unroll
    for (int k = 0; k < 16; ++k) {
        int i = tid + (k << 8);
        if (i < csize) {
            int gi = base + i;
            int d  = dArr[k];
            int b  = d >> 8;
            int s  = hist[b] + ranks[k];
            meta[s] = (unsigned)i | ((unsigned)b << 12) | ((unsigned)(d & 255) << 22);
            srcS[i] = ei[gi];
            __half2 uv = __floats2half2_rn(attr[2 * gi], attr[2 * gi + 1]);
            attrS[i] = *(const unsigned*)&uv;
        }
    }
    __syncthreads();

    // emit in sorted slot order (contiguous global writes)
    for (int s = tid; s < csize; s += 256) {
        unsigned mt = meta[s];
        int i = mt & 4095;
        int b = (mt >> 12) & 1023;
        unsigned av = attrS[i];
        float2 uv = __half22float2(*(const __half2*)&av);
        uint4 rec = make_edge_rec((unsigned)srcS[i], uv.x, uv.y);
        int gpos = offs[b * nWG + wg] + (s - hist[b]);
        buf1[gpos] = rec;
        dl1[gpos]  = (unsigned char)(mt >> 22);
    }
}

// ---------------- Phase B: per-bucket exact-dst sort + rowptr ----------------

__global__ __launch_bounds__(256) void kB_sort(
    const uint4* __restrict__ buf1, const unsigned char* __restrict__ dl1,
    const int* __restrict__ off, int nWG, int NBUK, int N, int E,
    uint4* __restrict__ edges, int* __restrict__ rowptr) {
    __shared__ int hist[256], pref[256], curs[256];
    __shared__ int sbase, ssize;
    int b = blockIdx.x, tid = threadIdx.x;
    if (tid == 0) {
        int s  = off[b * nWG];
        int e2 = (b + 1 < NBUK) ? off[(b + 1) * nWG] : E;
        sbase = s; ssize = e2 - s;
    }
    hist[tid] = 0;
    __syncthreads();
    int base = sbase, size = ssize;
    for (int i = tid; i < size; i += 256) atomicAdd(&hist[dl1[base + i]], 1);
    __syncthreads();
    if (tid == 0) {
        int acc = 0;
        for (int j = 0; j < 256; ++j) { pref[j] = acc; acc += hist[j]; }
    }
    __syncthreads();
    curs[tid] = pref[tid];
    int node = b * 256 + tid;
    if (node < N) rowptr[node] = base + pref[tid];
    if (b == NBUK - 1 && tid == 0) rowptr[N] = E;
    __syncthreads();
    for (int i = tid; i < size; i += 256) {
        int p = atomicAdd(&curs[dl1[base + i]], 1);
        edges[base + p] = buf1[base + i];
    }
}

// ---------------- w2 + root2 pre-pack into B-fragment order (fp16) ----------------
// agg k-position p = ch*16 + k  (ch in [0,32), k = ku+4kv in [0,16)).

__global__ void k_w2pack(const float* __restrict__ w2, const float* __restrict__ root2,
                         _Float16* __restrict__ w2f) {
    int f = blockIdx.x * blockDim.x + threadIdx.x;
    int stride = gridDim.x * blockDim.x;
    for (; f < 34816; f += stride) {
        int j = f & 7, l = (f >> 3) & 63, t = (f >> 9) & 3;
        int o = t * 16 + (l & 15);
        float v;
        if (f < 32768) {
            int s = f >> 11;
            int p = s * 32 + ((l >> 4) << 3) + j;
            int ch = p >> 4, k = p & 15;
            v = w2[(k * 32 + ch) * 64 + o];
        } else {
            int ci = ((l >> 4) << 3) + j;
            v = root2[ci * 64 + o];
        }
        w2f[f] = (_Float16)v;
    }
}

// ---------------- fc1w pre-pack into B-fragment order (fp16) ----------------

__global__ void k_fcpack(const float* __restrict__ fc1w, _Float16* __restrict__ fc1wf) {
    int f = blockIdx.x * blockDim.x + threadIdx.x;
    if (f >= 8192) return;
    int j = f & 7, l = (f >> 3) & 63, t = (f >> 9) & 7, s = f >> 12;
    int k = s * 32 + ((l >> 4) << 3) + j;
    int o = t * 16 + (l & 15);
    fc1wf[f] = (_Float16)fc1w[k * 128 + o];
}

// ---------------- Layer 1 conv (in=1 -> out=32), thread per node, fp16 out ----------------

__global__ void k_conv1(const float* __restrict__ x, const int* __restrict__ rowptr,
                        const uint4* __restrict__ edges,
                        const float* __restrict__ w1, const float* __restrict__ root1,
                        const float* __restrict__ b1, _Float16* __restrict__ h1h, int N) {
    __shared__ float w1s[16 * 32];
    __shared__ float r1s[32], b1s[32];
    int tid = threadIdx.x;
    for (int i = tid; i < 512; i += blockDim.x) w1s[i] = w1[i];
    if (tid < 32) { r1s[tid] = root1[tid]; b1s[tid] = b1[tid]; }
    __syncthreads();
    int n = blockIdx.x * blockDim.x + tid;
    if (n >= N) return;
    float agg[16] = {};
    int s = rowptr[n], e = rowptr[n + 1];

#define P1(rec, xs) { \
    float bu[4], bv[4]; \
    unpack_basis(rec, bu, bv); \
    float t0 = (xs) * bv[0], t1 = (xs) * bv[1], t2 = (xs) * bv[2], t3 = (xs) * bv[3]; \
    agg[0]  += bu[0] * t0; agg[1]  += bu[1] * t0; agg[2]  += bu[2] * t0; agg[3]  += bu[3] * t0; \
    agg[4]  += bu[0] * t1; agg[5]  += bu[1] * t1; agg[6]  += bu[2] * t1; agg[7]  += bu[3] * t1; \
    agg[8]  += bu[0] * t2; agg[9]  += bu[1] * t2; agg[10] += bu[2] * t2; agg[11] += bu[3] * t2; \
    agg[12] += bu[0] * t3; agg[13] += bu[1] * t3; agg[14] += bu[2] * t3; agg[15] += bu[3] * t3; }

    int j = s;
    for (; j + 3 < e; j += 4) {
        uint4 r0 = edges[j], r1 = edges[j + 1], r2 = edges[j + 2], r3 = edges[j + 3];
        float x0 = x[r0.x], x1 = x[r1.x], x2 = x[r2.x], x3 = x[r3.x];
        P1(r0, x0); P1(r1, x1); P1(r2, x2); P1(r3, x3);
    }
    for (; j < e; ++j) {
        uint4 r = edges[j];
        float xs = x[r.x];
        P1(r, xs);
    }
#undef P1

    float xn = x[n];
    _Float16* hp = h1h + (size_t)n * 32;
#pragma unroll
    for (int o8 = 0; o8 < 4; ++o8) {
        half8 hv;
#pragma unroll
        for (int oo = 0; oo < 8; ++oo) {
            int o = o8 * 8 + oo;
            float acc = b1s[o] + xn * r1s[o];
#pragma unroll
            for (int k = 0; k < 16; ++k) acc += agg[k] * w1s[k * 32 + o];
            hv[oo] = (_Float16)acc;
        }
        *(half8*)(hp + o8 * 8) = hv;
    }
}

// ---------------- BatchNorm (fp16 input stats) ----------------

template <int C>
__global__ void k_bnstath(const _Float16* __restrict__ h, int N, double* __restrict__ sums) {
    __shared__ float sh1[C], sh2[C];
    int tid  = blockIdx.x * blockDim.x + threadIdx.x;
    int c    = tid & (C - 1);
    int row  = tid / C;
    int rstr = (gridDim.x * blockDim.x) / C;
    float s1 = 0.f, s2 = 0.f;
    for (int r = row; r < N; r += rstr) {
        float v = (float)h[(size_t)r * C + c];
        s1 += v; s2 += v * v;
    }
    if (threadIdx.x < C) { sh1[threadIdx.x] = 0.f; sh2[threadIdx.x] = 0.f; }
    __syncthreads();
    atomicAdd(&sh1[c], s1);
    atomicAdd(&sh2[c], s2);
    __syncthreads();
    if (threadIdx.x < C) {
        atomicAdd(&sums[threadIdx.x],     (double)sh1[threadIdx.x]);
        atomicAdd(&sums[C + threadIdx.x], (double)sh2[threadIdx.x]);
    }
}

__global__ void k_bnfinal(const double* __restrict__ sums, const float* __restrict__ gamma,
                          const float* __restrict__ beta, int C, int N, float* __restrict__ scsh) {
    int c = threadIdx.x;
    if (c < C) {
        double m   = sums[c] / (double)N;
        double var = sums[C + c] / (double)N - m * m;
        float vpe  = (float)var + 1e-5f;
        float sc   = gamma[c] / sqrtf(vpe);
        scsh[c]     = sc;
        scsh[C + c] = beta[c] - (float)m * sc;
    }
}

// BN + ELU for h1h (C=32), in place fp16
__global__ void k_bnelu32h(_Float16* __restrict__ hh, int N, const float* __restrict__ scsh) {
    int total = N * 4;
    int i = blockIdx.x * blockDim.x + threadIdx.x;
    int stride = gridDim.x * blockDim.x;
    for (; i < total; i += stride) {
        half8 v = *(half8*)(hh + (size_t)i * 8);
        int c0 = (i * 8) & 31;
        half8 r;
#pragma unroll
        for (int j = 0; j < 8; ++j)
            r[j] = (_Float16)eluf((float)v[j] * scsh[c0 + j] + scsh[32 + c0 + j]);
        *(half8*)(hh + (size_t)i * 8) = r;
    }
}

// ---------------- Layer 2 fused: MFMA aggregation + GEMM (k_ag2) ----------------

__global__ __launch_bounds__(256) void k_ag2(
    const _Float16* __restrict__ h1h, const int* __restrict__ rowptr,
    const uint4* __restrict__ edges, const _Float16* __restrict__ w2f,
    const float* __restrict__ b2, _Float16* __restrict__ out2h, int N) {
    __shared__ __align__(16) _Float16 aggL[16][520];     // p = ch*16+k, pad 520
    __shared__ __align__(16) _Float16 basisL[4][16][72]; // [wave][k][edge(+pad)]
    __shared__ __align__(16) int      srcL[4][64];
    int tid = threadIdx.x, l = tid & 63, w = tid >> 6;
    int g = l >> 4, m = l & 15;
    int n0 = blockIdx.x * 16;

    for (int q = 0; q < 4; ++q) {
        int row = w * 4 + q;
        int n = n0 + row;
        if (n < N) {
            int s = __builtin_amdgcn_readfirstlane(rowptr[n]);
            int e = __builtin_amdgcn_readfirstlane(rowptr[n + 1]);
            f32x4 C0 = {0.f, 0.f, 0.f, 0.f}, C1 = C0;
            for (int t = s; t < e; t += 64) {
                int eg = t + l;
                bool act = eg < e;
                uint4 rec = edges[act ? eg : e - 1];
                srcL[w][l] = act ? (int)rec.x : 0;
                float bu[4], bv[4];
                unpack_basis(rec, bu, bv);
#pragma unroll
                for (int kv = 0; kv < 4; ++kv)
#pragma unroll
                    for (int ku = 0; ku < 4; ++ku)
                        basisL[w][kv * 4 + ku][l] = (_Float16)(bu[ku] * bv[kv]);
                int rem = e - t;
#pragma unroll
                for (int kh = 0; kh < 2; ++kh) {
                    if (kh == 1 && rem <= 32) break;
                    int ebase = kh * 32 + g * 8;
                    half8 a = *(const half8*)&basisL[w][m][ebase];
                    iv4 sA = *(const iv4*)&srcL[w][ebase];
                    iv4 sB = *(const iv4*)&srcL[w][ebase + 4];
                    half8 b0, b1;
#pragma unroll
                    for (int j = 0; j < 8; ++j) {
                        int sj = (j < 4) ? sA[j] : sB[j - 4];
                        bool aj = (t + ebase + j) < e;
                        _Float16 v0 = h1h[(size_t)sj * 32 + m];
                        _Float16 v1 = h1h[(size_t)sj * 32 + 16 + m];
                        b0[j] = aj ? v0 : (_Float16)0.f;
                        b1[j] = aj ? v1 : (_Float16)0.f;
                    }
                    C0 = __builtin_amdgcn_mfma_f32_16x16x32_f16(a, b0, C0, 0, 0, 0);
                    C1 = __builtin_amdgcn_mfma_f32_16x16x32_f16(a, b1, C1, 0, 0, 0);
                }
            }
            half4 c0, c1;
#pragma unroll
            for (int r = 0; r < 4; ++r) { c0[r] = (_Float16)C0[r]; c1[r] = (_Float16)C1[r]; }
            *(half4*)&aggL[row][m * 16 + g * 4]        = c0;
            *(half4*)&aggL[row][(16 + m) * 16 + g * 4] = c1;
        }
    }
    __syncthreads();

    f32x4 acc = {0.f, 0.f, 0.f, 0.f};
#pragma unroll
    for (int s = 0; s < 16; ++s) {
        half8 a = *(const half8*)&aggL[m][s * 32 + g * 8];
        half8 b = *(const half8*)&w2f[(size_t)(((s * 4 + w) * 64) + l) * 8];
        acc = __builtin_amdgcn_mfma_f32_16x16x32_f16(a, b, acc, 0, 0, 0);
    }
    {
        int nn = n0 + m; if (nn > N - 1) nn = N - 1;
        half8 a = *(const half8*)&h1h[(size_t)nn * 32 + g * 8];
        half8 b = *(const half8*)&w2f[(size_t)(((64 + w) * 64) + l) * 8];
        acc = __builtin_amdgcn_mfma_f32_16x16x32_f16(a, b, acc, 0, 0, 0);
    }
    int o = w * 16 + m;
    float bb = b2[o];
#pragma unroll
    for (int r = 0; r < 4; ++r) {
        int node = n0 + g * 4 + r;
        if (node < N) out2h[(size_t)node * 64 + o] = (_Float16)(acc[r] + bb);
    }
}

// ---------------- Final MLP via MFMA ----------------

__global__ __launch_bounds__(256) void k_fcm(
    const _Float16* __restrict__ out2h, const _Float16* __restrict__ fc1wf,
    const float* __restrict__ scsh, const float* __restrict__ fc1b,
    const float* __restrict__ fc2w, const float* __restrict__ fc2b,
    float* __restrict__ out, int N, int ntiles) {
    __shared__ _Float16 fw[8192];
    __shared__ float scs[64], shs[64], b1s[128], w2sv[128];
    int tid = threadIdx.x;
    {
        const uint4* s4 = (const uint4*)fc1wf;
        uint4* d4 = (uint4*)fw;
        for (int i = tid; i < 1024; i += 256) d4[i] = s4[i];
    }
    if (tid < 128) { b1s[tid] = fc1b[tid]; w2sv[tid] = fc2w[tid]; }
    if (tid < 64)  { scs[tid] = scsh[tid]; shs[tid] = scsh[64 + tid]; }
    __syncthreads();
    const half8* bp = (const half8*)fw;
    int l = tid & 63, w = tid >> 6;
    int g = l >> 4, m = l & 15, klo = g * 8;
    float f2b = fc2b[0];
    for (int tile = blockIdx.x * 4 + w; tile < ntiles; tile += gridDim.x * 4) {
        int base = tile * 16;
        int arow = base + m; if (arow > N - 1) arow = N - 1;
        const half8* hp = (const half8*)(out2h + (size_t)arow * 64 + klo);
        half8 r0 = hp[0];
        half8 r1 = hp[4];
        half8 a0, a1;
#pragma unroll
        for (int j = 0; j < 8; ++j) {
            int c0 = klo + j, c1 = 32 + klo + j;
            a0[j] = (_Float16)eluf((float)r0[j] * scs[c0] + shs[c0]);
            a1[j] = (_Float16)eluf((float)r1[j] * scs[c1] + shs[c1]);
        }
        f32x4 acc[8];
#pragma unroll
        for (int t = 0; t < 8; ++t) {
            f32x4 z = {0.f, 0.f, 0.f, 0.f};
            acc[t] = __builtin_amdgcn_mfma_f32_16x16x32_f16(a0, bp[t * 64 + l], z, 0, 0, 0);
            acc[t] = __builtin_amdgcn_mfma_f32_16x16x32_f16(a1, bp[(8 + t) * 64 + l], acc[t], 0, 0, 0);
        }
#pragma unroll
        for (int r = 0; r < 4; ++r) {
            float sum = 0.f;
#pragma unroll
            for (int t = 0; t < 8; ++t) {
                int o = t * 16 + m;
                sum += eluf(acc[t][r] + b1s[o]) * w2sv[o];
            }
            sum += __shfl_xor(sum, 1);
            sum += __shfl_xor(sum, 2);
            sum += __shfl_xor(sum, 4);
            sum += __shfl_xor(sum, 8);
            int node = base + g * 4 + r;
            if (m == 0 && node < N) out[node] = sum + f2b;
        }
    }
}

// ---------------------------------------------------------------------------

extern "C" void kernel_launch(void* const* d_in, const int* in_sizes, int n_in,
                              void* d_out, int out_size, void* d_ws, size_t ws_size,
                              hipStream_t stream) {
    const float* x     = (const float*)d_in[0];
    const int*   ei    = (const int*)  d_in[1];
    const float* attr  = (const float*)d_in[2];
    const float* w1    = (const float*)d_in[3];
    const float* root1 = (const float*)d_in[4];
    const float* b1    = (const float*)d_in[5];
    const float* g1    = (const float*)d_in[6];
    const float* be1   = (const float*)d_in[7];
    const float* w2    = (const float*)d_in[8];
    const float* root2 = (const float*)d_in[9];
    const float* b2    = (const float*)d_in[10];
    const float* g2    = (const float*)d_in[11];
    const float* be2   = (const float*)d_in[12];
    const float* fc1w  = (const float*)d_in[13];
    const float* fc1b  = (const float*)d_in[14];
    const float* fc2w  = (const float*)d_in[15];
    const float* fc2b  = (const float*)d_in[16];
    float* out = (float*)d_out;

    int N = in_sizes[0];          // 150000
    int E = in_sizes[1] / 2;      // 3000000

    int nWG  = (E + ACHUNK - 1) / ACHUNK;   // 733
    int NBUK = (N + 255) >> 8;              // 586
    int M    = NBUK * nWG;                  // ~430k

    char* ws = (char*)d_ws;
    size_t off = 0;
    auto alloc = [&](size_t bytes) -> void* {
        void* p = ws + off;
        off = (off + bytes + 255) & ~(size_t)255;
        return p;
    };
    int*      rowptr    = (int*)     alloc((size_t)(N + 1) * 4);
    int*      blockSums = (int*)     alloc(1024 * 4);
    int*      blockOff  = (int*)     alloc(1024 * 4);
    double*   bnsum1    = (double*)  alloc(128 * 8);
    double*   bnsum2    = (double*)  alloc(128 * 8);
    float*    scsh1     = (float*)   alloc(64 * 4);
    float*    scsh2     = (float*)   alloc(128 * 4);
    _Float16* w2f       = (_Float16*)alloc(34816 * 2);
    _Float16* fc1wf     = (_Float16*)alloc(8192 * 2);
    int*      cnt       = (int*)     alloc((size_t)M * 4);
    int*      offs      = (int*)     alloc((size_t)M * 4);
    uint4*    edges     = (uint4*)   alloc((size_t)E * 16);
    size_t    Roff      = off;              // start of aliasable region
    _Float16* h1h       = (_Float16*)alloc((size_t)N * 32 * 2);   //  9.6 MB
    _Float16* out2h     = (_Float16*)alloc((size_t)N * 64 * 2);   // 19.2 MB
    // buf1 + dl1 alias [h1h|out2h|free space]; dead before conv1 runs
    uint4*         buf1 = (uint4*)(ws + Roff);
    unsigned char* dl1  = (unsigned char*)(ws + Roff + (size_t)E * 16);
    (void)n_in; (void)out_size; (void)ws_size;

    hipMemsetAsync(bnsum1, 0, 128 * 8, stream);
    hipMemsetAsync(bnsum2, 0, 128 * 8, stream);

    size_t ldsA1 = (size_t)NBUK * 4;
    size_t ldsA2 = (size_t)NBUK * 4 + (size_t)ACHUNK * 12;  // hist + src+attr+meta
    int NBs = (M + 1023) / 1024;            // ~420 <= 512

    k_w2pack<<<136, 256, 0, stream>>>(w2, root2, w2f);
    k_fcpack<<<32, 256, 0, stream>>>(fc1w, fc1wf);
    kA1_hist<<<nWG, 256, ldsA1, stream>>>(ei + E, E, cnt, nWG, NBUK);
    k_scan1<<<NBs, 256, 0, stream>>>(cnt, M, offs, blockSums);
    k_scan2<<<1, 256, 0, stream>>>(blockSums, NBs, blockOff);
    k_scan3b<<<(M + 255) / 256, 256, 0, stream>>>(offs, blockOff, M);
    kA2_fill<<<nWG, 256, ldsA2, stream>>>(ei, attr, E, offs, nWG, NBUK, buf1, dl1);
    kB_sort<<<NBUK, 256, 0, stream>>>(buf1, dl1, offs, nWG, NBUK, N, E, edges, rowptr);

    k_conv1<<<(N + 255) / 256, 256, 0, stream>>>(x, rowptr, edges, w1, root1, b1, h1h, N);
    k_bnstath<32><<<256, 256, 0, stream>>>(h1h, N, bnsum1);
    k_bnfinal<<<1, 64, 0, stream>>>(bnsum1, g1, be1, 32, N, scsh1);
    k_bnelu32h<<<1024, 256, 0, stream>>>(h1h, N, scsh1);

    k_ag2<<<(N + 15) / 16, 256, 0, stream>>>(h1h, rowptr, edges, w2f, b2, out2h, N);

    k_bnstath<64><<<256, 256, 0, stream>>>(out2h, N, bnsum2);
    k_bnfinal<<<1, 64, 0, stream>>>(bnsum2, g2, be2, 64, N, scsh2);

    int ntilesF = (N + 15) / 16;
    int gridF = (ntilesF + 3) / 4; if (gridF > 2344) gridF = 2344;
    k_fcm<<<gridF, 256, 0, stream>>>(out2h, fc1wf, scsh2, fc1b, fc2w, fc2b, out, N, ntilesF);
}